// Round 5
// baseline (710.678 us; speedup 1.0000x reference)
//
#include <hip/hip_runtime.h>
#include <hip/hip_fp16.h>
#include <cstdint>

#define BN_EPS 1e-5f

typedef _Float16 f16;
typedef _Float16 f16x8 __attribute__((ext_vector_type(8)));
typedef _Float16 f16x4 __attribute__((ext_vector_type(4)));
typedef float f32x4 __attribute__((ext_vector_type(4)));

// ============================ edge preprocessing ============================

// Detect int64 vs int32 edge buffer (JAX may canonicalize int64 -> int32).
__global__ __launch_bounds__(256) void detect_k(const unsigned* __restrict__ eb,
                                                int E, int* __restrict__ flag) {
  int nz = 0;
  for (long long i = (long long)blockIdx.x * 256 + threadIdx.x; i < E;
       i += (long long)gridDim.x * 256)
    nz |= (eb[2 * i + 1] != 0u);
  if (__any(nz) && (threadIdx.x & 63) == 0) atomicOr(flag, 1);
}

__device__ __forceinline__ void load_edge(const void* eb, int E, bool w64,
                                          int e, int& s, int& d) {
  if (w64) {
    const long long* p = (const long long*)eb;
    s = (int)p[e];
    d = (int)p[E + e];
  } else {
    const int* p = (const int*)eb;
    s = p[e];
    d = p[E + e];
  }
}

__global__ __launch_bounds__(256) void count_k(const void* __restrict__ eb, int E,
                                               const int* __restrict__ flag,
                                               int* __restrict__ counts) {
  bool w64 = (*flag == 0);
  for (int e = blockIdx.x * 256 + threadIdx.x; e < E; e += gridDim.x * 256) {
    int s, d;
    load_edge(eb, E, w64, e, s, d);
    atomicAdd(&counts[d], 1);
  }
}

// --- scan pass 1: per-block sums (dinv fused) ---
__global__ __launch_bounds__(256) void scan1_k(const int* __restrict__ counts,
                                               int* __restrict__ bsum,
                                               float* __restrict__ dinv, int n) {
  __shared__ int ls[256];
  int t = threadIdx.x;
  int i = blockIdx.x * 256 + t;
  int c = (i < n) ? counts[i] : 0;
  if (i < n) dinv[i] = rsqrtf((float)(c + 1));  // +1 self-loop
  ls[t] = c;
  __syncthreads();
  for (int off = 128; off > 0; off >>= 1) {
    if (t < off) ls[t] += ls[t + off];
    __syncthreads();
  }
  if (t == 0) bsum[blockIdx.x] = ls[0];
}

// --- scan pass 2: each block derives its own prefix from bsum (NB <= 512) ---
__global__ __launch_bounds__(256) void scanF_k(const int* __restrict__ counts,
                                               const int* __restrict__ bsum,
                                               int* __restrict__ rp, int n, int E) {
  __shared__ int sa[256], sb[256];
  __shared__ int red[256];
  int t = threadIdx.x;
  // block-prefix: sum of bsum[j] for j < blockIdx.x
  int pacc = 0;
  for (int j = t; j < (int)blockIdx.x; j += 256) pacc += bsum[j];
  red[t] = pacc;
  __syncthreads();
  for (int off = 128; off > 0; off >>= 1) {
    if (t < off) red[t] += red[t + off];
    __syncthreads();
  }
  int off0 = red[0];
  __syncthreads();

  int i = blockIdx.x * 256 + t;
  int v = (i < n) ? counts[i] : 0;
  sa[t] = v;
  __syncthreads();
  int* src = sa;
  int* dst = sb;
  for (int off = 1; off < 256; off <<= 1) {
    int val = src[t] + (t >= off ? src[t - off] : 0);
    dst[t] = val;
    __syncthreads();
    int* tmp = src; src = dst; dst = tmp;
  }
  int incl = src[t];
  if (i < n) rp[i] = off0 + incl - v;
  if (i == n - 1) rp[n] = E;
}

// CSR entry: just the src index (norm folded into GEMM epilogue via dinv)
__global__ __launch_bounds__(256) void fill_k(const void* __restrict__ eb, int E,
                                              const int* __restrict__ flag,
                                              const int* __restrict__ rp,
                                              int* __restrict__ cursor,
                                              int* __restrict__ csr) {
  bool w64 = (*flag == 0);
  for (int e = blockIdx.x * 256 + threadIdx.x; e < E; e += gridDim.x * 256) {
    int s, d;
    load_edge(eb, E, w64, e, s, d);
    int pos = atomicAdd(&cursor[d], 1);
    csr[rp[d] + pos] = s;
  }
}

// ============================ W prep: transpose + fp16 (single launch) ============
// Wt[nc][k] = (f16) W[k][nc]; Wt3 zero-padded to 64 rows.
__global__ void prep_all(const float* __restrict__ W1, const float* __restrict__ W2,
                         const float* __restrict__ W3, f16* __restrict__ Wt1,
                         f16* __restrict__ Wt2, f16* __restrict__ Wt3) {
  int b = blockIdx.x, k = threadIdx.x;  // 128 threads
  if (b < 128) {
    Wt1[(size_t)b * 128 + k] = (f16)W1[(size_t)k * 128 + b];
  } else if (b < 256) {
    int nc = b - 128;
    Wt2[(size_t)nc * 128 + k] = (f16)W2[(size_t)k * 128 + nc];
  } else {
    int nc = b - 256;  // 0..63
    Wt3[(size_t)nc * 128 + k] = (nc < 40) ? (f16)W3[(size_t)k * 40 + nc] : (f16)0.f;
  }
}

// ============================ GEMM (MFMA f16) ============================
// H'[n][NCP] = dinv_row * act(X)[n][128] @ W[128][NCP]
// act = BN scale/shift + ReLU if BN (scale/shift derived in-kernel from raw sums).
// 256 thr = 4 waves, tile 128 rows; operand-swapped mfma -> 4 consecutive cols/lane.
template <int NCP, bool BN, bool F32IN>
__global__ __launch_bounds__(256) void gemm_mfma(const void* __restrict__ Xv,
                                                 const f16* __restrict__ Wt,
                                                 const float* __restrict__ bn_acc,
                                                 const float* __restrict__ g,
                                                 const float* __restrict__ bt,
                                                 float inv_n,
                                                 const float* __restrict__ dinv,
                                                 f16* __restrict__ H, int n) {
  constexpr int CB = NCP / 16;
  __shared__ f16 Xs[128][136];
  __shared__ f16 Ws[NCP][136];
  __shared__ float bnS[128], bnH[128];
  const int t = threadIdx.x;
  const int m0 = blockIdx.x * 128;

  if (BN) {
    if (t < 128) {
      float mean = bn_acc[t] * inv_n;
      float var = bn_acc[128 + t] * inv_n - mean * mean;
      float sc = g[t] * rsqrtf(var + BN_EPS);
      bnS[t] = sc;
      bnH[t] = fmaf(-mean, sc, bt[t]);
    }
    __syncthreads();
  }

  // ---- stage X tile (fp32 or fp16 global -> fp16 LDS, BN+ReLU fused) ----
  if constexpr (F32IN) {
    const float* X = (const float*)Xv;
#pragma unroll
    for (int p = 0; p < 16; p++) {
      int idx = p * 256 + t;          // 4096 float4 units
      int row = idx >> 5, c = (idx & 31) * 4;
      float4 v = make_float4(0.f, 0.f, 0.f, 0.f);
      if (m0 + row < n) v = *(const float4*)&X[(size_t)(m0 + row) * 128 + c];
      if (BN) {
        v.x = fmaxf(fmaf(v.x, bnS[c + 0], bnH[c + 0]), 0.f);
        v.y = fmaxf(fmaf(v.y, bnS[c + 1], bnH[c + 1]), 0.f);
        v.z = fmaxf(fmaf(v.z, bnS[c + 2], bnH[c + 2]), 0.f);
        v.w = fmaxf(fmaf(v.w, bnS[c + 3], bnH[c + 3]), 0.f);
      }
      f16x4 h = {(f16)v.x, (f16)v.y, (f16)v.z, (f16)v.w};
      *(f16x4*)&Xs[row][c] = h;
    }
  } else {
    const f16* X = (const f16*)Xv;
#pragma unroll
    for (int p = 0; p < 8; p++) {
      int idx = p * 256 + t;          // 2048 f16x8 units
      int row = idx >> 4, c = (idx & 15) * 8;
      f16x8 v = {0, 0, 0, 0, 0, 0, 0, 0};
      if (m0 + row < n) v = *(const f16x8*)&X[(size_t)(m0 + row) * 128 + c];
      if (BN) {
#pragma unroll
        for (int j = 0; j < 8; j++) {
          float f = (float)v[j];
          f = fmaxf(fmaf(f, bnS[c + j], bnH[c + j]), 0.f);
          v[j] = (f16)f;
        }
      }
      *(f16x8*)&Xs[row][c] = v;
    }
  }
  // ---- stage W tile (fp16 global, pre-padded) ----
#pragma unroll
  for (int idx = t; idx < NCP * 16; idx += 256) {
    int row = idx >> 4, c = (idx & 15) * 8;
    *(f16x8*)&Ws[row][c] = *(const f16x8*)&Wt[(size_t)row * 128 + c];
  }
  __syncthreads();

  const int w = t >> 6, l = t & 63;
  const int lr = l & 15, lq = l >> 4;
  f32x4 acc[2][CB];
#pragma unroll
  for (int i = 0; i < 2; i++)
#pragma unroll
    for (int j = 0; j < CB; j++) acc[i][j] = (f32x4){0.f, 0.f, 0.f, 0.f};

#pragma unroll
  for (int kb = 0; kb < 4; kb++) {
    f16x8 xf0 = *(const f16x8*)&Xs[w * 32 + lr][kb * 32 + lq * 8];
    f16x8 xf1 = *(const f16x8*)&Xs[w * 32 + 16 + lr][kb * 32 + lq * 8];
#pragma unroll
    for (int cb = 0; cb < CB; cb++) {
      f16x8 wf = *(const f16x8*)&Ws[cb * 16 + lr][kb * 32 + lq * 8];
      acc[0][cb] = __builtin_amdgcn_mfma_f32_16x16x32_f16(wf, xf0, acc[0][cb], 0, 0, 0);
      acc[1][cb] = __builtin_amdgcn_mfma_f32_16x16x32_f16(wf, xf1, acc[1][cb], 0, 0, 0);
    }
  }
  // ---- store: H'[row][col] = dinv[row] * acc ----
#pragma unroll
  for (int rg = 0; rg < 2; rg++) {
    int row = m0 + w * 32 + rg * 16 + lr;
    if (row >= n) continue;
    float dv = dinv[row];
#pragma unroll
    for (int cb = 0; cb < CB; cb++) {
      int col = cb * 16 + lq * 4;
      f32x4 a = acc[rg][cb];
      f16x4 h = {(f16)(a[0] * dv), (f16)(a[1] * dv), (f16)(a[2] * dv),
                 (f16)(a[3] * dv)};
      *(f16x4*)&H[(size_t)row * NCP + col] = h;
    }
  }
}

// ============================ aggregation (gather, fp16 rows) ============================
// out[i][:] = dinv[i] * (H'[i][:] + sum_e H'[src[e]][:]) + bias
// Grid-stride, one wave per node, edge loop unrolled x8 for MLP; csr stream NT.
__global__ __launch_bounds__(256) void agg128h(const f16* __restrict__ H,
                                               const int* __restrict__ rp,
                                               const int* __restrict__ csr,
                                               const float* __restrict__ dinv,
                                               const float* __restrict__ bias,
                                               f16* __restrict__ out, int n) {
  const int l = threadIdx.x & 63;
  const int gw = (blockIdx.x * 256 + threadIdx.x) >> 6;
  const int nw = (gridDim.x * 256) >> 6;
  const float2 bs = *(const float2*)&bias[l * 2];
  for (int i = gw; i < n; i += nw) {
    float2 acc = __half22float2(*(const __half2*)&H[(size_t)i * 128 + l * 2]);
    int e = rp[i], e1 = rp[i + 1];
    for (; e + 8 <= e1; e += 8) {
      int s0 = __builtin_nontemporal_load(&csr[e + 0]);
      int s1 = __builtin_nontemporal_load(&csr[e + 1]);
      int s2 = __builtin_nontemporal_load(&csr[e + 2]);
      int s3 = __builtin_nontemporal_load(&csr[e + 3]);
      int s4 = __builtin_nontemporal_load(&csr[e + 4]);
      int s5 = __builtin_nontemporal_load(&csr[e + 5]);
      int s6 = __builtin_nontemporal_load(&csr[e + 6]);
      int s7 = __builtin_nontemporal_load(&csr[e + 7]);
      float2 v0 = __half22float2(*(const __half2*)&H[(size_t)s0 * 128 + l * 2]);
      float2 v1 = __half22float2(*(const __half2*)&H[(size_t)s1 * 128 + l * 2]);
      float2 v2 = __half22float2(*(const __half2*)&H[(size_t)s2 * 128 + l * 2]);
      float2 v3 = __half22float2(*(const __half2*)&H[(size_t)s3 * 128 + l * 2]);
      float2 v4 = __half22float2(*(const __half2*)&H[(size_t)s4 * 128 + l * 2]);
      float2 v5 = __half22float2(*(const __half2*)&H[(size_t)s5 * 128 + l * 2]);
      float2 v6 = __half22float2(*(const __half2*)&H[(size_t)s6 * 128 + l * 2]);
      float2 v7 = __half22float2(*(const __half2*)&H[(size_t)s7 * 128 + l * 2]);
      acc.x += v0.x + v1.x + v2.x + v3.x + v4.x + v5.x + v6.x + v7.x;
      acc.y += v0.y + v1.y + v2.y + v3.y + v4.y + v5.y + v6.y + v7.y;
    }
    for (; e < e1; e++) {
      int s0 = __builtin_nontemporal_load(&csr[e]);
      float2 v0 = __half22float2(*(const __half2*)&H[(size_t)s0 * 128 + l * 2]);
      acc.x += v0.x;
      acc.y += v0.y;
    }
    float dv = dinv[i];
    float ox = fmaf(acc.x, dv, bs.x);
    float oy = fmaf(acc.y, dv, bs.y);
    *(__half2*)&out[(size_t)i * 128 + l * 2] = __floats2half2_rn(ox, oy);
  }
}

// layer-3: H padded to 64 cols (128B line-aligned rows), store only first 40 (fp32).
__global__ __launch_bounds__(256) void agg64h(const f16* __restrict__ H,
                                              const int* __restrict__ rp,
                                              const int* __restrict__ csr,
                                              const float* __restrict__ dinv,
                                              const float* __restrict__ bias,
                                              float* __restrict__ out, int n) {
  const int l = threadIdx.x & 63;
  const int gw = (blockIdx.x * 256 + threadIdx.x) >> 6;
  const int nw = (gridDim.x * 256) >> 6;
  const float bs = (l < 40) ? bias[l] : 0.f;
  for (int i = gw; i < n; i += nw) {
    float acc = (float)H[(size_t)i * 64 + l];
    int e = rp[i], e1 = rp[i + 1];
    for (; e + 8 <= e1; e += 8) {
      int s0 = __builtin_nontemporal_load(&csr[e + 0]);
      int s1 = __builtin_nontemporal_load(&csr[e + 1]);
      int s2 = __builtin_nontemporal_load(&csr[e + 2]);
      int s3 = __builtin_nontemporal_load(&csr[e + 3]);
      int s4 = __builtin_nontemporal_load(&csr[e + 4]);
      int s5 = __builtin_nontemporal_load(&csr[e + 5]);
      int s6 = __builtin_nontemporal_load(&csr[e + 6]);
      int s7 = __builtin_nontemporal_load(&csr[e + 7]);
      float v0 = (float)H[(size_t)s0 * 64 + l];
      float v1 = (float)H[(size_t)s1 * 64 + l];
      float v2 = (float)H[(size_t)s2 * 64 + l];
      float v3 = (float)H[(size_t)s3 * 64 + l];
      float v4 = (float)H[(size_t)s4 * 64 + l];
      float v5 = (float)H[(size_t)s5 * 64 + l];
      float v6 = (float)H[(size_t)s6 * 64 + l];
      float v7 = (float)H[(size_t)s7 * 64 + l];
      acc += v0 + v1 + v2 + v3 + v4 + v5 + v6 + v7;
    }
    for (; e < e1; e++) {
      int s0 = __builtin_nontemporal_load(&csr[e]);
      acc += (float)H[(size_t)s0 * 64 + l];
    }
    if (l < 40) out[(size_t)i * 40 + l] = fmaf(acc, dinv[i], bs);
  }
}

// ============================ batchnorm stats (fp16 input) ============================
__global__ __launch_bounds__(256) void bn_stats_h(const f16* __restrict__ H, int n,
                                                  float* __restrict__ acc) {
  int t = threadIdx.x;
  int c2 = t & 63;   // half2 column
  int rg = t >> 6;   // 0..3
  float2 s = {0.f, 0.f}, s2 = {0.f, 0.f};
  for (int r = blockIdx.x * 4 + rg; r < n; r += gridDim.x * 4) {
    float2 v = __half22float2(*(const __half2*)&H[(size_t)r * 128 + c2 * 2]);
    s.x += v.x;
    s.y += v.y;
    s2.x = fmaf(v.x, v.x, s2.x);
    s2.y = fmaf(v.y, v.y, s2.y);
  }
  __shared__ float ls[4][128], ls2[4][128];
  ls[rg][c2 * 2] = s.x;
  ls[rg][c2 * 2 + 1] = s.y;
  ls2[rg][c2 * 2] = s2.x;
  ls2[rg][c2 * 2 + 1] = s2.y;
  __syncthreads();
  if (t < 128) {
    float a_ = ls[0][t] + ls[1][t] + ls[2][t] + ls[3][t];
    float b_ = ls2[0][t] + ls2[1][t] + ls2[2][t] + ls2[3][t];
    atomicAdd(&acc[t], a_);
    atomicAdd(&acc[128 + t], b_);
  }
}

// ============================ launch ============================
extern "C" void kernel_launch(void* const* d_in, const int* in_sizes, int n_in,
                              void* d_out, int out_size, void* d_ws, size_t ws_size,
                              hipStream_t stream) {
  const float* x = (const float*)d_in[0];
  const void* eb = d_in[1];
  const float* W1 = (const float*)d_in[2];
  const float* b1 = (const float*)d_in[3];
  const float* g1 = (const float*)d_in[4];
  const float* bt1 = (const float*)d_in[5];
  const float* W2 = (const float*)d_in[6];
  const float* b2 = (const float*)d_in[7];
  const float* g2 = (const float*)d_in[8];
  const float* bt2 = (const float*)d_in[9];
  const float* W3 = (const float*)d_in[10];
  const float* b3 = (const float*)d_in[11];

  const int n = in_sizes[0] / 128;
  const int E = in_sizes[1] / 2;
  const float inv_n = 1.0f / (float)n;

  char* w = (char*)d_ws;
  auto alloc = [&](size_t bytes) {
    void* p = (void*)w;
    w += (bytes + 255) & ~(size_t)255;
    return p;
  };
  f16* hA = (f16*)alloc((size_t)n * 128 * 2);
  f16* hB = (f16*)alloc((size_t)n * 128 * 2);
  int* csr = (int*)alloc((size_t)E * 4);
  float* dinv = (float*)alloc((size_t)n * 4);
  int* rp = (int*)alloc((size_t)(n + 1) * 4);
  int* bsum = (int*)alloc(512 * 4);
  f16* Wt1 = (f16*)alloc(128 * 128 * 2);
  f16* Wt2 = (f16*)alloc(128 * 128 * 2);
  f16* Wt3 = (f16*)alloc(64 * 128 * 2);
  // contiguous zero region:
  int* counts = (int*)alloc((size_t)n * 4);
  int* cursor = (int*)alloc((size_t)n * 4);
  float* bn_acc1 = (float*)alloc(256 * 4);
  float* bn_acc2 = (float*)alloc(256 * 4);
  int* flag = (int*)alloc(256);
  size_t zbytes = (char*)flag + 256 - (char*)counts;
  hipMemsetAsync(counts, 0, zbytes, stream);

  const int NB = (n + 255) / 256;

  prep_all<<<320, 128, 0, stream>>>(W1, W2, W3, Wt1, Wt2, Wt3);

  detect_k<<<512, 256, 0, stream>>>((const unsigned*)eb, E, flag);
  count_k<<<2048, 256, 0, stream>>>(eb, E, flag, counts);
  scan1_k<<<NB, 256, 0, stream>>>(counts, bsum, dinv, n);
  scanF_k<<<NB, 256, 0, stream>>>(counts, bsum, rp, n, E);
  fill_k<<<2048, 256, 0, stream>>>(eb, E, flag, rp, cursor, csr);

  const int GB = (n + 127) / 128;  // gemm blocks
  const int AGB = 4096;            // agg blocks (grid-stride, 16K waves)

  // layer 1
  gemm_mfma<128, false, true><<<GB, 256, 0, stream>>>(x, Wt1, nullptr, nullptr,
                                                      nullptr, inv_n, dinv, hA, n);
  agg128h<<<AGB, 256, 0, stream>>>(hA, rp, csr, dinv, b1, hB, n);
  bn_stats_h<<<1024, 256, 0, stream>>>(hB, n, bn_acc1);
  // layer 2 (BN scale/shift computed inside GEMM from raw sums)
  gemm_mfma<128, true, false><<<GB, 256, 0, stream>>>(hB, Wt2, bn_acc1, g1, bt1,
                                                      inv_n, dinv, hA, n);
  agg128h<<<AGB, 256, 0, stream>>>(hA, rp, csr, dinv, b2, hB, n);
  bn_stats_h<<<1024, 256, 0, stream>>>(hB, n, bn_acc2);
  // layer 3 (H padded to 64 cols for line-aligned gathers)
  gemm_mfma<64, true, false><<<GB, 256, 0, stream>>>(hB, Wt3, bn_acc2, g2, bt2,
                                                     inv_n, dinv, hA, n);
  agg64h<<<AGB, 256, 0, stream>>>(hA, rp, csr, dinv, b3, (float*)d_out, n);
}

// Round 6
// 677.861 us; speedup vs baseline: 1.0484x; 1.0484x over previous
//
#include <hip/hip_runtime.h>
#include <hip/hip_fp16.h>
#include <cstdint>

#define BN_EPS 1e-5f

typedef _Float16 f16;
typedef _Float16 f16x8 __attribute__((ext_vector_type(8)));
typedef _Float16 f16x4 __attribute__((ext_vector_type(4)));
typedef float f32x4 __attribute__((ext_vector_type(4)));

// ============================ edge preprocessing ============================

// Detect int64 vs int32 edge buffer (JAX may canonicalize int64 -> int32).
__global__ __launch_bounds__(256) void detect_k(const unsigned* __restrict__ eb,
                                                int E, int* __restrict__ flag) {
  int nz = 0;
  for (long long i = (long long)blockIdx.x * 256 + threadIdx.x; i < E;
       i += (long long)gridDim.x * 256)
    nz |= (eb[2 * i + 1] != 0u);
  if (__any(nz) && (threadIdx.x & 63) == 0) atomicOr(flag, 1);
}

__device__ __forceinline__ void load_edge(const void* eb, int E, bool w64,
                                          int e, int& s, int& d) {
  if (w64) {
    const long long* p = (const long long*)eb;
    s = (int)p[e];
    d = (int)p[E + e];
  } else {
    const int* p = (const int*)eb;
    s = p[e];
    d = p[E + e];
  }
}

__global__ __launch_bounds__(256) void count_k(const void* __restrict__ eb, int E,
                                               const int* __restrict__ flag,
                                               int* __restrict__ counts) {
  bool w64 = (*flag == 0);
  for (int e = blockIdx.x * 256 + threadIdx.x; e < E; e += gridDim.x * 256) {
    int s, d;
    load_edge(eb, E, w64, e, s, d);
    atomicAdd(&counts[d], 1);
  }
}

// --- scan pass 1: per-block sums (dinv fused) ---
__global__ __launch_bounds__(256) void scan1_k(const int* __restrict__ counts,
                                               int* __restrict__ bsum,
                                               float* __restrict__ dinv, int n) {
  __shared__ int ls[256];
  int t = threadIdx.x;
  int i = blockIdx.x * 256 + t;
  int c = (i < n) ? counts[i] : 0;
  if (i < n) dinv[i] = rsqrtf((float)(c + 1));  // +1 self-loop
  ls[t] = c;
  __syncthreads();
  for (int off = 128; off > 0; off >>= 1) {
    if (t < off) ls[t] += ls[t + off];
    __syncthreads();
  }
  if (t == 0) bsum[blockIdx.x] = ls[0];
}

// --- scan pass 2: each block derives its own prefix from bsum (NB <= 512) ---
__global__ __launch_bounds__(256) void scanF_k(const int* __restrict__ counts,
                                               const int* __restrict__ bsum,
                                               int* __restrict__ rp, int n, int E) {
  __shared__ int sa[256], sb[256];
  __shared__ int red[256];
  int t = threadIdx.x;
  int pacc = 0;
  for (int j = t; j < (int)blockIdx.x; j += 256) pacc += bsum[j];
  red[t] = pacc;
  __syncthreads();
  for (int off = 128; off > 0; off >>= 1) {
    if (t < off) red[t] += red[t + off];
    __syncthreads();
  }
  int off0 = red[0];
  __syncthreads();

  int i = blockIdx.x * 256 + t;
  int v = (i < n) ? counts[i] : 0;
  sa[t] = v;
  __syncthreads();
  int* src = sa;
  int* dst = sb;
  for (int off = 1; off < 256; off <<= 1) {
    int val = src[t] + (t >= off ? src[t - off] : 0);
    dst[t] = val;
    __syncthreads();
    int* tmp = src; src = dst; dst = tmp;
  }
  int incl = src[t];
  if (i < n) rp[i] = off0 + incl - v;
  if (i == n - 1) rp[n] = E;
}

// packed CSR entry: {src, norm_bits} -> single 8B store per edge (proven fastest
// scatter form: 4B-entry stores defeated L2 write-merging, 2x slower measured)
__global__ __launch_bounds__(256) void fill_k(const void* __restrict__ eb, int E,
                                              const int* __restrict__ flag,
                                              const int* __restrict__ rp,
                                              int* __restrict__ cursor,
                                              const float* __restrict__ dinv,
                                              int2* __restrict__ csr) {
  bool w64 = (*flag == 0);
  for (int e = blockIdx.x * 256 + threadIdx.x; e < E; e += gridDim.x * 256) {
    int s, d;
    load_edge(eb, E, w64, e, s, d);
    int pos = atomicAdd(&cursor[d], 1);
    int2 ent;
    ent.x = s;
    ent.y = __float_as_int(dinv[s] * dinv[d]);
    csr[rp[d] + pos] = ent;
  }
}

// ============================ W prep: transpose + fp16 (single launch) ============
// Wt[nc][k] = (f16) W[k][nc]; Wt3 zero-padded to 64 rows.
__global__ void prep_all(const float* __restrict__ W1, const float* __restrict__ W2,
                         const float* __restrict__ W3, f16* __restrict__ Wt1,
                         f16* __restrict__ Wt2, f16* __restrict__ Wt3) {
  int b = blockIdx.x, k = threadIdx.x;  // 128 threads
  if (b < 128) {
    Wt1[(size_t)b * 128 + k] = (f16)W1[(size_t)k * 128 + b];
  } else if (b < 256) {
    int nc = b - 128;
    Wt2[(size_t)nc * 128 + k] = (f16)W2[(size_t)k * 128 + nc];
  } else {
    int nc = b - 256;  // 0..63
    Wt3[(size_t)nc * 128 + k] = (nc < 40) ? (f16)W3[(size_t)k * 40 + nc] : (f16)0.f;
  }
}

// ============================ GEMM (MFMA f16) ============================
// H[n][NCP] = act(X)[n][128] @ W[128][NCP]
// act = BN scale/shift + ReLU if BN (scale/shift derived in-kernel from raw sums).
// 256 thr = 4 waves, tile 128 rows; operand-swapped mfma -> 4 consecutive cols/lane.
template <int NCP, bool BN, bool F32IN>
__global__ __launch_bounds__(256) void gemm_mfma(const void* __restrict__ Xv,
                                                 const f16* __restrict__ Wt,
                                                 const float* __restrict__ bn_acc,
                                                 const float* __restrict__ g,
                                                 const float* __restrict__ bt,
                                                 float inv_n,
                                                 f16* __restrict__ H, int n) {
  constexpr int CB = NCP / 16;
  __shared__ f16 Xs[128][136];
  __shared__ f16 Ws[NCP][136];
  __shared__ float bnS[128], bnH[128];
  const int t = threadIdx.x;
  const int m0 = blockIdx.x * 128;

  if (BN) {
    if (t < 128) {
      float mean = bn_acc[t] * inv_n;
      float var = bn_acc[128 + t] * inv_n - mean * mean;
      float sc = g[t] * rsqrtf(var + BN_EPS);
      bnS[t] = sc;
      bnH[t] = fmaf(-mean, sc, bt[t]);
    }
    __syncthreads();
  }

  // ---- stage X tile (fp32 or fp16 global -> fp16 LDS, BN+ReLU fused) ----
  if constexpr (F32IN) {
    const float* X = (const float*)Xv;
#pragma unroll
    for (int p = 0; p < 16; p++) {
      int idx = p * 256 + t;          // 4096 float4 units
      int row = idx >> 5, c = (idx & 31) * 4;
      float4 v = make_float4(0.f, 0.f, 0.f, 0.f);
      if (m0 + row < n) v = *(const float4*)&X[(size_t)(m0 + row) * 128 + c];
      if (BN) {
        v.x = fmaxf(fmaf(v.x, bnS[c + 0], bnH[c + 0]), 0.f);
        v.y = fmaxf(fmaf(v.y, bnS[c + 1], bnH[c + 1]), 0.f);
        v.z = fmaxf(fmaf(v.z, bnS[c + 2], bnH[c + 2]), 0.f);
        v.w = fmaxf(fmaf(v.w, bnS[c + 3], bnH[c + 3]), 0.f);
      }
      f16x4 h = {(f16)v.x, (f16)v.y, (f16)v.z, (f16)v.w};
      *(f16x4*)&Xs[row][c] = h;
    }
  } else {
    const f16* X = (const f16*)Xv;
#pragma unroll
    for (int p = 0; p < 8; p++) {
      int idx = p * 256 + t;          // 2048 f16x8 units
      int row = idx >> 4, c = (idx & 15) * 8;
      f16x8 v = {0, 0, 0, 0, 0, 0, 0, 0};
      if (m0 + row < n) v = *(const f16x8*)&X[(size_t)(m0 + row) * 128 + c];
      if (BN) {
#pragma unroll
        for (int j = 0; j < 8; j++) {
          float f = (float)v[j];
          f = fmaxf(fmaf(f, bnS[c + j], bnH[c + j]), 0.f);
          v[j] = (f16)f;
        }
      }
      *(f16x8*)&Xs[row][c] = v;
    }
  }
  // ---- stage W tile (fp16 global, pre-padded) ----
#pragma unroll
  for (int idx = t; idx < NCP * 16; idx += 256) {
    int row = idx >> 4, c = (idx & 15) * 8;
    *(f16x8*)&Ws[row][c] = *(const f16x8*)&Wt[(size_t)row * 128 + c];
  }
  __syncthreads();

  const int w = t >> 6, l = t & 63;
  const int lr = l & 15, lq = l >> 4;
  f32x4 acc[2][CB];
#pragma unroll
  for (int i = 0; i < 2; i++)
#pragma unroll
    for (int j = 0; j < CB; j++) acc[i][j] = (f32x4){0.f, 0.f, 0.f, 0.f};

#pragma unroll
  for (int kb = 0; kb < 4; kb++) {
    f16x8 xf0 = *(const f16x8*)&Xs[w * 32 + lr][kb * 32 + lq * 8];
    f16x8 xf1 = *(const f16x8*)&Xs[w * 32 + 16 + lr][kb * 32 + lq * 8];
#pragma unroll
    for (int cb = 0; cb < CB; cb++) {
      f16x8 wf = *(const f16x8*)&Ws[cb * 16 + lr][kb * 32 + lq * 8];
      acc[0][cb] = __builtin_amdgcn_mfma_f32_16x16x32_f16(wf, xf0, acc[0][cb], 0, 0, 0);
      acc[1][cb] = __builtin_amdgcn_mfma_f32_16x16x32_f16(wf, xf1, acc[1][cb], 0, 0, 0);
    }
  }
  // ---- store: lane holds H[row = base + (l&15)][col = cb*16 + lq*4 .. +3] ----
#pragma unroll
  for (int rg = 0; rg < 2; rg++) {
    int row = m0 + w * 32 + rg * 16 + lr;
    if (row >= n) continue;
#pragma unroll
    for (int cb = 0; cb < CB; cb++) {
      int col = cb * 16 + lq * 4;
      f32x4 a = acc[rg][cb];
      f16x4 h = {(f16)a[0], (f16)a[1], (f16)a[2], (f16)a[3]};
      *(f16x4*)&H[(size_t)row * NCP + col] = h;
    }
  }
}

// ============================ aggregation (gather, fp16 rows) ============================
// out[i][:] = bias + dinv[i]^2 * H[i][:] + sum_e norm[e] * H[src[e]][:]
// Grid-stride, one wave per node, edge loop unrolled x8 for MLP; NT csr loads.
__device__ __forceinline__ void unpack(long long p, int& s, float& w) {
  s = (int)(unsigned)(p & 0xffffffffll);
  w = __int_as_float((int)(p >> 32));
}

__global__ __launch_bounds__(256) void agg128h(const f16* __restrict__ H,
                                               const int* __restrict__ rp,
                                               const long long* __restrict__ csr,
                                               const float* __restrict__ dinv,
                                               const float* __restrict__ bias,
                                               f16* __restrict__ out, int n) {
  const int l = threadIdx.x & 63;
  const int gw = (blockIdx.x * 256 + threadIdx.x) >> 6;
  const int nw = (gridDim.x * 256) >> 6;
  const float2 bs = *(const float2*)&bias[l * 2];
  for (int i = gw; i < n; i += nw) {
    float di = dinv[i];
    float dii = di * di;
    float2 hf = __half22float2(*(const __half2*)&H[(size_t)i * 128 + l * 2]);
    float2 acc;
    acc.x = fmaf(hf.x, dii, bs.x);
    acc.y = fmaf(hf.y, dii, bs.y);
    int e = rp[i], e1 = rp[i + 1];
    for (; e + 8 <= e1; e += 8) {
      int s0, s1, s2, s3, s4, s5, s6, s7;
      float w0, w1, w2, w3, w4, w5, w6, w7;
      unpack(__builtin_nontemporal_load(&csr[e + 0]), s0, w0);
      unpack(__builtin_nontemporal_load(&csr[e + 1]), s1, w1);
      unpack(__builtin_nontemporal_load(&csr[e + 2]), s2, w2);
      unpack(__builtin_nontemporal_load(&csr[e + 3]), s3, w3);
      unpack(__builtin_nontemporal_load(&csr[e + 4]), s4, w4);
      unpack(__builtin_nontemporal_load(&csr[e + 5]), s5, w5);
      unpack(__builtin_nontemporal_load(&csr[e + 6]), s6, w6);
      unpack(__builtin_nontemporal_load(&csr[e + 7]), s7, w7);
      float2 v0 = __half22float2(*(const __half2*)&H[(size_t)s0 * 128 + l * 2]);
      float2 v1 = __half22float2(*(const __half2*)&H[(size_t)s1 * 128 + l * 2]);
      float2 v2 = __half22float2(*(const __half2*)&H[(size_t)s2 * 128 + l * 2]);
      float2 v3 = __half22float2(*(const __half2*)&H[(size_t)s3 * 128 + l * 2]);
      float2 v4 = __half22float2(*(const __half2*)&H[(size_t)s4 * 128 + l * 2]);
      float2 v5 = __half22float2(*(const __half2*)&H[(size_t)s5 * 128 + l * 2]);
      float2 v6 = __half22float2(*(const __half2*)&H[(size_t)s6 * 128 + l * 2]);
      float2 v7 = __half22float2(*(const __half2*)&H[(size_t)s7 * 128 + l * 2]);
      acc.x = fmaf(v0.x, w0, acc.x); acc.y = fmaf(v0.y, w0, acc.y);
      acc.x = fmaf(v1.x, w1, acc.x); acc.y = fmaf(v1.y, w1, acc.y);
      acc.x = fmaf(v2.x, w2, acc.x); acc.y = fmaf(v2.y, w2, acc.y);
      acc.x = fmaf(v3.x, w3, acc.x); acc.y = fmaf(v3.y, w3, acc.y);
      acc.x = fmaf(v4.x, w4, acc.x); acc.y = fmaf(v4.y, w4, acc.y);
      acc.x = fmaf(v5.x, w5, acc.x); acc.y = fmaf(v5.y, w5, acc.y);
      acc.x = fmaf(v6.x, w6, acc.x); acc.y = fmaf(v6.y, w6, acc.y);
      acc.x = fmaf(v7.x, w7, acc.x); acc.y = fmaf(v7.y, w7, acc.y);
    }
    for (; e < e1; e++) {
      int s0; float w0;
      unpack(__builtin_nontemporal_load(&csr[e]), s0, w0);
      float2 v0 = __half22float2(*(const __half2*)&H[(size_t)s0 * 128 + l * 2]);
      acc.x = fmaf(v0.x, w0, acc.x);
      acc.y = fmaf(v0.y, w0, acc.y);
    }
    *(__half2*)&out[(size_t)i * 128 + l * 2] = __floats2half2_rn(acc.x, acc.y);
  }
}

// layer-3: H padded to 64 cols (128B line-aligned rows), store only first 40 (fp32).
__global__ __launch_bounds__(256) void agg64h(const f16* __restrict__ H,
                                              const int* __restrict__ rp,
                                              const long long* __restrict__ csr,
                                              const float* __restrict__ dinv,
                                              const float* __restrict__ bias,
                                              float* __restrict__ out, int n) {
  const int l = threadIdx.x & 63;
  const int gw = (blockIdx.x * 256 + threadIdx.x) >> 6;
  const int nw = (gridDim.x * 256) >> 6;
  const float bs = (l < 40) ? bias[l] : 0.f;
  for (int i = gw; i < n; i += nw) {
    float di = dinv[i];
    float acc = fmaf((float)H[(size_t)i * 64 + l], di * di, bs);
    int e = rp[i], e1 = rp[i + 1];
    for (; e + 8 <= e1; e += 8) {
      int s0, s1, s2, s3, s4, s5, s6, s7;
      float w0, w1, w2, w3, w4, w5, w6, w7;
      unpack(__builtin_nontemporal_load(&csr[e + 0]), s0, w0);
      unpack(__builtin_nontemporal_load(&csr[e + 1]), s1, w1);
      unpack(__builtin_nontemporal_load(&csr[e + 2]), s2, w2);
      unpack(__builtin_nontemporal_load(&csr[e + 3]), s3, w3);
      unpack(__builtin_nontemporal_load(&csr[e + 4]), s4, w4);
      unpack(__builtin_nontemporal_load(&csr[e + 5]), s5, w5);
      unpack(__builtin_nontemporal_load(&csr[e + 6]), s6, w6);
      unpack(__builtin_nontemporal_load(&csr[e + 7]), s7, w7);
      float v0 = (float)H[(size_t)s0 * 64 + l];
      float v1 = (float)H[(size_t)s1 * 64 + l];
      float v2 = (float)H[(size_t)s2 * 64 + l];
      float v3 = (float)H[(size_t)s3 * 64 + l];
      float v4 = (float)H[(size_t)s4 * 64 + l];
      float v5 = (float)H[(size_t)s5 * 64 + l];
      float v6 = (float)H[(size_t)s6 * 64 + l];
      float v7 = (float)H[(size_t)s7 * 64 + l];
      acc = fmaf(v0, w0, acc); acc = fmaf(v1, w1, acc);
      acc = fmaf(v2, w2, acc); acc = fmaf(v3, w3, acc);
      acc = fmaf(v4, w4, acc); acc = fmaf(v5, w5, acc);
      acc = fmaf(v6, w6, acc); acc = fmaf(v7, w7, acc);
    }
    for (; e < e1; e++) {
      int s0; float w0;
      unpack(__builtin_nontemporal_load(&csr[e]), s0, w0);
      acc = fmaf((float)H[(size_t)s0 * 64 + l], w0, acc);
    }
    if (l < 40) out[(size_t)i * 40 + l] = acc;
  }
}

// ============================ batchnorm stats (fp16 input) ============================
__global__ __launch_bounds__(256) void bn_stats_h(const f16* __restrict__ H, int n,
                                                  float* __restrict__ acc) {
  int t = threadIdx.x;
  int c2 = t & 63;   // half2 column
  int rg = t >> 6;   // 0..3
  float2 s = {0.f, 0.f}, s2 = {0.f, 0.f};
  for (int r = blockIdx.x * 4 + rg; r < n; r += gridDim.x * 4) {
    float2 v = __half22float2(*(const __half2*)&H[(size_t)r * 128 + c2 * 2]);
    s.x += v.x;
    s.y += v.y;
    s2.x = fmaf(v.x, v.x, s2.x);
    s2.y = fmaf(v.y, v.y, s2.y);
  }
  __shared__ float ls[4][128], ls2[4][128];
  ls[rg][c2 * 2] = s.x;
  ls[rg][c2 * 2 + 1] = s.y;
  ls2[rg][c2 * 2] = s2.x;
  ls2[rg][c2 * 2 + 1] = s2.y;
  __syncthreads();
  if (t < 128) {
    float a_ = ls[0][t] + ls[1][t] + ls[2][t] + ls[3][t];
    float b_ = ls2[0][t] + ls2[1][t] + ls2[2][t] + ls2[3][t];
    atomicAdd(&acc[t], a_);
    atomicAdd(&acc[128 + t], b_);
  }
}

// ============================ launch ============================
extern "C" void kernel_launch(void* const* d_in, const int* in_sizes, int n_in,
                              void* d_out, int out_size, void* d_ws, size_t ws_size,
                              hipStream_t stream) {
  const float* x = (const float*)d_in[0];
  const void* eb = d_in[1];
  const float* W1 = (const float*)d_in[2];
  const float* b1 = (const float*)d_in[3];
  const float* g1 = (const float*)d_in[4];
  const float* bt1 = (const float*)d_in[5];
  const float* W2 = (const float*)d_in[6];
  const float* b2 = (const float*)d_in[7];
  const float* g2 = (const float*)d_in[8];
  const float* bt2 = (const float*)d_in[9];
  const float* W3 = (const float*)d_in[10];
  const float* b3 = (const float*)d_in[11];

  const int n = in_sizes[0] / 128;
  const int E = in_sizes[1] / 2;
  const float inv_n = 1.0f / (float)n;

  char* w = (char*)d_ws;
  auto alloc = [&](size_t bytes) {
    void* p = (void*)w;
    w += (bytes + 255) & ~(size_t)255;
    return p;
  };
  f16* hA = (f16*)alloc((size_t)n * 128 * 2);
  f16* hB = (f16*)alloc((size_t)n * 128 * 2);
  int2* csr = (int2*)alloc((size_t)E * 8);
  float* dinv = (float*)alloc((size_t)n * 4);
  int* rp = (int*)alloc((size_t)(n + 1) * 4);
  int* bsum = (int*)alloc(512 * 4);
  f16* Wt1 = (f16*)alloc(128 * 128 * 2);
  f16* Wt2 = (f16*)alloc(128 * 128 * 2);
  f16* Wt3 = (f16*)alloc(64 * 128 * 2);
  // contiguous zero region:
  int* counts = (int*)alloc((size_t)n * 4);
  int* cursor = (int*)alloc((size_t)n * 4);
  float* bn_acc1 = (float*)alloc(256 * 4);
  float* bn_acc2 = (float*)alloc(256 * 4);
  int* flag = (int*)alloc(256);
  size_t zbytes = (char*)flag + 256 - (char*)counts;
  hipMemsetAsync(counts, 0, zbytes, stream);

  const int NB = (n + 255) / 256;

  prep_all<<<320, 128, 0, stream>>>(W1, W2, W3, Wt1, Wt2, Wt3);

  detect_k<<<512, 256, 0, stream>>>((const unsigned*)eb, E, flag);
  count_k<<<2048, 256, 0, stream>>>(eb, E, flag, counts);
  scan1_k<<<NB, 256, 0, stream>>>(counts, bsum, dinv, n);
  scanF_k<<<NB, 256, 0, stream>>>(counts, bsum, rp, n, E);
  fill_k<<<2048, 256, 0, stream>>>(eb, E, flag, rp, cursor, dinv, csr);

  const int GB = (n + 127) / 128;  // gemm blocks
  const int AGB = 4096;            // agg blocks (grid-stride, 16K waves)

  // layer 1
  gemm_mfma<128, false, true><<<GB, 256, 0, stream>>>(x, Wt1, nullptr, nullptr,
                                                      nullptr, inv_n, hA, n);
  agg128h<<<AGB, 256, 0, stream>>>(hA, rp, (const long long*)csr, dinv, b1, hB, n);
  bn_stats_h<<<1024, 256, 0, stream>>>(hB, n, bn_acc1);
  // layer 2 (BN scale/shift computed inside GEMM from raw sums)
  gemm_mfma<128, true, false><<<GB, 256, 0, stream>>>(hB, Wt2, bn_acc1, g1, bt1,
                                                      inv_n, hA, n);
  agg128h<<<AGB, 256, 0, stream>>>(hA, rp, (const long long*)csr, dinv, b2, hB, n);
  bn_stats_h<<<1024, 256, 0, stream>>>(hB, n, bn_acc2);
  // layer 3 (H padded to 64 cols for line-aligned gathers)
  gemm_mfma<64, true, false><<<GB, 256, 0, stream>>>(hB, Wt3, bn_acc2, g2, bt2,
                                                     inv_n, hA, n);
  agg64h<<<AGB, 256, 0, stream>>>(hA, rp, (const long long*)csr, dinv, b3,
                                  (float*)d_out, n);
}

// Round 7
// 565.645 us; speedup vs baseline: 1.2564x; 1.1984x over previous
//
#include <hip/hip_runtime.h>
#include <hip/hip_fp16.h>
#include <cstdint>

#define BN_EPS 1e-5f

typedef _Float16 f16;
typedef _Float16 f16x8 __attribute__((ext_vector_type(8)));
typedef _Float16 f16x4 __attribute__((ext_vector_type(4)));
typedef float f32x4 __attribute__((ext_vector_type(4)));

// ============================ edge preprocessing ============================

// Detect int64 vs int32 edge buffer. int64 layout (values < 2^31) -> ALL odd
// 32-bit words are zero. int32 random indices -> a nonzero odd word appears
// within the first few. One block scans the first 2048 odd words.
__global__ void detect_k(const unsigned* __restrict__ eb, int E,
                         int* __restrict__ flag) {
  int t = threadIdx.x;  // 256
  int cov = min(2048, E);
  int nz = 0;
  for (int k = t; k < cov; k += 256) nz |= (eb[2 * k + 1] != 0u);
  if (nz) atomicOr(flag, 1);
}

__device__ __forceinline__ void load_edge(const void* eb, int E, bool w64,
                                          int e, int& s, int& d) {
  if (w64) {
    const long long* p = (const long long*)eb;
    s = (int)p[e];
    d = (int)p[E + e];
  } else {
    const int* p = (const int*)eb;
    s = p[e];
    d = p[E + e];
  }
}

__global__ __launch_bounds__(256) void count_k(const void* __restrict__ eb, int E,
                                               const int* __restrict__ flag,
                                               int* __restrict__ counts) {
  bool w64 = (*flag == 0);
  for (int e = blockIdx.x * 256 + threadIdx.x; e < E; e += gridDim.x * 256) {
    int s, d;
    load_edge(eb, E, w64, e, s, d);
    atomicAdd(&counts[d], 1);
  }
}

// --- scan pass 1: per-block sums (dinv fused) ---
__global__ __launch_bounds__(256) void scan1_k(const int* __restrict__ counts,
                                               int* __restrict__ bsum,
                                               float* __restrict__ dinv, int n) {
  __shared__ int ls[256];
  int t = threadIdx.x;
  int i = blockIdx.x * 256 + t;
  int c = (i < n) ? counts[i] : 0;
  if (i < n) dinv[i] = rsqrtf((float)(c + 1));  // +1 self-loop
  ls[t] = c;
  __syncthreads();
  for (int off = 128; off > 0; off >>= 1) {
    if (t < off) ls[t] += ls[t + off];
    __syncthreads();
  }
  if (t == 0) bsum[blockIdx.x] = ls[0];
}

// --- scan pass 2: each block derives its own prefix from bsum (NB <= 512) ---
__global__ __launch_bounds__(256) void scanF_k(const int* __restrict__ counts,
                                               const int* __restrict__ bsum,
                                               int* __restrict__ rp, int n, int E) {
  __shared__ int sa[256], sb[256];
  __shared__ int red[256];
  int t = threadIdx.x;
  int pacc = 0;
  for (int j = t; j < (int)blockIdx.x; j += 256) pacc += bsum[j];
  red[t] = pacc;
  __syncthreads();
  for (int off = 128; off > 0; off >>= 1) {
    if (t < off) red[t] += red[t + off];
    __syncthreads();
  }
  int off0 = red[0];
  __syncthreads();

  int i = blockIdx.x * 256 + t;
  int v = (i < n) ? counts[i] : 0;
  sa[t] = v;
  __syncthreads();
  int* src = sa;
  int* dst = sb;
  for (int off = 1; off < 256; off <<= 1) {
    int val = src[t] + (t >= off ? src[t - off] : 0);
    dst[t] = val;
    __syncthreads();
    int* tmp = src; src = dst; dst = tmp;
  }
  int incl = src[t];
  if (i < n) rp[i] = off0 + incl - v;
  if (i == n - 1) rp[n] = E;
}

// packed CSR entry: {src, norm_bits} -> single 8B store per edge (proven fastest
// scatter form: 4B-entry stores defeated L2 write-merging, 2x slower measured)
__global__ __launch_bounds__(256) void fill_k(const void* __restrict__ eb, int E,
                                              const int* __restrict__ flag,
                                              const int* __restrict__ rp,
                                              int* __restrict__ cursor,
                                              const float* __restrict__ dinv,
                                              int2* __restrict__ csr) {
  bool w64 = (*flag == 0);
  for (int e = blockIdx.x * 256 + threadIdx.x; e < E; e += gridDim.x * 256) {
    int s, d;
    load_edge(eb, E, w64, e, s, d);
    int pos = atomicAdd(&cursor[d], 1);
    int2 ent;
    ent.x = s;
    ent.y = __float_as_int(dinv[s] * dinv[d]);
    csr[rp[d] + pos] = ent;
  }
}

// ============================ W prep: transpose + fp16 (single launch) ============
// Wt[nc][k] = (f16) W[k][nc]; Wt3 zero-padded to 64 rows.
__global__ void prep_all(const float* __restrict__ W1, const float* __restrict__ W2,
                         const float* __restrict__ W3, f16* __restrict__ Wt1,
                         f16* __restrict__ Wt2, f16* __restrict__ Wt3) {
  int b = blockIdx.x, k = threadIdx.x;  // 128 threads
  if (b < 128) {
    Wt1[(size_t)b * 128 + k] = (f16)W1[(size_t)k * 128 + b];
  } else if (b < 256) {
    int nc = b - 128;
    Wt2[(size_t)nc * 128 + k] = (f16)W2[(size_t)k * 128 + nc];
  } else {
    int nc = b - 256;  // 0..63
    Wt3[(size_t)nc * 128 + k] = (nc < 40) ? (f16)W3[(size_t)k * 40 + nc] : (f16)0.f;
  }
}

// ============================ GEMM (MFMA f16) ============================
// H[n][NCP] = act(X)[n][128] @ W[128][NCP]
// act = BN scale/shift + ReLU if BN (scale/shift derived in-kernel from raw sums).
// 256 thr = 4 waves, tile 128 rows; operand-swapped mfma -> 4 consecutive cols/lane.
template <int NCP, bool BN, bool F32IN>
__global__ __launch_bounds__(256) void gemm_mfma(const void* __restrict__ Xv,
                                                 const f16* __restrict__ Wt,
                                                 const float* __restrict__ bn_acc,
                                                 const float* __restrict__ g,
                                                 const float* __restrict__ bt,
                                                 float inv_n,
                                                 f16* __restrict__ H, int n) {
  constexpr int CB = NCP / 16;
  __shared__ f16 Xs[128][136];
  __shared__ f16 Ws[NCP][136];
  __shared__ float bnS[128], bnH[128];
  const int t = threadIdx.x;
  const int m0 = blockIdx.x * 128;

  if (BN) {
    if (t < 128) {
      float mean = bn_acc[t] * inv_n;
      float var = bn_acc[128 + t] * inv_n - mean * mean;
      float sc = g[t] * rsqrtf(var + BN_EPS);
      bnS[t] = sc;
      bnH[t] = fmaf(-mean, sc, bt[t]);
    }
    __syncthreads();
  }

  // ---- stage X tile (fp32 or fp16 global -> fp16 LDS, BN+ReLU fused) ----
  if constexpr (F32IN) {
    const float* X = (const float*)Xv;
#pragma unroll
    for (int p = 0; p < 16; p++) {
      int idx = p * 256 + t;          // 4096 float4 units
      int row = idx >> 5, c = (idx & 31) * 4;
      float4 v = make_float4(0.f, 0.f, 0.f, 0.f);
      if (m0 + row < n) v = *(const float4*)&X[(size_t)(m0 + row) * 128 + c];
      if (BN) {
        v.x = fmaxf(fmaf(v.x, bnS[c + 0], bnH[c + 0]), 0.f);
        v.y = fmaxf(fmaf(v.y, bnS[c + 1], bnH[c + 1]), 0.f);
        v.z = fmaxf(fmaf(v.z, bnS[c + 2], bnH[c + 2]), 0.f);
        v.w = fmaxf(fmaf(v.w, bnS[c + 3], bnH[c + 3]), 0.f);
      }
      f16x4 h = {(f16)v.x, (f16)v.y, (f16)v.z, (f16)v.w};
      *(f16x4*)&Xs[row][c] = h;
    }
  } else {
    const f16* X = (const f16*)Xv;
#pragma unroll
    for (int p = 0; p < 8; p++) {
      int idx = p * 256 + t;          // 2048 f16x8 units
      int row = idx >> 4, c = (idx & 15) * 8;
      f16x8 v = {0, 0, 0, 0, 0, 0, 0, 0};
      if (m0 + row < n) v = *(const f16x8*)&X[(size_t)(m0 + row) * 128 + c];
      if (BN) {
#pragma unroll
        for (int j = 0; j < 8; j++) {
          float f = (float)v[j];
          f = fmaxf(fmaf(f, bnS[c + j], bnH[c + j]), 0.f);
          v[j] = (f16)f;
        }
      }
      *(f16x8*)&Xs[row][c] = v;
    }
  }
  // ---- stage W tile (fp16 global, pre-padded) ----
#pragma unroll
  for (int idx = t; idx < NCP * 16; idx += 256) {
    int row = idx >> 4, c = (idx & 15) * 8;
    *(f16x8*)&Ws[row][c] = *(const f16x8*)&Wt[(size_t)row * 128 + c];
  }
  __syncthreads();

  const int w = t >> 6, l = t & 63;
  const int lr = l & 15, lq = l >> 4;
  f32x4 acc[2][CB];
#pragma unroll
  for (int i = 0; i < 2; i++)
#pragma unroll
    for (int j = 0; j < CB; j++) acc[i][j] = (f32x4){0.f, 0.f, 0.f, 0.f};

#pragma unroll
  for (int kb = 0; kb < 4; kb++) {
    f16x8 xf0 = *(const f16x8*)&Xs[w * 32 + lr][kb * 32 + lq * 8];
    f16x8 xf1 = *(const f16x8*)&Xs[w * 32 + 16 + lr][kb * 32 + lq * 8];
#pragma unroll
    for (int cb = 0; cb < CB; cb++) {
      f16x8 wf = *(const f16x8*)&Ws[cb * 16 + lr][kb * 32 + lq * 8];
      acc[0][cb] = __builtin_amdgcn_mfma_f32_16x16x32_f16(wf, xf0, acc[0][cb], 0, 0, 0);
      acc[1][cb] = __builtin_amdgcn_mfma_f32_16x16x32_f16(wf, xf1, acc[1][cb], 0, 0, 0);
    }
  }
  // ---- store: lane holds H[row = base + (l&15)][col = cb*16 + lq*4 .. +3] ----
#pragma unroll
  for (int rg = 0; rg < 2; rg++) {
    int row = m0 + w * 32 + rg * 16 + lr;
    if (row >= n) continue;
#pragma unroll
    for (int cb = 0; cb < CB; cb++) {
      int col = cb * 16 + lq * 4;
      f32x4 a = acc[rg][cb];
      f16x4 h = {(f16)a[0], (f16)a[1], (f16)a[2], (f16)a[3]};
      *(f16x4*)&H[(size_t)row * NCP + col] = h;
    }
  }
}

// ============================ aggregation (gather, fp16 rows) ============================
// out[i][:] = bias + dinv[i]^2 * H[i][:] + sum_e norm[e] * H[src[e]][:]
// Paired half-wave scheme: nodes (2p, 2p+1) on lane halves; each lane covers
// 4 channels (8B loads) -> one vmem instruction gathers TWO 256B rows.
// Degree mismatch padded with row 0 / weight 0 (L1-hot, free).
__device__ __forceinline__ void unpack(long long p, int& s, float& w) {
  s = (int)(unsigned)(p & 0xffffffffll);
  w = __int_as_float((int)(p >> 32));
}

__global__ __launch_bounds__(256) void agg128h(const f16* __restrict__ H,
                                               const int* __restrict__ rp,
                                               const long long* __restrict__ csr,
                                               const float* __restrict__ dinv,
                                               const float* __restrict__ bias,
                                               f16* __restrict__ out, int n) {
  const int lane = threadIdx.x & 63;
  const int hl = lane & 31, side = lane >> 5;
  const int gw = (blockIdx.x * 256 + threadIdx.x) >> 6;
  const int nw = (gridDim.x * 256) >> 6;
  const int npairs = (n + 1) >> 1;
  const float4 bs = *(const float4*)&bias[hl * 4];
  for (int p = gw; p < npairs; p += nw) {
    const int i = p * 2 + side;
    const bool valid = (i < n);
    const int ic = valid ? i : 0;
    float di = dinv[ic];
    float dii = di * di;
    f16x4 hv = *(const f16x4*)&H[(size_t)ic * 128 + hl * 4];
    float a0 = fmaf((float)hv[0], dii, bs.x);
    float a1 = fmaf((float)hv[1], dii, bs.y);
    float a2 = fmaf((float)hv[2], dii, bs.z);
    float a3 = fmaf((float)hv[3], dii, bs.w);
    int e0 = rp[ic];
    int cnt = valid ? (rp[ic + 1] - e0) : 0;
    int maxc = max(cnt, __shfl_xor(cnt, 32));
    int j = 0;
    for (; j + 4 <= maxc; j += 4) {
      int x0 = (j + 0 < cnt) ? e0 + j + 0 : 0;
      int x1 = (j + 1 < cnt) ? e0 + j + 1 : 0;
      int x2 = (j + 2 < cnt) ? e0 + j + 2 : 0;
      int x3 = (j + 3 < cnt) ? e0 + j + 3 : 0;
      long long cc0 = csr[x0], cc1 = csr[x1], cc2 = csr[x2], cc3 = csr[x3];
      int s0, s1, s2, s3;
      float w0, w1, w2, w3;
      unpack(cc0, s0, w0); unpack(cc1, s1, w1);
      unpack(cc2, s2, w2); unpack(cc3, s3, w3);
      if (j + 0 >= cnt) w0 = 0.f;
      if (j + 1 >= cnt) w1 = 0.f;
      if (j + 2 >= cnt) w2 = 0.f;
      if (j + 3 >= cnt) w3 = 0.f;
      f16x4 v0 = *(const f16x4*)&H[(size_t)s0 * 128 + hl * 4];
      f16x4 v1 = *(const f16x4*)&H[(size_t)s1 * 128 + hl * 4];
      f16x4 v2 = *(const f16x4*)&H[(size_t)s2 * 128 + hl * 4];
      f16x4 v3 = *(const f16x4*)&H[(size_t)s3 * 128 + hl * 4];
      a0 = fmaf((float)v0[0], w0, a0); a1 = fmaf((float)v0[1], w0, a1);
      a2 = fmaf((float)v0[2], w0, a2); a3 = fmaf((float)v0[3], w0, a3);
      a0 = fmaf((float)v1[0], w1, a0); a1 = fmaf((float)v1[1], w1, a1);
      a2 = fmaf((float)v1[2], w1, a2); a3 = fmaf((float)v1[3], w1, a3);
      a0 = fmaf((float)v2[0], w2, a0); a1 = fmaf((float)v2[1], w2, a1);
      a2 = fmaf((float)v2[2], w2, a2); a3 = fmaf((float)v2[3], w2, a3);
      a0 = fmaf((float)v3[0], w3, a0); a1 = fmaf((float)v3[1], w3, a1);
      a2 = fmaf((float)v3[2], w3, a2); a3 = fmaf((float)v3[3], w3, a3);
    }
    for (; j < maxc; j++) {
      int x0 = (j < cnt) ? e0 + j : 0;
      long long cc0 = csr[x0];
      int s0;
      float w0;
      unpack(cc0, s0, w0);
      if (j >= cnt) w0 = 0.f;
      f16x4 v0 = *(const f16x4*)&H[(size_t)s0 * 128 + hl * 4];
      a0 = fmaf((float)v0[0], w0, a0); a1 = fmaf((float)v0[1], w0, a1);
      a2 = fmaf((float)v0[2], w0, a2); a3 = fmaf((float)v0[3], w0, a3);
    }
    if (valid) {
      f16x4 h = {(f16)a0, (f16)a1, (f16)a2, (f16)a3};
      *(f16x4*)&out[(size_t)i * 128 + hl * 4] = h;
    }
  }
}

// layer-3: H padded to 64 cols (128B line-aligned rows); paired half-wave,
// 2 channels/lane; store first 40 cols as fp32.
__global__ __launch_bounds__(256) void agg64h(const f16* __restrict__ H,
                                              const int* __restrict__ rp,
                                              const long long* __restrict__ csr,
                                              const float* __restrict__ dinv,
                                              const float* __restrict__ bias,
                                              float* __restrict__ out, int n) {
  const int lane = threadIdx.x & 63;
  const int hl = lane & 31, side = lane >> 5;
  const int gw = (blockIdx.x * 256 + threadIdx.x) >> 6;
  const int nw = (gridDim.x * 256) >> 6;
  const int npairs = (n + 1) >> 1;
  const int col0 = hl * 2, col1 = hl * 2 + 1;
  const float b0 = (col0 < 40) ? bias[col0] : 0.f;
  const float b1 = (col1 < 40) ? bias[col1] : 0.f;
  for (int p = gw; p < npairs; p += nw) {
    const int i = p * 2 + side;
    const bool valid = (i < n);
    const int ic = valid ? i : 0;
    float di = dinv[ic];
    float dii = di * di;
    float2 hf = __half22float2(*(const __half2*)&H[(size_t)ic * 64 + col0]);
    float a0 = fmaf(hf.x, dii, b0);
    float a1 = fmaf(hf.y, dii, b1);
    int e0 = rp[ic];
    int cnt = valid ? (rp[ic + 1] - e0) : 0;
    int maxc = max(cnt, __shfl_xor(cnt, 32));
    int j = 0;
    for (; j + 4 <= maxc; j += 4) {
      int x0 = (j + 0 < cnt) ? e0 + j + 0 : 0;
      int x1 = (j + 1 < cnt) ? e0 + j + 1 : 0;
      int x2 = (j + 2 < cnt) ? e0 + j + 2 : 0;
      int x3 = (j + 3 < cnt) ? e0 + j + 3 : 0;
      long long cc0 = csr[x0], cc1 = csr[x1], cc2 = csr[x2], cc3 = csr[x3];
      int s0, s1, s2, s3;
      float w0, w1, w2, w3;
      unpack(cc0, s0, w0); unpack(cc1, s1, w1);
      unpack(cc2, s2, w2); unpack(cc3, s3, w3);
      if (j + 0 >= cnt) w0 = 0.f;
      if (j + 1 >= cnt) w1 = 0.f;
      if (j + 2 >= cnt) w2 = 0.f;
      if (j + 3 >= cnt) w3 = 0.f;
      float2 v0 = __half22float2(*(const __half2*)&H[(size_t)s0 * 64 + col0]);
      float2 v1 = __half22float2(*(const __half2*)&H[(size_t)s1 * 64 + col0]);
      float2 v2 = __half22float2(*(const __half2*)&H[(size_t)s2 * 64 + col0]);
      float2 v3 = __half22float2(*(const __half2*)&H[(size_t)s3 * 64 + col0]);
      a0 = fmaf(v0.x, w0, a0); a1 = fmaf(v0.y, w0, a1);
      a0 = fmaf(v1.x, w1, a0); a1 = fmaf(v1.y, w1, a1);
      a0 = fmaf(v2.x, w2, a0); a1 = fmaf(v2.y, w2, a1);
      a0 = fmaf(v3.x, w3, a0); a1 = fmaf(v3.y, w3, a1);
    }
    for (; j < maxc; j++) {
      int x0 = (j < cnt) ? e0 + j : 0;
      long long cc0 = csr[x0];
      int s0;
      float w0;
      unpack(cc0, s0, w0);
      if (j >= cnt) w0 = 0.f;
      float2 v0 = __half22float2(*(const __half2*)&H[(size_t)s0 * 64 + col0]);
      a0 = fmaf(v0.x, w0, a0);
      a1 = fmaf(v0.y, w0, a1);
    }
    if (valid) {
      if (col0 < 40) out[(size_t)i * 40 + col0] = a0;
      if (col1 < 40) out[(size_t)i * 40 + col1] = a1;
    }
  }
}

// ============================ batchnorm stats (fp16 input) ============================
__global__ __launch_bounds__(256) void bn_stats_h(const f16* __restrict__ H, int n,
                                                  float* __restrict__ acc) {
  int t = threadIdx.x;
  int c2 = t & 63;   // half2 column
  int rg = t >> 6;   // 0..3
  float2 s = {0.f, 0.f}, s2 = {0.f, 0.f};
  for (int r = blockIdx.x * 4 + rg; r < n; r += gridDim.x * 4) {
    float2 v = __half22float2(*(const __half2*)&H[(size_t)r * 128 + c2 * 2]);
    s.x += v.x;
    s.y += v.y;
    s2.x = fmaf(v.x, v.x, s2.x);
    s2.y = fmaf(v.y, v.y, s2.y);
  }
  __shared__ float ls[4][128], ls2[4][128];
  ls[rg][c2 * 2] = s.x;
  ls[rg][c2 * 2 + 1] = s.y;
  ls2[rg][c2 * 2] = s2.x;
  ls2[rg][c2 * 2 + 1] = s2.y;
  __syncthreads();
  if (t < 128) {
    float a_ = ls[0][t] + ls[1][t] + ls[2][t] + ls[3][t];
    float b_ = ls2[0][t] + ls2[1][t] + ls2[2][t] + ls2[3][t];
    atomicAdd(&acc[t], a_);
    atomicAdd(&acc[128 + t], b_);
  }
}

// ============================ launch ============================
extern "C" void kernel_launch(void* const* d_in, const int* in_sizes, int n_in,
                              void* d_out, int out_size, void* d_ws, size_t ws_size,
                              hipStream_t stream) {
  const float* x = (const float*)d_in[0];
  const void* eb = d_in[1];
  const float* W1 = (const float*)d_in[2];
  const float* b1 = (const float*)d_in[3];
  const float* g1 = (const float*)d_in[4];
  const float* bt1 = (const float*)d_in[5];
  const float* W2 = (const float*)d_in[6];
  const float* b2 = (const float*)d_in[7];
  const float* g2 = (const float*)d_in[8];
  const float* bt2 = (const float*)d_in[9];
  const float* W3 = (const float*)d_in[10];
  const float* b3 = (const float*)d_in[11];

  const int n = in_sizes[0] / 128;
  const int E = in_sizes[1] / 2;
  const float inv_n = 1.0f / (float)n;

  char* w = (char*)d_ws;
  auto alloc = [&](size_t bytes) {
    void* p = (void*)w;
    w += (bytes + 255) & ~(size_t)255;
    return p;
  };
  f16* hA = (f16*)alloc((size_t)n * 128 * 2);
  f16* hB = (f16*)alloc((size_t)n * 128 * 2);
  int2* csr = (int2*)alloc((size_t)E * 8);
  float* dinv = (float*)alloc((size_t)n * 4);
  int* rp = (int*)alloc((size_t)(n + 1) * 4);
  int* bsum = (int*)alloc(512 * 4);
  f16* Wt1 = (f16*)alloc(128 * 128 * 2);
  f16* Wt2 = (f16*)alloc(128 * 128 * 2);
  f16* Wt3 = (f16*)alloc(64 * 128 * 2);
  // contiguous zero region:
  int* counts = (int*)alloc((size_t)n * 4);
  int* cursor = (int*)alloc((size_t)n * 4);
  float* bn_acc1 = (float*)alloc(256 * 4);
  float* bn_acc2 = (float*)alloc(256 * 4);
  int* flag = (int*)alloc(256);
  size_t zbytes = (char*)flag + 256 - (char*)counts;
  hipMemsetAsync(counts, 0, zbytes, stream);

  const int NB = (n + 255) / 256;

  prep_all<<<320, 128, 0, stream>>>(W1, W2, W3, Wt1, Wt2, Wt3);

  detect_k<<<1, 256, 0, stream>>>((const unsigned*)eb, E, flag);
  count_k<<<2048, 256, 0, stream>>>(eb, E, flag, counts);
  scan1_k<<<NB, 256, 0, stream>>>(counts, bsum, dinv, n);
  scanF_k<<<NB, 256, 0, stream>>>(counts, bsum, rp, n, E);
  fill_k<<<2048, 256, 0, stream>>>(eb, E, flag, rp, cursor, dinv, csr);

  const int GB = (n + 127) / 128;  // gemm blocks
  const int AGB = 4096;            // agg blocks (grid-stride, 16K waves)

  // layer 1
  gemm_mfma<128, false, true><<<GB, 256, 0, stream>>>(x, Wt1, nullptr, nullptr,
                                                      nullptr, inv_n, hA, n);
  agg128h<<<AGB, 256, 0, stream>>>(hA, rp, (const long long*)csr, dinv, b1, hB, n);
  bn_stats_h<<<1024, 256, 0, stream>>>(hB, n, bn_acc1);
  // layer 2 (BN scale/shift computed inside GEMM from raw sums)
  gemm_mfma<128, true, false><<<GB, 256, 0, stream>>>(hB, Wt2, bn_acc1, g1, bt1,
                                                      inv_n, hA, n);
  agg128h<<<AGB, 256, 0, stream>>>(hA, rp, (const long long*)csr, dinv, b2, hB, n);
  bn_stats_h<<<1024, 256, 0, stream>>>(hB, n, bn_acc2);
  // layer 3 (H padded to 64 cols for line-aligned gathers)
  gemm_mfma<64, true, false><<<GB, 256, 0, stream>>>(hB, Wt3, bn_acc2, g2, bt2,
                                                     inv_n, hA, n);
  agg64h<<<AGB, 256, 0, stream>>>(hA, rp, (const long long*)csr, dinv, b3,
                                  (float*)d_out, n);
}

// Round 8
// 533.111 us; speedup vs baseline: 1.3331x; 1.0610x over previous
//
#include <hip/hip_runtime.h>
#include <hip/hip_fp16.h>
#include <cstdint>

#define BN_EPS 1e-5f

typedef _Float16 f16;
typedef _Float16 f16x8 __attribute__((ext_vector_type(8)));
typedef _Float16 f16x4 __attribute__((ext_vector_type(4)));
typedef float f32x4 __attribute__((ext_vector_type(4)));

// ============================ edge preprocessing ============================

// Detect int64 vs int32 edge buffer (JAX may canonicalize int64 -> int32).
__global__ void detect_k(const unsigned* __restrict__ eb, int E,
                         int* __restrict__ flag) {
  int t = threadIdx.x;  // 256
  int cov = min(2048, E);
  int nz = 0;
  for (int k = t; k < cov; k += 256) nz |= (eb[2 * k + 1] != 0u);
  if (nz) atomicOr(flag, 1);
}

__device__ __forceinline__ void load_edge(const void* eb, int E, bool w64,
                                          int e, int& s, int& d) {
  if (w64) {
    const long long* p = (const long long*)eb;
    s = (int)p[e];
    d = (int)p[E + e];
  } else {
    const int* p = (const int*)eb;
    s = p[e];
    d = p[E + e];
  }
}

// dst-only histogram (src half never read)
__global__ __launch_bounds__(256) void count_k(const void* __restrict__ eb, int E,
                                               const int* __restrict__ flag,
                                               int* __restrict__ counts) {
  bool w64 = (*flag == 0);
  for (int e = blockIdx.x * 256 + threadIdx.x; e < E; e += gridDim.x * 256) {
    int d = w64 ? (int)((const long long*)eb)[E + e] : ((const int*)eb)[E + e];
    atomicAdd(&counts[d], 1);
  }
}

// --- scan pass 1: per-block sums (dinv fused) ---
__global__ __launch_bounds__(256) void scan1_k(const int* __restrict__ counts,
                                               int* __restrict__ bsum,
                                               float* __restrict__ dinv, int n) {
  __shared__ int ls[256];
  int t = threadIdx.x;
  int i = blockIdx.x * 256 + t;
  int c = (i < n) ? counts[i] : 0;
  if (i < n) dinv[i] = rsqrtf((float)(c + 1));  // +1 self-loop
  ls[t] = c;
  __syncthreads();
  for (int off = 128; off > 0; off >>= 1) {
    if (t < off) ls[t] += ls[t + off];
    __syncthreads();
  }
  if (t == 0) bsum[blockIdx.x] = ls[0];
}

// --- scan pass 2: rp + per-bucket partition cursors (pcur[b] = rp[b*512]) ---
__global__ __launch_bounds__(256) void scanF_k(const int* __restrict__ counts,
                                               const int* __restrict__ bsum,
                                               int* __restrict__ rp,
                                               int* __restrict__ pcur,
                                               int n, int E) {
  __shared__ int sa[256], sb[256];
  __shared__ int red[256];
  int t = threadIdx.x;
  int pacc = 0;
  for (int j = t; j < (int)blockIdx.x; j += 256) pacc += bsum[j];
  red[t] = pacc;
  __syncthreads();
  for (int off = 128; off > 0; off >>= 1) {
    if (t < off) red[t] += red[t + off];
    __syncthreads();
  }
  int off0 = red[0];
  __syncthreads();

  int i = blockIdx.x * 256 + t;
  int v = (i < n) ? counts[i] : 0;
  sa[t] = v;
  __syncthreads();
  int* src = sa;
  int* dst = sb;
  for (int off = 1; off < 256; off <<= 1) {
    int val = src[t] + (t >= off ? src[t - off] : 0);
    dst[t] = val;
    __syncthreads();
    int* tmp = src; src = dst; dst = tmp;
  }
  int incl = src[t];
  int rv = off0 + incl - v;
  if (i < n) {
    rp[i] = rv;
    if ((i & 511) == 0) pcur[i >> 9] = rv;  // bucket base cursor
  }
  if (i == n - 1) rp[n] = E;
}

// --- partition pass 1: block-local bucket grouping -> contiguous runs ---
#define PCHUNK 4096
__global__ __launch_bounds__(256) void part_k(const void* __restrict__ eb, int E,
                                              const int* __restrict__ flag,
                                              int* __restrict__ pcur,
                                              int2* __restrict__ part) {
  __shared__ int hist[256], lofs[256], gbase[256], lcur[256];
  __shared__ int sa[256], sb[256];
  __shared__ int2 stage[PCHUNK];  // 32KB
  bool w64 = (*flag == 0);
  const int t = threadIdx.x;
  const int e0 = blockIdx.x * PCHUNK;
  const int cnt = min(PCHUNK, E - e0);
  hist[t] = 0;
  __syncthreads();
  int2 ed[16];
#pragma unroll
  for (int k = 0; k < 16; k++) {
    int idx = t + k * 256;
    if (idx < cnt) {
      int s, d;
      load_edge(eb, E, w64, e0 + idx, s, d);
      ed[k].x = s;
      ed[k].y = d;
      atomicAdd(&hist[d >> 9], 1);
    }
  }
  __syncthreads();
  // exclusive scan of hist -> lofs
  sa[t] = hist[t];
  __syncthreads();
  int* src = sa;
  int* dst = sb;
  for (int off = 1; off < 256; off <<= 1) {
    int val = src[t] + (t >= off ? src[t - off] : 0);
    dst[t] = val;
    __syncthreads();
    int* tmp = src; src = dst; dst = tmp;
  }
  int c = hist[t];
  lofs[t] = src[t] - c;
  gbase[t] = (c > 0) ? atomicAdd(&pcur[t], c) : 0;
  lcur[t] = src[t] - c;
  __syncthreads();
  // place into staging, grouped by bucket
#pragma unroll
  for (int k = 0; k < 16; k++) {
    int idx = t + k * 256;
    if (idx < cnt) {
      int b = ed[k].y >> 9;
      int p = atomicAdd(&lcur[b], 1);
      stage[p] = ed[k];
    }
  }
  __syncthreads();
  // stream out: each bucket-run lands contiguously at its global base
  for (int idx = t; idx < cnt; idx += 256) {
    int2 e = stage[idx];
    int b = e.y >> 9;
    part[gbase[b] + (idx - lofs[b])] = e;
  }
}

// --- partition pass 2: per-bucket exact placement (scatter confined to 65KB) ---
__global__ __launch_bounds__(512) void sort_k(const int2* __restrict__ part,
                                              const int* __restrict__ rp,
                                              const float* __restrict__ dinv,
                                              int2* __restrict__ csr, int n) {
  __shared__ int lrp[512];
  __shared__ float ldv[512];
  __shared__ int lcur[512];
  const int b = blockIdx.x;
  const int d0 = b << 9;
  const int dEnd = min(d0 + 512, n);
  const int nloc = dEnd - d0;
  const int t = threadIdx.x;
  for (int k = t; k < nloc; k += 512) {
    lrp[k] = rp[d0 + k];
    ldv[k] = dinv[d0 + k];
    lcur[k] = 0;
  }
  __syncthreads();
  const int base = rp[d0];
  const int total = rp[dEnd] - base;
  for (int idx = t; idx < total; idx += 512) {
    int2 e = part[base + idx];
    int ld = e.y - d0;
    int pos = lrp[ld] + atomicAdd(&lcur[ld], 1);
    float nm = dinv[e.x] * ldv[ld];
    int2 ent;
    ent.x = e.x;
    ent.y = __float_as_int(nm);
    csr[pos] = ent;
  }
}

// ============================ W prep: transpose + fp16 (single launch) ============
__global__ void prep_all(const float* __restrict__ W1, const float* __restrict__ W2,
                         const float* __restrict__ W3, f16* __restrict__ Wt1,
                         f16* __restrict__ Wt2, f16* __restrict__ Wt3) {
  int b = blockIdx.x, k = threadIdx.x;  // 128 threads
  if (b < 128) {
    Wt1[(size_t)b * 128 + k] = (f16)W1[(size_t)k * 128 + b];
  } else if (b < 256) {
    int nc = b - 128;
    Wt2[(size_t)nc * 128 + k] = (f16)W2[(size_t)k * 128 + nc];
  } else {
    int nc = b - 256;  // 0..63
    Wt3[(size_t)nc * 128 + k] = (nc < 40) ? (f16)W3[(size_t)k * 40 + nc] : (f16)0.f;
  }
}

// ============================ GEMM (MFMA f16) ============================
template <int NCP, bool BN, bool F32IN>
__global__ __launch_bounds__(256) void gemm_mfma(const void* __restrict__ Xv,
                                                 const f16* __restrict__ Wt,
                                                 const float* __restrict__ bn_acc,
                                                 const float* __restrict__ g,
                                                 const float* __restrict__ bt,
                                                 float inv_n,
                                                 f16* __restrict__ H, int n) {
  constexpr int CB = NCP / 16;
  __shared__ f16 Xs[128][136];
  __shared__ f16 Ws[NCP][136];
  __shared__ float bnS[128], bnH[128];
  const int t = threadIdx.x;
  const int m0 = blockIdx.x * 128;

  if (BN) {
    if (t < 128) {
      float mean = bn_acc[t] * inv_n;
      float var = bn_acc[128 + t] * inv_n - mean * mean;
      float sc = g[t] * rsqrtf(var + BN_EPS);
      bnS[t] = sc;
      bnH[t] = fmaf(-mean, sc, bt[t]);
    }
    __syncthreads();
  }

  if constexpr (F32IN) {
    const float* X = (const float*)Xv;
#pragma unroll
    for (int p = 0; p < 16; p++) {
      int idx = p * 256 + t;
      int row = idx >> 5, c = (idx & 31) * 4;
      float4 v = make_float4(0.f, 0.f, 0.f, 0.f);
      if (m0 + row < n) v = *(const float4*)&X[(size_t)(m0 + row) * 128 + c];
      if (BN) {
        v.x = fmaxf(fmaf(v.x, bnS[c + 0], bnH[c + 0]), 0.f);
        v.y = fmaxf(fmaf(v.y, bnS[c + 1], bnH[c + 1]), 0.f);
        v.z = fmaxf(fmaf(v.z, bnS[c + 2], bnH[c + 2]), 0.f);
        v.w = fmaxf(fmaf(v.w, bnS[c + 3], bnH[c + 3]), 0.f);
      }
      f16x4 h = {(f16)v.x, (f16)v.y, (f16)v.z, (f16)v.w};
      *(f16x4*)&Xs[row][c] = h;
    }
  } else {
    const f16* X = (const f16*)Xv;
#pragma unroll
    for (int p = 0; p < 8; p++) {
      int idx = p * 256 + t;
      int row = idx >> 4, c = (idx & 15) * 8;
      f16x8 v = {0, 0, 0, 0, 0, 0, 0, 0};
      if (m0 + row < n) v = *(const f16x8*)&X[(size_t)(m0 + row) * 128 + c];
      if (BN) {
#pragma unroll
        for (int j = 0; j < 8; j++) {
          float f = (float)v[j];
          f = fmaxf(fmaf(f, bnS[c + j], bnH[c + j]), 0.f);
          v[j] = (f16)f;
        }
      }
      *(f16x8*)&Xs[row][c] = v;
    }
  }
#pragma unroll
  for (int idx = t; idx < NCP * 16; idx += 256) {
    int row = idx >> 4, c = (idx & 15) * 8;
    *(f16x8*)&Ws[row][c] = *(const f16x8*)&Wt[(size_t)row * 128 + c];
  }
  __syncthreads();

  const int w = t >> 6, l = t & 63;
  const int lr = l & 15, lq = l >> 4;
  f32x4 acc[2][CB];
#pragma unroll
  for (int i = 0; i < 2; i++)
#pragma unroll
    for (int j = 0; j < CB; j++) acc[i][j] = (f32x4){0.f, 0.f, 0.f, 0.f};

#pragma unroll
  for (int kb = 0; kb < 4; kb++) {
    f16x8 xf0 = *(const f16x8*)&Xs[w * 32 + lr][kb * 32 + lq * 8];
    f16x8 xf1 = *(const f16x8*)&Xs[w * 32 + 16 + lr][kb * 32 + lq * 8];
#pragma unroll
    for (int cb = 0; cb < CB; cb++) {
      f16x8 wf = *(const f16x8*)&Ws[cb * 16 + lr][kb * 32 + lq * 8];
      acc[0][cb] = __builtin_amdgcn_mfma_f32_16x16x32_f16(wf, xf0, acc[0][cb], 0, 0, 0);
      acc[1][cb] = __builtin_amdgcn_mfma_f32_16x16x32_f16(wf, xf1, acc[1][cb], 0, 0, 0);
    }
  }
#pragma unroll
  for (int rg = 0; rg < 2; rg++) {
    int row = m0 + w * 32 + rg * 16 + lr;
    if (row >= n) continue;
#pragma unroll
    for (int cb = 0; cb < CB; cb++) {
      int col = cb * 16 + lq * 4;
      f32x4 a = acc[rg][cb];
      f16x4 h = {(f16)a[0], (f16)a[1], (f16)a[2], (f16)a[3]};
      *(f16x4*)&H[(size_t)row * NCP + col] = h;
    }
  }
}

// ============================ aggregation (gather, fp16 rows) ============================
// Paired half-wave scheme: nodes (2p, 2p+1) on lane halves; each lane covers
// 4 channels (8B loads) -> one vmem instruction gathers TWO 256B rows.
__device__ __forceinline__ void unpack(long long p, int& s, float& w) {
  s = (int)(unsigned)(p & 0xffffffffll);
  w = __int_as_float((int)(p >> 32));
}

__global__ __launch_bounds__(256) void agg128h(const f16* __restrict__ H,
                                               const int* __restrict__ rp,
                                               const long long* __restrict__ csr,
                                               const float* __restrict__ dinv,
                                               const float* __restrict__ bias,
                                               f16* __restrict__ out, int n) {
  const int lane = threadIdx.x & 63;
  const int hl = lane & 31, side = lane >> 5;
  const int gw = (blockIdx.x * 256 + threadIdx.x) >> 6;
  const int nw = (gridDim.x * 256) >> 6;
  const int npairs = (n + 1) >> 1;
  const float4 bs = *(const float4*)&bias[hl * 4];
  for (int p = gw; p < npairs; p += nw) {
    const int i = p * 2 + side;
    const bool valid = (i < n);
    const int ic = valid ? i : 0;
    float di = dinv[ic];
    float dii = di * di;
    f16x4 hv = *(const f16x4*)&H[(size_t)ic * 128 + hl * 4];
    float a0 = fmaf((float)hv[0], dii, bs.x);
    float a1 = fmaf((float)hv[1], dii, bs.y);
    float a2 = fmaf((float)hv[2], dii, bs.z);
    float a3 = fmaf((float)hv[3], dii, bs.w);
    int e0 = rp[ic];
    int cnt = valid ? (rp[ic + 1] - e0) : 0;
    int maxc = max(cnt, __shfl_xor(cnt, 32));
    int j = 0;
    for (; j + 4 <= maxc; j += 4) {
      int x0 = (j + 0 < cnt) ? e0 + j + 0 : 0;
      int x1 = (j + 1 < cnt) ? e0 + j + 1 : 0;
      int x2 = (j + 2 < cnt) ? e0 + j + 2 : 0;
      int x3 = (j + 3 < cnt) ? e0 + j + 3 : 0;
      long long cc0 = csr[x0], cc1 = csr[x1], cc2 = csr[x2], cc3 = csr[x3];
      int s0, s1, s2, s3;
      float w0, w1, w2, w3;
      unpack(cc0, s0, w0); unpack(cc1, s1, w1);
      unpack(cc2, s2, w2); unpack(cc3, s3, w3);
      if (j + 0 >= cnt) w0 = 0.f;
      if (j + 1 >= cnt) w1 = 0.f;
      if (j + 2 >= cnt) w2 = 0.f;
      if (j + 3 >= cnt) w3 = 0.f;
      f16x4 v0 = *(const f16x4*)&H[(size_t)s0 * 128 + hl * 4];
      f16x4 v1 = *(const f16x4*)&H[(size_t)s1 * 128 + hl * 4];
      f16x4 v2 = *(const f16x4*)&H[(size_t)s2 * 128 + hl * 4];
      f16x4 v3 = *(const f16x4*)&H[(size_t)s3 * 128 + hl * 4];
      a0 = fmaf((float)v0[0], w0, a0); a1 = fmaf((float)v0[1], w0, a1);
      a2 = fmaf((float)v0[2], w0, a2); a3 = fmaf((float)v0[3], w0, a3);
      a0 = fmaf((float)v1[0], w1, a0); a1 = fmaf((float)v1[1], w1, a1);
      a2 = fmaf((float)v1[2], w1, a2); a3 = fmaf((float)v1[3], w1, a3);
      a0 = fmaf((float)v2[0], w2, a0); a1 = fmaf((float)v2[1], w2, a1);
      a2 = fmaf((float)v2[2], w2, a2); a3 = fmaf((float)v2[3], w2, a3);
      a0 = fmaf((float)v3[0], w3, a0); a1 = fmaf((float)v3[1], w3, a1);
      a2 = fmaf((float)v3[2], w3, a2); a3 = fmaf((float)v3[3], w3, a3);
    }
    for (; j < maxc; j++) {
      int x0 = (j < cnt) ? e0 + j : 0;
      long long cc0 = csr[x0];
      int s0;
      float w0;
      unpack(cc0, s0, w0);
      if (j >= cnt) w0 = 0.f;
      f16x4 v0 = *(const f16x4*)&H[(size_t)s0 * 128 + hl * 4];
      a0 = fmaf((float)v0[0], w0, a0); a1 = fmaf((float)v0[1], w0, a1);
      a2 = fmaf((float)v0[2], w0, a2); a3 = fmaf((float)v0[3], w0, a3);
    }
    if (valid) {
      f16x4 h = {(f16)a0, (f16)a1, (f16)a2, (f16)a3};
      *(f16x4*)&out[(size_t)i * 128 + hl * 4] = h;
    }
  }
}

// layer-3: H padded to 64 cols; paired half-wave, 2 ch/lane; fp32 out (40 cols).
__global__ __launch_bounds__(256) void agg64h(const f16* __restrict__ H,
                                              const int* __restrict__ rp,
                                              const long long* __restrict__ csr,
                                              const float* __restrict__ dinv,
                                              const float* __restrict__ bias,
                                              float* __restrict__ out, int n) {
  const int lane = threadIdx.x & 63;
  const int hl = lane & 31, side = lane >> 5;
  const int gw = (blockIdx.x * 256 + threadIdx.x) >> 6;
  const int nw = (gridDim.x * 256) >> 6;
  const int npairs = (n + 1) >> 1;
  const int col0 = hl * 2, col1 = hl * 2 + 1;
  const float b0 = (col0 < 40) ? bias[col0] : 0.f;
  const float b1 = (col1 < 40) ? bias[col1] : 0.f;
  for (int p = gw; p < npairs; p += nw) {
    const int i = p * 2 + side;
    const bool valid = (i < n);
    const int ic = valid ? i : 0;
    float di = dinv[ic];
    float dii = di * di;
    float2 hf = __half22float2(*(const __half2*)&H[(size_t)ic * 64 + col0]);
    float a0 = fmaf(hf.x, dii, b0);
    float a1 = fmaf(hf.y, dii, b1);
    int e0 = rp[ic];
    int cnt = valid ? (rp[ic + 1] - e0) : 0;
    int maxc = max(cnt, __shfl_xor(cnt, 32));
    int j = 0;
    for (; j + 4 <= maxc; j += 4) {
      int x0 = (j + 0 < cnt) ? e0 + j + 0 : 0;
      int x1 = (j + 1 < cnt) ? e0 + j + 1 : 0;
      int x2 = (j + 2 < cnt) ? e0 + j + 2 : 0;
      int x3 = (j + 3 < cnt) ? e0 + j + 3 : 0;
      long long cc0 = csr[x0], cc1 = csr[x1], cc2 = csr[x2], cc3 = csr[x3];
      int s0, s1, s2, s3;
      float w0, w1, w2, w3;
      unpack(cc0, s0, w0); unpack(cc1, s1, w1);
      unpack(cc2, s2, w2); unpack(cc3, s3, w3);
      if (j + 0 >= cnt) w0 = 0.f;
      if (j + 1 >= cnt) w1 = 0.f;
      if (j + 2 >= cnt) w2 = 0.f;
      if (j + 3 >= cnt) w3 = 0.f;
      float2 v0 = __half22float2(*(const __half2*)&H[(size_t)s0 * 64 + col0]);
      float2 v1 = __half22float2(*(const __half2*)&H[(size_t)s1 * 64 + col0]);
      float2 v2 = __half22float2(*(const __half2*)&H[(size_t)s2 * 64 + col0]);
      float2 v3 = __half22float2(*(const __half2*)&H[(size_t)s3 * 64 + col0]);
      a0 = fmaf(v0.x, w0, a0); a1 = fmaf(v0.y, w0, a1);
      a0 = fmaf(v1.x, w1, a0); a1 = fmaf(v1.y, w1, a1);
      a0 = fmaf(v2.x, w2, a0); a1 = fmaf(v2.y, w2, a1);
      a0 = fmaf(v3.x, w3, a0); a1 = fmaf(v3.y, w3, a1);
    }
    for (; j < maxc; j++) {
      int x0 = (j < cnt) ? e0 + j : 0;
      long long cc0 = csr[x0];
      int s0;
      float w0;
      unpack(cc0, s0, w0);
      if (j >= cnt) w0 = 0.f;
      float2 v0 = __half22float2(*(const __half2*)&H[(size_t)s0 * 64 + col0]);
      a0 = fmaf(v0.x, w0, a0);
      a1 = fmaf(v0.y, w0, a1);
    }
    if (valid) {
      if (col0 < 40) out[(size_t)i * 40 + col0] = a0;
      if (col1 < 40) out[(size_t)i * 40 + col1] = a1;
    }
  }
}

// ============================ batchnorm stats (fp16 input) ============================
__global__ __launch_bounds__(256) void bn_stats_h(const f16* __restrict__ H, int n,
                                                  float* __restrict__ acc) {
  int t = threadIdx.x;
  int c2 = t & 63;
  int rg = t >> 6;
  float2 s = {0.f, 0.f}, s2 = {0.f, 0.f};
  for (int r = blockIdx.x * 4 + rg; r < n; r += gridDim.x * 4) {
    float2 v = __half22float2(*(const __half2*)&H[(size_t)r * 128 + c2 * 2]);
    s.x += v.x;
    s.y += v.y;
    s2.x = fmaf(v.x, v.x, s2.x);
    s2.y = fmaf(v.y, v.y, s2.y);
  }
  __shared__ float ls[4][128], ls2[4][128];
  ls[rg][c2 * 2] = s.x;
  ls[rg][c2 * 2 + 1] = s.y;
  ls2[rg][c2 * 2] = s2.x;
  ls2[rg][c2 * 2 + 1] = s2.y;
  __syncthreads();
  if (t < 128) {
    float a_ = ls[0][t] + ls[1][t] + ls[2][t] + ls[3][t];
    float b_ = ls2[0][t] + ls2[1][t] + ls2[2][t] + ls2[3][t];
    atomicAdd(&acc[t], a_);
    atomicAdd(&acc[128 + t], b_);
  }
}

// ============================ launch ============================
extern "C" void kernel_launch(void* const* d_in, const int* in_sizes, int n_in,
                              void* d_out, int out_size, void* d_ws, size_t ws_size,
                              hipStream_t stream) {
  const float* x = (const float*)d_in[0];
  const void* eb = d_in[1];
  const float* W1 = (const float*)d_in[2];
  const float* b1 = (const float*)d_in[3];
  const float* g1 = (const float*)d_in[4];
  const float* bt1 = (const float*)d_in[5];
  const float* W2 = (const float*)d_in[6];
  const float* b2 = (const float*)d_in[7];
  const float* g2 = (const float*)d_in[8];
  const float* bt2 = (const float*)d_in[9];
  const float* W3 = (const float*)d_in[10];
  const float* b3 = (const float*)d_in[11];

  const int n = in_sizes[0] / 128;
  const int E = in_sizes[1] / 2;
  const float inv_n = 1.0f / (float)n;

  char* w = (char*)d_ws;
  auto alloc = [&](size_t bytes) {
    void* p = (void*)w;
    w += (bytes + 255) & ~(size_t)255;
    return p;
  };
  f16* hA = (f16*)alloc((size_t)n * 128 * 2);
  f16* hB = (f16*)alloc((size_t)n * 128 * 2);
  int2* csr = (int2*)alloc((size_t)E * 8);
  int2* part = (int2*)alloc((size_t)E * 8);
  float* dinv = (float*)alloc((size_t)n * 4);
  int* rp = (int*)alloc((size_t)(n + 1) * 4);
  int* bsum = (int*)alloc(512 * 4);
  int* pcur = (int*)alloc(256 * 4);
  f16* Wt1 = (f16*)alloc(128 * 128 * 2);
  f16* Wt2 = (f16*)alloc(128 * 128 * 2);
  f16* Wt3 = (f16*)alloc(64 * 128 * 2);
  // contiguous zero region:
  int* counts = (int*)alloc((size_t)n * 4);
  float* bn_acc1 = (float*)alloc(256 * 4);
  float* bn_acc2 = (float*)alloc(256 * 4);
  int* flag = (int*)alloc(256);
  size_t zbytes = (char*)flag + 256 - (char*)counts;
  hipMemsetAsync(counts, 0, zbytes, stream);

  const int NB = (n + 255) / 256;
  const int NBKT = (n + 511) / 512;  // 196 buckets (<= 256)
  const int PB = (E + PCHUNK - 1) / PCHUNK;

  prep_all<<<320, 128, 0, stream>>>(W1, W2, W3, Wt1, Wt2, Wt3);

  detect_k<<<1, 256, 0, stream>>>((const unsigned*)eb, E, flag);
  count_k<<<2048, 256, 0, stream>>>(eb, E, flag, counts);
  scan1_k<<<NB, 256, 0, stream>>>(counts, bsum, dinv, n);
  scanF_k<<<NB, 256, 0, stream>>>(counts, bsum, rp, pcur, n, E);
  part_k<<<PB, 256, 0, stream>>>(eb, E, flag, pcur, part);
  sort_k<<<NBKT, 512, 0, stream>>>(part, rp, dinv, csr, n);

  const int GB = (n + 127) / 128;  // gemm blocks
  const int AGB = 4096;            // agg blocks (grid-stride, 16K waves)

  // layer 1
  gemm_mfma<128, false, true><<<GB, 256, 0, stream>>>(x, Wt1, nullptr, nullptr,
                                                      nullptr, inv_n, hA, n);
  agg128h<<<AGB, 256, 0, stream>>>(hA, rp, (const long long*)csr, dinv, b1, hB, n);
  bn_stats_h<<<1024, 256, 0, stream>>>(hB, n, bn_acc1);
  // layer 2 (BN scale/shift computed inside GEMM from raw sums)
  gemm_mfma<128, true, false><<<GB, 256, 0, stream>>>(hB, Wt2, bn_acc1, g1, bt1,
                                                      inv_n, hA, n);
  agg128h<<<AGB, 256, 0, stream>>>(hA, rp, (const long long*)csr, dinv, b2, hB, n);
  bn_stats_h<<<1024, 256, 0, stream>>>(hB, n, bn_acc2);
  // layer 3 (H padded to 64 cols for line-aligned gathers)
  gemm_mfma<64, true, false><<<GB, 256, 0, stream>>>(hB, Wt3, bn_acc2, g2, bt2,
                                                     inv_n, hA, n);
  agg64h<<<AGB, 256, 0, stream>>>(hA, rp, (const long long*)csr, dinv, b3,
                                  (float*)d_out, n);
}

// Round 9
// 526.723 us; speedup vs baseline: 1.3492x; 1.0121x over previous
//
#include <hip/hip_runtime.h>
#include <hip/hip_fp16.h>
#include <cstdint>

#define BN_EPS 1e-5f
#define PCHUNK 4096
#define BCAP 16384  // per-bucket capacity (mean 8163 for uniform dst, 90+ sigma)

typedef _Float16 f16;
typedef _Float16 f16x8 __attribute__((ext_vector_type(8)));
typedef _Float16 f16x4 __attribute__((ext_vector_type(4)));
typedef float f32x4 __attribute__((ext_vector_type(4)));

// ============================ edge preprocessing ============================

// Detect int64 vs int32 edge buffer (JAX may canonicalize int64 -> int32).
__global__ void detect_k(const unsigned* __restrict__ eb, int E,
                         int* __restrict__ flag) {
  int t = threadIdx.x;  // 256
  int cov = min(2048, E);
  int nz = 0;
  for (int k = t; k < cov; k += 256) nz |= (eb[2 * k + 1] != 0u);
  if (nz) atomicOr(flag, 1);
}

__device__ __forceinline__ void load_edge(const void* eb, int E, bool w64,
                                          int e, int& s, int& d) {
  if (w64) {
    const long long* p = (const long long*)eb;
    s = (int)p[e];
    d = (int)p[E + e];
  } else {
    const int* p = (const int*)eb;
    s = p[e];
    d = p[E + e];
  }
}

// --- partition pass 1 (fused dst-histogram): block-local bucket grouping ---
// Buckets of 512 dst nodes, fixed capacity BCAP, zero-based cursors in pcur.
__global__ __launch_bounds__(256) void part_k(const void* __restrict__ eb, int E,
                                              const int* __restrict__ flag,
                                              int* __restrict__ counts,
                                              int* __restrict__ pcur,
                                              int2* __restrict__ part) {
  __shared__ int hist[256], lofs[256], gbase[256], lcur[256];
  __shared__ int sa[256], sb[256];
  __shared__ int2 stage[PCHUNK];  // 32KB
  bool w64 = (*flag == 0);
  const int t = threadIdx.x;
  const int e0 = blockIdx.x * PCHUNK;
  const int cnt = min(PCHUNK, E - e0);
  hist[t] = 0;
  __syncthreads();
  int2 ed[16];
#pragma unroll
  for (int k = 0; k < 16; k++) {
    int idx = t + k * 256;
    if (idx < cnt) {
      int s, d;
      load_edge(eb, E, w64, e0 + idx, s, d);
      ed[k].x = s;
      ed[k].y = d;
      atomicAdd(&hist[d >> 9], 1);
      atomicAdd(&counts[d], 1);  // fused global degree histogram
    }
  }
  __syncthreads();
  // exclusive scan of hist -> lofs
  sa[t] = hist[t];
  __syncthreads();
  int* src = sa;
  int* dst = sb;
  for (int off = 1; off < 256; off <<= 1) {
    int val = src[t] + (t >= off ? src[t - off] : 0);
    dst[t] = val;
    __syncthreads();
    int* tmp = src; src = dst; dst = tmp;
  }
  int c = hist[t];
  lofs[t] = src[t] - c;
  gbase[t] = (c > 0) ? (t * BCAP + atomicAdd(&pcur[t], c)) : 0;
  lcur[t] = src[t] - c;
  __syncthreads();
  // place into staging, grouped by bucket
#pragma unroll
  for (int k = 0; k < 16; k++) {
    int idx = t + k * 256;
    if (idx < cnt) {
      int b = ed[k].y >> 9;
      int p = atomicAdd(&lcur[b], 1);
      stage[p] = ed[k];
    }
  }
  __syncthreads();
  // stream out: each bucket-run lands contiguously at its global base
  for (int idx = t; idx < cnt; idx += 256) {
    int2 e = stage[idx];
    int b = e.y >> 9;
    part[gbase[b] + (idx - lofs[b])] = e;
  }
}

// --- scan pass 1: per-block sums (dinv fused) ---
__global__ __launch_bounds__(256) void scan1_k(const int* __restrict__ counts,
                                               int* __restrict__ bsum,
                                               float* __restrict__ dinv, int n) {
  __shared__ int ls[256];
  int t = threadIdx.x;
  int i = blockIdx.x * 256 + t;
  int c = (i < n) ? counts[i] : 0;
  if (i < n) dinv[i] = rsqrtf((float)(c + 1));  // +1 self-loop
  ls[t] = c;
  __syncthreads();
  for (int off = 128; off > 0; off >>= 1) {
    if (t < off) ls[t] += ls[t + off];
    __syncthreads();
  }
  if (t == 0) bsum[blockIdx.x] = ls[0];
}

// --- scan pass 2: rp (each block derives its prefix from bsum; NB <= 512) ---
__global__ __launch_bounds__(256) void scanF_k(const int* __restrict__ counts,
                                               const int* __restrict__ bsum,
                                               int* __restrict__ rp, int n, int E) {
  __shared__ int sa[256], sb[256];
  __shared__ int red[256];
  int t = threadIdx.x;
  int pacc = 0;
  for (int j = t; j < (int)blockIdx.x; j += 256) pacc += bsum[j];
  red[t] = pacc;
  __syncthreads();
  for (int off = 128; off > 0; off >>= 1) {
    if (t < off) red[t] += red[t + off];
    __syncthreads();
  }
  int off0 = red[0];
  __syncthreads();

  int i = blockIdx.x * 256 + t;
  int v = (i < n) ? counts[i] : 0;
  sa[t] = v;
  __syncthreads();
  int* src = sa;
  int* dst = sb;
  for (int off = 1; off < 256; off <<= 1) {
    int val = src[t] + (t >= off ? src[t - off] : 0);
    dst[t] = val;
    __syncthreads();
    int* tmp = src; src = dst; dst = tmp;
  }
  int incl = src[t];
  if (i < n) rp[i] = off0 + incl - v;
  if (i == n - 1) rp[n] = E;
}

// --- partition pass 2: per-bucket exact placement (scatter confined to 65KB) ---
__global__ __launch_bounds__(512) void sort_k(const int2* __restrict__ part,
                                              const int* __restrict__ pcur,
                                              const int* __restrict__ rp,
                                              const float* __restrict__ dinv,
                                              int2* __restrict__ csr, int n) {
  __shared__ int lrp[512];
  __shared__ float ldv[512];
  __shared__ int lcur[512];
  const int b = blockIdx.x;
  const int d0 = b << 9;
  const int dEnd = min(d0 + 512, n);
  const int nloc = dEnd - d0;
  const int t = threadIdx.x;
  for (int k = t; k < nloc; k += 512) {
    lrp[k] = rp[d0 + k];
    ldv[k] = dinv[d0 + k];
    lcur[k] = 0;
  }
  __syncthreads();
  const int base = b * BCAP;
  const int total = pcur[b];
  for (int idx = t; idx < total; idx += 512) {
    int2 e = part[base + idx];
    int ld = e.y - d0;
    int pos = lrp[ld] + atomicAdd(&lcur[ld], 1);
    float nm = dinv[e.x] * ldv[ld];
    int2 ent;
    ent.x = e.x;
    ent.y = __float_as_int(nm);
    csr[pos] = ent;
  }
}

// ============================ W prep: transpose + fp16 (single launch) ============
__global__ void prep_all(const float* __restrict__ W1, const float* __restrict__ W2,
                         const float* __restrict__ W3, f16* __restrict__ Wt1,
                         f16* __restrict__ Wt2, f16* __restrict__ Wt3) {
  int b = blockIdx.x, k = threadIdx.x;  // 128 threads
  if (b < 128) {
    Wt1[(size_t)b * 128 + k] = (f16)W1[(size_t)k * 128 + b];
  } else if (b < 256) {
    int nc = b - 128;
    Wt2[(size_t)nc * 128 + k] = (f16)W2[(size_t)k * 128 + nc];
  } else {
    int nc = b - 256;  // 0..63
    Wt3[(size_t)nc * 128 + k] = (nc < 40) ? (f16)W3[(size_t)k * 40 + nc] : (f16)0.f;
  }
}

// ============================ GEMM (MFMA f16) ============================
template <int NCP, bool BN, bool F32IN>
__global__ __launch_bounds__(256) void gemm_mfma(const void* __restrict__ Xv,
                                                 const f16* __restrict__ Wt,
                                                 const float* __restrict__ bn_acc,
                                                 const float* __restrict__ g,
                                                 const float* __restrict__ bt,
                                                 float inv_n,
                                                 f16* __restrict__ H, int n) {
  constexpr int CB = NCP / 16;
  __shared__ f16 Xs[128][136];
  __shared__ f16 Ws[NCP][136];
  __shared__ float bnS[128], bnH[128];
  const int t = threadIdx.x;
  const int m0 = blockIdx.x * 128;

  if (BN) {
    if (t < 128) {
      float mean = bn_acc[t] * inv_n;
      float var = bn_acc[128 + t] * inv_n - mean * mean;
      float sc = g[t] * rsqrtf(var + BN_EPS);
      bnS[t] = sc;
      bnH[t] = fmaf(-mean, sc, bt[t]);
    }
    __syncthreads();
  }

  if constexpr (F32IN) {
    const float* X = (const float*)Xv;
#pragma unroll
    for (int p = 0; p < 16; p++) {
      int idx = p * 256 + t;
      int row = idx >> 5, c = (idx & 31) * 4;
      float4 v = make_float4(0.f, 0.f, 0.f, 0.f);
      if (m0 + row < n) v = *(const float4*)&X[(size_t)(m0 + row) * 128 + c];
      if (BN) {
        v.x = fmaxf(fmaf(v.x, bnS[c + 0], bnH[c + 0]), 0.f);
        v.y = fmaxf(fmaf(v.y, bnS[c + 1], bnH[c + 1]), 0.f);
        v.z = fmaxf(fmaf(v.z, bnS[c + 2], bnH[c + 2]), 0.f);
        v.w = fmaxf(fmaf(v.w, bnS[c + 3], bnH[c + 3]), 0.f);
      }
      f16x4 h = {(f16)v.x, (f16)v.y, (f16)v.z, (f16)v.w};
      *(f16x4*)&Xs[row][c] = h;
    }
  } else {
    const f16* X = (const f16*)Xv;
#pragma unroll
    for (int p = 0; p < 8; p++) {
      int idx = p * 256 + t;
      int row = idx >> 4, c = (idx & 15) * 8;
      f16x8 v = {0, 0, 0, 0, 0, 0, 0, 0};
      if (m0 + row < n) v = *(const f16x8*)&X[(size_t)(m0 + row) * 128 + c];
      if (BN) {
#pragma unroll
        for (int j = 0; j < 8; j++) {
          float f = (float)v[j];
          f = fmaxf(fmaf(f, bnS[c + j], bnH[c + j]), 0.f);
          v[j] = (f16)f;
        }
      }
      *(f16x8*)&Xs[row][c] = v;
    }
  }
#pragma unroll
  for (int idx = t; idx < NCP * 16; idx += 256) {
    int row = idx >> 4, c = (idx & 15) * 8;
    *(f16x8*)&Ws[row][c] = *(const f16x8*)&Wt[(size_t)row * 128 + c];
  }
  __syncthreads();

  const int w = t >> 6, l = t & 63;
  const int lr = l & 15, lq = l >> 4;
  f32x4 acc[2][CB];
#pragma unroll
  for (int i = 0; i < 2; i++)
#pragma unroll
    for (int j = 0; j < CB; j++) acc[i][j] = (f32x4){0.f, 0.f, 0.f, 0.f};

#pragma unroll
  for (int kb = 0; kb < 4; kb++) {
    f16x8 xf0 = *(const f16x8*)&Xs[w * 32 + lr][kb * 32 + lq * 8];
    f16x8 xf1 = *(const f16x8*)&Xs[w * 32 + 16 + lr][kb * 32 + lq * 8];
#pragma unroll
    for (int cb = 0; cb < CB; cb++) {
      f16x8 wf = *(const f16x8*)&Ws[cb * 16 + lr][kb * 32 + lq * 8];
      acc[0][cb] = __builtin_amdgcn_mfma_f32_16x16x32_f16(wf, xf0, acc[0][cb], 0, 0, 0);
      acc[1][cb] = __builtin_amdgcn_mfma_f32_16x16x32_f16(wf, xf1, acc[1][cb], 0, 0, 0);
    }
  }
#pragma unroll
  for (int rg = 0; rg < 2; rg++) {
    int row = m0 + w * 32 + rg * 16 + lr;
    if (row >= n) continue;
#pragma unroll
    for (int cb = 0; cb < CB; cb++) {
      int col = cb * 16 + lq * 4;
      f32x4 a = acc[rg][cb];
      f16x4 h = {(f16)a[0], (f16)a[1], (f16)a[2], (f16)a[3]};
      *(f16x4*)&H[(size_t)row * NCP + col] = h;
    }
  }
}

// ============================ aggregation (gather, fp16 rows) ============================
// Paired half-wave scheme: nodes (2p, 2p+1) on lane halves; each lane covers
// 4 channels (8B loads) -> one vmem instruction gathers TWO 256B rows.
// Edge loop unrolled x8 (16 gathers in flight per wave batch).
__device__ __forceinline__ void unpack(long long p, int& s, float& w) {
  s = (int)(unsigned)(p & 0xffffffffll);
  w = __int_as_float((int)(p >> 32));
}

__global__ __launch_bounds__(256) void agg128h(const f16* __restrict__ H,
                                               const int* __restrict__ rp,
                                               const long long* __restrict__ csr,
                                               const float* __restrict__ dinv,
                                               const float* __restrict__ bias,
                                               f16* __restrict__ out, int n) {
  const int lane = threadIdx.x & 63;
  const int hl = lane & 31, side = lane >> 5;
  const int gw = (blockIdx.x * 256 + threadIdx.x) >> 6;
  const int nw = (gridDim.x * 256) >> 6;
  const int npairs = (n + 1) >> 1;
  const float4 bs = *(const float4*)&bias[hl * 4];
  for (int p = gw; p < npairs; p += nw) {
    const int i = p * 2 + side;
    const bool valid = (i < n);
    const int ic = valid ? i : 0;
    float di = dinv[ic];
    float dii = di * di;
    f16x4 hv = *(const f16x4*)&H[(size_t)ic * 128 + hl * 4];
    float a0 = fmaf((float)hv[0], dii, bs.x);
    float a1 = fmaf((float)hv[1], dii, bs.y);
    float a2 = fmaf((float)hv[2], dii, bs.z);
    float a3 = fmaf((float)hv[3], dii, bs.w);
    int e0 = rp[ic];
    int cnt = valid ? (rp[ic + 1] - e0) : 0;
    int maxc = max(cnt, __shfl_xor(cnt, 32));
    int j = 0;
    for (; j + 8 <= maxc; j += 8) {
      int xs[8];
      long long cc[8];
      int ss[8];
      float ww[8];
#pragma unroll
      for (int k = 0; k < 8; k++) xs[k] = (j + k < cnt) ? e0 + j + k : 0;
#pragma unroll
      for (int k = 0; k < 8; k++) cc[k] = csr[xs[k]];
#pragma unroll
      for (int k = 0; k < 8; k++) {
        unpack(cc[k], ss[k], ww[k]);
        if (j + k >= cnt) ww[k] = 0.f;
      }
      f16x4 vv[8];
#pragma unroll
      for (int k = 0; k < 8; k++)
        vv[k] = *(const f16x4*)&H[(size_t)ss[k] * 128 + hl * 4];
#pragma unroll
      for (int k = 0; k < 8; k++) {
        a0 = fmaf((float)vv[k][0], ww[k], a0);
        a1 = fmaf((float)vv[k][1], ww[k], a1);
        a2 = fmaf((float)vv[k][2], ww[k], a2);
        a3 = fmaf((float)vv[k][3], ww[k], a3);
      }
    }
    for (; j < maxc; j++) {
      int x0 = (j < cnt) ? e0 + j : 0;
      long long cc0 = csr[x0];
      int s0;
      float w0;
      unpack(cc0, s0, w0);
      if (j >= cnt) w0 = 0.f;
      f16x4 v0 = *(const f16x4*)&H[(size_t)s0 * 128 + hl * 4];
      a0 = fmaf((float)v0[0], w0, a0); a1 = fmaf((float)v0[1], w0, a1);
      a2 = fmaf((float)v0[2], w0, a2); a3 = fmaf((float)v0[3], w0, a3);
    }
    if (valid) {
      f16x4 h = {(f16)a0, (f16)a1, (f16)a2, (f16)a3};
      *(f16x4*)&out[(size_t)i * 128 + hl * 4] = h;
    }
  }
}

// layer-3: H padded to 64 cols; paired half-wave, 2 ch/lane; fp32 out (40 cols).
__global__ __launch_bounds__(256) void agg64h(const f16* __restrict__ H,
                                              const int* __restrict__ rp,
                                              const long long* __restrict__ csr,
                                              const float* __restrict__ dinv,
                                              const float* __restrict__ bias,
                                              float* __restrict__ out, int n) {
  const int lane = threadIdx.x & 63;
  const int hl = lane & 31, side = lane >> 5;
  const int gw = (blockIdx.x * 256 + threadIdx.x) >> 6;
  const int nw = (gridDim.x * 256) >> 6;
  const int npairs = (n + 1) >> 1;
  const int col0 = hl * 2, col1 = hl * 2 + 1;
  const float b0 = (col0 < 40) ? bias[col0] : 0.f;
  const float b1 = (col1 < 40) ? bias[col1] : 0.f;
  for (int p = gw; p < npairs; p += nw) {
    const int i = p * 2 + side;
    const bool valid = (i < n);
    const int ic = valid ? i : 0;
    float di = dinv[ic];
    float dii = di * di;
    float2 hf = __half22float2(*(const __half2*)&H[(size_t)ic * 64 + col0]);
    float a0 = fmaf(hf.x, dii, b0);
    float a1 = fmaf(hf.y, dii, b1);
    int e0 = rp[ic];
    int cnt = valid ? (rp[ic + 1] - e0) : 0;
    int maxc = max(cnt, __shfl_xor(cnt, 32));
    int j = 0;
    for (; j + 8 <= maxc; j += 8) {
      int xs[8];
      long long cc[8];
      int ss[8];
      float ww[8];
#pragma unroll
      for (int k = 0; k < 8; k++) xs[k] = (j + k < cnt) ? e0 + j + k : 0;
#pragma unroll
      for (int k = 0; k < 8; k++) cc[k] = csr[xs[k]];
#pragma unroll
      for (int k = 0; k < 8; k++) {
        unpack(cc[k], ss[k], ww[k]);
        if (j + k >= cnt) ww[k] = 0.f;
      }
      float2 vv[8];
#pragma unroll
      for (int k = 0; k < 8; k++)
        vv[k] = __half22float2(*(const __half2*)&H[(size_t)ss[k] * 64 + col0]);
#pragma unroll
      for (int k = 0; k < 8; k++) {
        a0 = fmaf(vv[k].x, ww[k], a0);
        a1 = fmaf(vv[k].y, ww[k], a1);
      }
    }
    for (; j < maxc; j++) {
      int x0 = (j < cnt) ? e0 + j : 0;
      long long cc0 = csr[x0];
      int s0;
      float w0;
      unpack(cc0, s0, w0);
      if (j >= cnt) w0 = 0.f;
      float2 v0 = __half22float2(*(const __half2*)&H[(size_t)s0 * 64 + col0]);
      a0 = fmaf(v0.x, w0, a0);
      a1 = fmaf(v0.y, w0, a1);
    }
    if (valid) {
      if (col0 < 40) out[(size_t)i * 40 + col0] = a0;
      if (col1 < 40) out[(size_t)i * 40 + col1] = a1;
    }
  }
}

// ============================ batchnorm stats (fp16 input) ============================
__global__ __launch_bounds__(256) void bn_stats_h(const f16* __restrict__ H, int n,
                                                  float* __restrict__ acc) {
  int t = threadIdx.x;
  int c2 = t & 63;
  int rg = t >> 6;
  float2 s = {0.f, 0.f}, s2 = {0.f, 0.f};
  for (int r = blockIdx.x * 4 + rg; r < n; r += gridDim.x * 4) {
    float2 v = __half22float2(*(const __half2*)&H[(size_t)r * 128 + c2 * 2]);
    s.x += v.x;
    s.y += v.y;
    s2.x = fmaf(v.x, v.x, s2.x);
    s2.y = fmaf(v.y, v.y, s2.y);
  }
  __shared__ float ls[4][128], ls2[4][128];
  ls[rg][c2 * 2] = s.x;
  ls[rg][c2 * 2 + 1] = s.y;
  ls2[rg][c2 * 2] = s2.x;
  ls2[rg][c2 * 2 + 1] = s2.y;
  __syncthreads();
  if (t < 128) {
    float a_ = ls[0][t] + ls[1][t] + ls[2][t] + ls[3][t];
    float b_ = ls2[0][t] + ls2[1][t] + ls2[2][t] + ls2[3][t];
    atomicAdd(&acc[t], a_);
    atomicAdd(&acc[128 + t], b_);
  }
}

// ============================ launch ============================
extern "C" void kernel_launch(void* const* d_in, const int* in_sizes, int n_in,
                              void* d_out, int out_size, void* d_ws, size_t ws_size,
                              hipStream_t stream) {
  const float* x = (const float*)d_in[0];
  const void* eb = d_in[1];
  const float* W1 = (const float*)d_in[2];
  const float* b1 = (const float*)d_in[3];
  const float* g1 = (const float*)d_in[4];
  const float* bt1 = (const float*)d_in[5];
  const float* W2 = (const float*)d_in[6];
  const float* b2 = (const float*)d_in[7];
  const float* g2 = (const float*)d_in[8];
  const float* bt2 = (const float*)d_in[9];
  const float* W3 = (const float*)d_in[10];
  const float* b3 = (const float*)d_in[11];

  const int n = in_sizes[0] / 128;
  const int E = in_sizes[1] / 2;
  const float inv_n = 1.0f / (float)n;

  char* w = (char*)d_ws;
  auto alloc = [&](size_t bytes) {
    void* p = (void*)w;
    w += (bytes + 255) & ~(size_t)255;
    return p;
  };
  const int NBKT = (n + 511) / 512;  // buckets of 512 nodes (<= 256)
  f16* hA = (f16*)alloc((size_t)n * 128 * 2);
  f16* hB = (f16*)alloc((size_t)n * 128 * 2);
  int2* csr = (int2*)alloc((size_t)E * 8);
  int2* part = (int2*)alloc((size_t)NBKT * BCAP * 8);
  float* dinv = (float*)alloc((size_t)n * 4);
  int* rp = (int*)alloc((size_t)(n + 1) * 4);
  int* bsum = (int*)alloc(512 * 4);
  f16* Wt1 = (f16*)alloc(128 * 128 * 2);
  f16* Wt2 = (f16*)alloc(128 * 128 * 2);
  f16* Wt3 = (f16*)alloc(64 * 128 * 2);
  // contiguous zero region:
  int* counts = (int*)alloc((size_t)n * 4);
  int* pcur = (int*)alloc(256 * 4);
  float* bn_acc1 = (float*)alloc(256 * 4);
  float* bn_acc2 = (float*)alloc(256 * 4);
  int* flag = (int*)alloc(256);
  size_t zbytes = (char*)flag + 256 - (char*)counts;
  hipMemsetAsync(counts, 0, zbytes, stream);

  const int NB = (n + 255) / 256;
  const int PB = (E + PCHUNK - 1) / PCHUNK;

  prep_all<<<320, 128, 0, stream>>>(W1, W2, W3, Wt1, Wt2, Wt3);

  detect_k<<<1, 256, 0, stream>>>((const unsigned*)eb, E, flag);
  part_k<<<PB, 256, 0, stream>>>(eb, E, flag, counts, pcur, part);
  scan1_k<<<NB, 256, 0, stream>>>(counts, bsum, dinv, n);
  scanF_k<<<NB, 256, 0, stream>>>(counts, bsum, rp, n, E);
  sort_k<<<NBKT, 512, 0, stream>>>(part, pcur, rp, dinv, csr, n);

  const int GB = (n + 127) / 128;  // gemm blocks
  const int AGB = 4096;            // agg blocks (grid-stride, 16K waves)

  // layer 1
  gemm_mfma<128, false, true><<<GB, 256, 0, stream>>>(x, Wt1, nullptr, nullptr,
                                                      nullptr, inv_n, hA, n);
  agg128h<<<AGB, 256, 0, stream>>>(hA, rp, (const long long*)csr, dinv, b1, hB, n);
  bn_stats_h<<<1024, 256, 0, stream>>>(hB, n, bn_acc1);
  // layer 2 (BN scale/shift computed inside GEMM from raw sums)
  gemm_mfma<128, true, false><<<GB, 256, 0, stream>>>(hB, Wt2, bn_acc1, g1, bt1,
                                                      inv_n, hA, n);
  agg128h<<<AGB, 256, 0, stream>>>(hA, rp, (const long long*)csr, dinv, b2, hB, n);
  bn_stats_h<<<1024, 256, 0, stream>>>(hB, n, bn_acc2);
  // layer 3 (H padded to 64 cols for line-aligned gathers)
  gemm_mfma<64, true, false><<<GB, 256, 0, stream>>>(hB, Wt3, bn_acc2, g2, bt2,
                                                     inv_n, hA, n);
  agg64h<<<AGB, 256, 0, stream>>>(hA, rp, (const long long*)csr, dinv, b3,
                                  (float*)d_out, n);
}

// Round 10
// 461.047 us; speedup vs baseline: 1.5414x; 1.1424x over previous
//
#include <hip/hip_runtime.h>
#include <hip/hip_fp16.h>
#include <cstdint>

#define BN_EPS 1e-5f
#define PCHUNK 4096
#define BCAP 16384  // per-bucket capacity (mean ~8.2K for uniform dst + padding)

typedef _Float16 f16;
typedef _Float16 f16x8 __attribute__((ext_vector_type(8)));
typedef _Float16 f16x4 __attribute__((ext_vector_type(4)));
typedef float f32x4 __attribute__((ext_vector_type(4)));

// ============================ edge preprocessing ============================

// Detect int64 vs int32 edge buffer (JAX may canonicalize int64 -> int32).
__global__ void detect_k(const unsigned* __restrict__ eb, int E,
                         int* __restrict__ flag) {
  int t = threadIdx.x;  // 256
  int cov = min(2048, E);
  int nz = 0;
  for (int k = t; k < cov; k += 256) nz |= (eb[2 * k + 1] != 0u);
  if (nz) atomicOr(flag, 1);
}

__device__ __forceinline__ void load_edge(const void* eb, int E, bool w64,
                                          int e, int& s, int& d) {
  if (w64) {
    const long long* p = (const long long*)eb;
    s = (int)p[e];
    d = (int)p[E + e];
  } else {
    const int* p = (const int*)eb;
    s = p[e];
    d = p[E + e];
  }
}

// --- partition: block-local bucket grouping -> 64B-aligned contiguous runs ---
// No per-edge global atomics; 196 bucket-level atomics per block only.
__global__ __launch_bounds__(256) void part_k(const void* __restrict__ eb, int E,
                                              const int* __restrict__ flag,
                                              int* __restrict__ realtot,
                                              int* __restrict__ pcur,
                                              int2* __restrict__ part) {
  __shared__ int hist[256], lofs[256], gbase[256], lcur[256];
  __shared__ int sa[256], sb[256];
  __shared__ int2 stage[PCHUNK];  // 32KB
  bool w64 = (*flag == 0);
  const int t = threadIdx.x;
  const int e0 = blockIdx.x * PCHUNK;
  const int cnt = min(PCHUNK, E - e0);
  hist[t] = 0;
  __syncthreads();
  int2 ed[16];
#pragma unroll
  for (int k = 0; k < 16; k++) {
    int idx = t + k * 256;
    if (idx < cnt) {
      int s, d;
      load_edge(eb, E, w64, e0 + idx, s, d);
      ed[k].x = s;
      ed[k].y = d;
      atomicAdd(&hist[d >> 9], 1);
    }
  }
  __syncthreads();
  // exclusive scan of hist -> lofs
  sa[t] = hist[t];
  __syncthreads();
  int* src = sa;
  int* dst = sb;
  for (int off = 1; off < 256; off <<= 1) {
    int val = src[t] + (t >= off ? src[t - off] : 0);
    dst[t] = val;
    __syncthreads();
    int* tmp = src; src = dst; dst = tmp;
  }
  int c = hist[t];
  lofs[t] = src[t] - c;
  int cpad = (c + 7) & ~7;  // 64B-aligned reservation
  gbase[t] = (c > 0) ? (t * BCAP + atomicAdd(&pcur[t], cpad)) : 0;
  if (c > 0) atomicAdd(&realtot[t], c);
  lcur[t] = src[t] - c;
  __syncthreads();
  // place into staging, grouped by bucket
#pragma unroll
  for (int k = 0; k < 16; k++) {
    int idx = t + k * 256;
    if (idx < cnt) {
      int b = ed[k].y >> 9;
      int p = atomicAdd(&lcur[b], 1);
      stage[p] = ed[k];
    }
  }
  __syncthreads();
  // stream out: each bucket-run lands contiguously at its 64B-aligned base
  for (int idx = t; idx < cnt; idx += 256) {
    int2 e = stage[idx];
    int b = e.y >> 9;
    part[gbase[b] + (idx - lofs[b])] = e;
  }
  // sentinel padding (dst=-1) to fill the aligned tail
  if (c > 0) {
    for (int k = c; k < cpad; k++) part[gbase[t] + k] = make_int2(0, -1);
  }
}

// --- tiny scan of real bucket totals -> bucket csr bases ---
__global__ void bscan_k(const int* __restrict__ realtot, int* __restrict__ rbase,
                        int* __restrict__ rp, int nbkt, int n, int E) {
  __shared__ int sa[256], sb[256];
  int t = threadIdx.x;  // 256
  int v = (t < nbkt) ? realtot[t] : 0;
  sa[t] = v;
  __syncthreads();
  int* src = sa;
  int* dst = sb;
  for (int off = 1; off < 256; off <<= 1) {
    int val = src[t] + (t >= off ? src[t - off] : 0);
    dst[t] = val;
    __syncthreads();
    int* tmp = src; src = dst; dst = tmp;
  }
  rbase[t] = src[t] - v;
  if (t == 0) rp[n] = E;
}

// --- per-bucket: local degree histogram -> rp, dinv, csr placement ---
// csr stores src only (4B); scatter window ~32KB, L2-resident -> no write amp.
__global__ __launch_bounds__(512) void sort_k(const int2* __restrict__ part,
                                              const int* __restrict__ pcur,
                                              const int* __restrict__ rbase,
                                              int* __restrict__ rp,
                                              float* __restrict__ dinv,
                                              int* __restrict__ csr, int n) {
  __shared__ int lhist[512], lcur[512];
  __shared__ int sa[512], sb[512];
  const int b = blockIdx.x;
  const int d0 = b << 9;
  const int t = threadIdx.x;
  const int nloc = min(512, n - d0);
  lhist[t] = 0;
  __syncthreads();
  const int base = b * BCAP;
  const int T = pcur[b];
  for (int idx = t; idx < T; idx += 512) {
    int2 e = part[base + idx];
    if (e.y >= 0) atomicAdd(&lhist[e.y - d0], 1);
  }
  __syncthreads();
  sa[t] = lhist[t];
  __syncthreads();
  int* src = sa;
  int* dst = sb;
  for (int off = 1; off < 512; off <<= 1) {
    int val = src[t] + (t >= off ? src[t - off] : 0);
    dst[t] = val;
    __syncthreads();
    int* tmp = src; src = dst; dst = tmp;
  }
  int c = lhist[t];
  int gpos = rbase[b] + src[t] - c;
  if (t < nloc) {
    rp[d0 + t] = gpos;
    dinv[d0 + t] = rsqrtf((float)(c + 1));  // +1 self-loop
  }
  lcur[t] = gpos;
  __syncthreads();
  for (int idx = t; idx < T; idx += 512) {
    int2 e = part[base + idx];
    if (e.y >= 0) {
      int pos = atomicAdd(&lcur[e.y - d0], 1);
      csr[pos] = e.x;
    }
  }
}

// ============================ W prep: transpose + fp16 (single launch) ============
__global__ void prep_all(const float* __restrict__ W1, const float* __restrict__ W2,
                         const float* __restrict__ W3, f16* __restrict__ Wt1,
                         f16* __restrict__ Wt2, f16* __restrict__ Wt3) {
  int b = blockIdx.x, k = threadIdx.x;  // 128 threads
  if (b < 128) {
    Wt1[(size_t)b * 128 + k] = (f16)W1[(size_t)k * 128 + b];
  } else if (b < 256) {
    int nc = b - 128;
    Wt2[(size_t)nc * 128 + k] = (f16)W2[(size_t)k * 128 + nc];
  } else {
    int nc = b - 256;  // 0..63
    Wt3[(size_t)nc * 128 + k] = (nc < 40) ? (f16)W3[(size_t)k * 40 + nc] : (f16)0.f;
  }
}

// ============================ GEMM (MFMA f16, dinv-folded epilogue) ============
// H'[n][NCP] = dinv_row * act(X)[n][128] @ W[128][NCP]
template <int NCP, bool BN, bool F32IN>
__global__ __launch_bounds__(256) void gemm_mfma(const void* __restrict__ Xv,
                                                 const f16* __restrict__ Wt,
                                                 const float* __restrict__ bn_acc,
                                                 const float* __restrict__ g,
                                                 const float* __restrict__ bt,
                                                 float inv_n,
                                                 const float* __restrict__ dinv,
                                                 f16* __restrict__ H, int n) {
  constexpr int CB = NCP / 16;
  __shared__ f16 Xs[128][136];
  __shared__ f16 Ws[NCP][136];
  __shared__ float bnS[128], bnH[128];
  const int t = threadIdx.x;
  const int m0 = blockIdx.x * 128;

  if (BN) {
    if (t < 128) {
      float mean = bn_acc[t] * inv_n;
      float var = bn_acc[128 + t] * inv_n - mean * mean;
      float sc = g[t] * rsqrtf(var + BN_EPS);
      bnS[t] = sc;
      bnH[t] = fmaf(-mean, sc, bt[t]);
    }
    __syncthreads();
  }

  if constexpr (F32IN) {
    const float* X = (const float*)Xv;
#pragma unroll
    for (int p = 0; p < 16; p++) {
      int idx = p * 256 + t;
      int row = idx >> 5, c = (idx & 31) * 4;
      float4 v = make_float4(0.f, 0.f, 0.f, 0.f);
      if (m0 + row < n) v = *(const float4*)&X[(size_t)(m0 + row) * 128 + c];
      if (BN) {
        v.x = fmaxf(fmaf(v.x, bnS[c + 0], bnH[c + 0]), 0.f);
        v.y = fmaxf(fmaf(v.y, bnS[c + 1], bnH[c + 1]), 0.f);
        v.z = fmaxf(fmaf(v.z, bnS[c + 2], bnH[c + 2]), 0.f);
        v.w = fmaxf(fmaf(v.w, bnS[c + 3], bnH[c + 3]), 0.f);
      }
      f16x4 h = {(f16)v.x, (f16)v.y, (f16)v.z, (f16)v.w};
      *(f16x4*)&Xs[row][c] = h;
    }
  } else {
    const f16* X = (const f16*)Xv;
#pragma unroll
    for (int p = 0; p < 8; p++) {
      int idx = p * 256 + t;
      int row = idx >> 4, c = (idx & 15) * 8;
      f16x8 v = {0, 0, 0, 0, 0, 0, 0, 0};
      if (m0 + row < n) v = *(const f16x8*)&X[(size_t)(m0 + row) * 128 + c];
      if (BN) {
#pragma unroll
        for (int j = 0; j < 8; j++) {
          float f = (float)v[j];
          f = fmaxf(fmaf(f, bnS[c + j], bnH[c + j]), 0.f);
          v[j] = (f16)f;
        }
      }
      *(f16x8*)&Xs[row][c] = v;
    }
  }
#pragma unroll
  for (int idx = t; idx < NCP * 16; idx += 256) {
    int row = idx >> 4, c = (idx & 15) * 8;
    *(f16x8*)&Ws[row][c] = *(const f16x8*)&Wt[(size_t)row * 128 + c];
  }
  __syncthreads();

  const int w = t >> 6, l = t & 63;
  const int lr = l & 15, lq = l >> 4;
  f32x4 acc[2][CB];
#pragma unroll
  for (int i = 0; i < 2; i++)
#pragma unroll
    for (int j = 0; j < CB; j++) acc[i][j] = (f32x4){0.f, 0.f, 0.f, 0.f};

#pragma unroll
  for (int kb = 0; kb < 4; kb++) {
    f16x8 xf0 = *(const f16x8*)&Xs[w * 32 + lr][kb * 32 + lq * 8];
    f16x8 xf1 = *(const f16x8*)&Xs[w * 32 + 16 + lr][kb * 32 + lq * 8];
#pragma unroll
    for (int cb = 0; cb < CB; cb++) {
      f16x8 wf = *(const f16x8*)&Ws[cb * 16 + lr][kb * 32 + lq * 8];
      acc[0][cb] = __builtin_amdgcn_mfma_f32_16x16x32_f16(wf, xf0, acc[0][cb], 0, 0, 0);
      acc[1][cb] = __builtin_amdgcn_mfma_f32_16x16x32_f16(wf, xf1, acc[1][cb], 0, 0, 0);
    }
  }
#pragma unroll
  for (int rg = 0; rg < 2; rg++) {
    int row = m0 + w * 32 + rg * 16 + lr;
    if (row >= n) continue;
    float dv = dinv[row];
#pragma unroll
    for (int cb = 0; cb < CB; cb++) {
      int col = cb * 16 + lq * 4;
      f32x4 a = acc[rg][cb];
      f16x4 h = {(f16)(a[0] * dv), (f16)(a[1] * dv), (f16)(a[2] * dv),
                 (f16)(a[3] * dv)};
      *(f16x4*)&H[(size_t)row * NCP + col] = h;
    }
  }
}

// ============================ aggregation (gather, fp16 rows) ============================
// out[i][:] = dinv[i] * (H'[i][:] + sum_e H'[src[e]][:]) + bias
// Paired half-wave: nodes (2p, 2p+1) on lane halves; 4 ch/lane (8B loads);
// one vmem instruction gathers TWO 256B rows. Edge loop unrolled x8.
__global__ __launch_bounds__(256) void agg128h(const f16* __restrict__ H,
                                               const int* __restrict__ rp,
                                               const int* __restrict__ csr,
                                               const float* __restrict__ dinv,
                                               const float* __restrict__ bias,
                                               f16* __restrict__ out, int n) {
  const int lane = threadIdx.x & 63;
  const int hl = lane & 31, side = lane >> 5;
  const int gw = (blockIdx.x * 256 + threadIdx.x) >> 6;
  const int nw = (gridDim.x * 256) >> 6;
  const int npairs = (n + 1) >> 1;
  const float4 bs = *(const float4*)&bias[hl * 4];
  for (int p = gw; p < npairs; p += nw) {
    const int i = p * 2 + side;
    const bool valid = (i < n);
    const int ic = valid ? i : 0;
    f16x4 hv = *(const f16x4*)&H[(size_t)ic * 128 + hl * 4];
    float a0 = (float)hv[0];
    float a1 = (float)hv[1];
    float a2 = (float)hv[2];
    float a3 = (float)hv[3];
    int e0 = rp[ic];
    int cnt = valid ? (rp[ic + 1] - e0) : 0;
    int maxc = max(cnt, __shfl_xor(cnt, 32));
    int j = 0;
    for (; j + 8 <= maxc; j += 8) {
      int xs[8], ss[8];
      float ww[8];
#pragma unroll
      for (int k = 0; k < 8; k++) xs[k] = (j + k < cnt) ? e0 + j + k : 0;
#pragma unroll
      for (int k = 0; k < 8; k++) ss[k] = csr[xs[k]];
#pragma unroll
      for (int k = 0; k < 8; k++) ww[k] = (j + k < cnt) ? 1.f : 0.f;
      f16x4 vv[8];
#pragma unroll
      for (int k = 0; k < 8; k++)
        vv[k] = *(const f16x4*)&H[(size_t)ss[k] * 128 + hl * 4];
#pragma unroll
      for (int k = 0; k < 8; k++) {
        a0 = fmaf((float)vv[k][0], ww[k], a0);
        a1 = fmaf((float)vv[k][1], ww[k], a1);
        a2 = fmaf((float)vv[k][2], ww[k], a2);
        a3 = fmaf((float)vv[k][3], ww[k], a3);
      }
    }
    for (; j < maxc; j++) {
      int x0 = (j < cnt) ? e0 + j : 0;
      int s0 = csr[x0];
      float w0 = (j < cnt) ? 1.f : 0.f;
      f16x4 v0 = *(const f16x4*)&H[(size_t)s0 * 128 + hl * 4];
      a0 = fmaf((float)v0[0], w0, a0); a1 = fmaf((float)v0[1], w0, a1);
      a2 = fmaf((float)v0[2], w0, a2); a3 = fmaf((float)v0[3], w0, a3);
    }
    if (valid) {
      float dv = dinv[ic];
      f16x4 h = {(f16)fmaf(a0, dv, bs.x), (f16)fmaf(a1, dv, bs.y),
                 (f16)fmaf(a2, dv, bs.z), (f16)fmaf(a3, dv, bs.w)};
      *(f16x4*)&out[(size_t)i * 128 + hl * 4] = h;
    }
  }
}

// layer-3: H padded to 64 cols; paired half-wave, 2 ch/lane; fp32 out (40 cols).
__global__ __launch_bounds__(256) void agg64h(const f16* __restrict__ H,
                                              const int* __restrict__ rp,
                                              const int* __restrict__ csr,
                                              const float* __restrict__ dinv,
                                              const float* __restrict__ bias,
                                              float* __restrict__ out, int n) {
  const int lane = threadIdx.x & 63;
  const int hl = lane & 31, side = lane >> 5;
  const int gw = (blockIdx.x * 256 + threadIdx.x) >> 6;
  const int nw = (gridDim.x * 256) >> 6;
  const int npairs = (n + 1) >> 1;
  const int col0 = hl * 2, col1 = hl * 2 + 1;
  const float b0 = (col0 < 40) ? bias[col0] : 0.f;
  const float b1 = (col1 < 40) ? bias[col1] : 0.f;
  for (int p = gw; p < npairs; p += nw) {
    const int i = p * 2 + side;
    const bool valid = (i < n);
    const int ic = valid ? i : 0;
    float2 hf = __half22float2(*(const __half2*)&H[(size_t)ic * 64 + col0]);
    float a0 = hf.x;
    float a1 = hf.y;
    int e0 = rp[ic];
    int cnt = valid ? (rp[ic + 1] - e0) : 0;
    int maxc = max(cnt, __shfl_xor(cnt, 32));
    int j = 0;
    for (; j + 8 <= maxc; j += 8) {
      int xs[8], ss[8];
      float ww[8];
#pragma unroll
      for (int k = 0; k < 8; k++) xs[k] = (j + k < cnt) ? e0 + j + k : 0;
#pragma unroll
      for (int k = 0; k < 8; k++) ss[k] = csr[xs[k]];
#pragma unroll
      for (int k = 0; k < 8; k++) ww[k] = (j + k < cnt) ? 1.f : 0.f;
      float2 vv[8];
#pragma unroll
      for (int k = 0; k < 8; k++)
        vv[k] = __half22float2(*(const __half2*)&H[(size_t)ss[k] * 64 + col0]);
#pragma unroll
      for (int k = 0; k < 8; k++) {
        a0 = fmaf(vv[k].x, ww[k], a0);
        a1 = fmaf(vv[k].y, ww[k], a1);
      }
    }
    for (; j < maxc; j++) {
      int x0 = (j < cnt) ? e0 + j : 0;
      int s0 = csr[x0];
      float w0 = (j < cnt) ? 1.f : 0.f;
      float2 v0 = __half22float2(*(const __half2*)&H[(size_t)s0 * 64 + col0]);
      a0 = fmaf(v0.x, w0, a0);
      a1 = fmaf(v0.y, w0, a1);
    }
    if (valid) {
      float dv = dinv[ic];
      if (col0 < 40) out[(size_t)i * 40 + col0] = fmaf(a0, dv, b0);
      if (col1 < 40) out[(size_t)i * 40 + col1] = fmaf(a1, dv, b1);
    }
  }
}

// ============================ batchnorm stats (fp16 input) ============================
__global__ __launch_bounds__(256) void bn_stats_h(const f16* __restrict__ H, int n,
                                                  float* __restrict__ acc) {
  int t = threadIdx.x;
  int c2 = t & 63;
  int rg = t >> 6;
  float2 s = {0.f, 0.f}, s2 = {0.f, 0.f};
  for (int r = blockIdx.x * 4 + rg; r < n; r += gridDim.x * 4) {
    float2 v = __half22float2(*(const __half2*)&H[(size_t)r * 128 + c2 * 2]);
    s.x += v.x;
    s.y += v.y;
    s2.x = fmaf(v.x, v.x, s2.x);
    s2.y = fmaf(v.y, v.y, s2.y);
  }
  __shared__ float ls[4][128], ls2[4][128];
  ls[rg][c2 * 2] = s.x;
  ls[rg][c2 * 2 + 1] = s.y;
  ls2[rg][c2 * 2] = s2.x;
  ls2[rg][c2 * 2 + 1] = s2.y;
  __syncthreads();
  if (t < 128) {
    float a_ = ls[0][t] + ls[1][t] + ls[2][t] + ls[3][t];
    float b_ = ls2[0][t] + ls2[1][t] + ls2[2][t] + ls2[3][t];
    atomicAdd(&acc[t], a_);
    atomicAdd(&acc[128 + t], b_);
  }
}

// ============================ launch ============================
extern "C" void kernel_launch(void* const* d_in, const int* in_sizes, int n_in,
                              void* d_out, int out_size, void* d_ws, size_t ws_size,
                              hipStream_t stream) {
  const float* x = (const float*)d_in[0];
  const void* eb = d_in[1];
  const float* W1 = (const float*)d_in[2];
  const float* b1 = (const float*)d_in[3];
  const float* g1 = (const float*)d_in[4];
  const float* bt1 = (const float*)d_in[5];
  const float* W2 = (const float*)d_in[6];
  const float* b2 = (const float*)d_in[7];
  const float* g2 = (const float*)d_in[8];
  const float* bt2 = (const float*)d_in[9];
  const float* W3 = (const float*)d_in[10];
  const float* b3 = (const float*)d_in[11];

  const int n = in_sizes[0] / 128;
  const int E = in_sizes[1] / 2;
  const float inv_n = 1.0f / (float)n;

  char* w = (char*)d_ws;
  auto alloc = [&](size_t bytes) {
    void* p = (void*)w;
    w += (bytes + 255) & ~(size_t)255;
    return p;
  };
  const int NBKT = (n + 511) / 512;  // buckets of 512 nodes (<= 256)
  f16* hA = (f16*)alloc((size_t)n * 128 * 2);
  f16* hB = (f16*)alloc((size_t)n * 128 * 2);
  int* csr = (int*)alloc((size_t)E * 4);
  int2* part = (int2*)alloc((size_t)NBKT * BCAP * 8);
  float* dinv = (float*)alloc((size_t)n * 4);
  int* rp = (int*)alloc((size_t)(n + 1) * 4);
  int* rbase = (int*)alloc(256 * 4);
  f16* Wt1 = (f16*)alloc(128 * 128 * 2);
  f16* Wt2 = (f16*)alloc(128 * 128 * 2);
  f16* Wt3 = (f16*)alloc(64 * 128 * 2);
  // contiguous zero region:
  int* pcur = (int*)alloc(256 * 4);
  int* realtot = (int*)alloc(256 * 4);
  float* bn_acc1 = (float*)alloc(256 * 4);
  float* bn_acc2 = (float*)alloc(256 * 4);
  int* flag = (int*)alloc(256);
  size_t zbytes = (char*)flag + 256 - (char*)pcur;
  hipMemsetAsync(pcur, 0, zbytes, stream);

  const int PB = (E + PCHUNK - 1) / PCHUNK;

  prep_all<<<320, 128, 0, stream>>>(W1, W2, W3, Wt1, Wt2, Wt3);

  detect_k<<<1, 256, 0, stream>>>((const unsigned*)eb, E, flag);
  part_k<<<PB, 256, 0, stream>>>(eb, E, flag, realtot, pcur, part);
  bscan_k<<<1, 256, 0, stream>>>(realtot, rbase, rp, NBKT, n, E);
  sort_k<<<NBKT, 512, 0, stream>>>(part, pcur, rbase, rp, dinv, csr, n);

  const int GB = (n + 127) / 128;  // gemm blocks
  const int AGB = 4096;            // agg blocks (grid-stride, 16K waves)

  // layer 1
  gemm_mfma<128, false, true><<<GB, 256, 0, stream>>>(x, Wt1, nullptr, nullptr,
                                                      nullptr, inv_n, dinv, hA, n);
  agg128h<<<AGB, 256, 0, stream>>>(hA, rp, csr, dinv, b1, hB, n);
  bn_stats_h<<<1024, 256, 0, stream>>>(hB, n, bn_acc1);
  // layer 2 (BN scale/shift computed inside GEMM from raw sums)
  gemm_mfma<128, true, false><<<GB, 256, 0, stream>>>(hB, Wt2, bn_acc1, g1, bt1,
                                                      inv_n, dinv, hA, n);
  agg128h<<<AGB, 256, 0, stream>>>(hA, rp, csr, dinv, b2, hB, n);
  bn_stats_h<<<1024, 256, 0, stream>>>(hB, n, bn_acc2);
  // layer 3 (H padded to 64 cols for line-aligned gathers)
  gemm_mfma<64, true, false><<<GB, 256, 0, stream>>>(hB, Wt3, bn_acc2, g2, bt2,
                                                     inv_n, dinv, hA, n);
  agg64h<<<AGB, 256, 0, stream>>>(hA, rp, csr, dinv, b3, (float*)d_out, n);
}

// Round 11
// 436.119 us; speedup vs baseline: 1.6296x; 1.0572x over previous
//
#include <hip/hip_runtime.h>
#include <hip/hip_fp16.h>
#include <cstdint>

#define BN_EPS 1e-5f
#define PCHUNK 4096
#define BCAP 16384  // per-bucket capacity (mean ~8.2K for uniform dst + padding)

typedef _Float16 f16;
typedef _Float16 f16x8 __attribute__((ext_vector_type(8)));
typedef _Float16 f16x4 __attribute__((ext_vector_type(4)));
typedef float f32x4 __attribute__((ext_vector_type(4)));

// ============================ edge preprocessing ============================

__device__ __forceinline__ void load_edge(const void* eb, int E, bool w64,
                                          int e, int& s, int& d) {
  if (w64) {
    const long long* p = (const long long*)eb;
    s = (int)p[e];
    d = (int)p[E + e];
  } else {
    const int* p = (const int*)eb;
    s = p[e];
    d = p[E + e];
  }
}

// --- partition: block-local bucket grouping -> 64B-aligned contiguous runs ---
// int64-vs-int32 detection is per-block (512 odd words of own chunk: for int64
// src values < 2^31 they are all 0; for int32 random indices ~never).
__global__ __launch_bounds__(256) void part_k(const void* __restrict__ eb, int E,
                                              int* __restrict__ realtot,
                                              int* __restrict__ pcur,
                                              int2* __restrict__ part) {
  __shared__ int hist[256], lofs[256], gbase[256], lcur[256];
  __shared__ int sa[256], sb[256];
  __shared__ int2 stage[PCHUNK];  // 32KB
  __shared__ int w64f;
  const int t = threadIdx.x;
  const int e0 = blockIdx.x * PCHUNK;
  const int cnt = min(PCHUNK, E - e0);
  hist[t] = 0;
  if (t == 0) w64f = 0;
  __syncthreads();
  {
    const unsigned* w = (const unsigned*)eb;
    int nz = 0;
    int cov = min(cnt, 512);
    for (int k = t; k < cov; k += 256) nz |= (w[2 * (size_t)(e0 + k) + 1] != 0u);
    if (nz) atomicOr(&w64f, 1);
  }
  __syncthreads();
  const bool w64 = (w64f == 0);
  int2 ed[16];
#pragma unroll
  for (int k = 0; k < 16; k++) {
    int idx = t + k * 256;
    if (idx < cnt) {
      int s, d;
      load_edge(eb, E, w64, e0 + idx, s, d);
      ed[k].x = s;
      ed[k].y = d;
      atomicAdd(&hist[d >> 9], 1);
    }
  }
  __syncthreads();
  // exclusive scan of hist -> lofs
  sa[t] = hist[t];
  __syncthreads();
  int* src = sa;
  int* dst = sb;
  for (int off = 1; off < 256; off <<= 1) {
    int val = src[t] + (t >= off ? src[t - off] : 0);
    dst[t] = val;
    __syncthreads();
    int* tmp = src; src = dst; dst = tmp;
  }
  int c = hist[t];
  lofs[t] = src[t] - c;
  int cpad = (c + 7) & ~7;  // 64B-aligned reservation
  gbase[t] = (c > 0) ? (t * BCAP + atomicAdd(&pcur[t], cpad)) : 0;
  if (c > 0) atomicAdd(&realtot[t], c);
  lcur[t] = src[t] - c;
  __syncthreads();
  // place into staging, grouped by bucket
#pragma unroll
  for (int k = 0; k < 16; k++) {
    int idx = t + k * 256;
    if (idx < cnt) {
      int b = ed[k].y >> 9;
      int p = atomicAdd(&lcur[b], 1);
      stage[p] = ed[k];
    }
  }
  __syncthreads();
  // stream out: each bucket-run lands contiguously at its 64B-aligned base
  for (int idx = t; idx < cnt; idx += 256) {
    int2 e = stage[idx];
    int b = e.y >> 9;
    part[gbase[b] + (idx - lofs[b])] = e;
  }
  // sentinel padding (dst=-1) to fill the aligned tail
  if (c > 0) {
    for (int k = c; k < cpad; k++) part[gbase[t] + k] = make_int2(0, -1);
  }
}

// --- per-bucket: rbase prefix + local degree histogram -> rp, dinv, csr ---
// csr stores src only (4B); scatter window ~32KB, L2-resident -> no write amp.
__global__ __launch_bounds__(512) void sort_k(const int2* __restrict__ part,
                                              const int* __restrict__ pcur,
                                              const int* __restrict__ realtot,
                                              int* __restrict__ rp,
                                              float* __restrict__ dinv,
                                              int* __restrict__ csr, int n, int E,
                                              int nbkt) {
  __shared__ int lhist[512], lcur[512];
  __shared__ int sa[512], sb[512];
  const int b = blockIdx.x;
  const int d0 = b << 9;
  const int t = threadIdx.x;
  const int nloc = min(512, n - d0);
  // rbase = sum(realtot[0..b))
  int pacc = 0;
  for (int j = t; j < b; j += 512) pacc += realtot[j];
  sa[t] = pacc;
  __syncthreads();
  for (int off = 256; off > 0; off >>= 1) {
    if (t < off) sa[t] += sa[t + off];
    __syncthreads();
  }
  const int rbase = sa[0];
  __syncthreads();

  lhist[t] = 0;
  __syncthreads();
  const int base = b * BCAP;
  const int T = pcur[b];
  for (int idx = t; idx < T; idx += 512) {
    int2 e = part[base + idx];
    if (e.y >= 0) atomicAdd(&lhist[e.y - d0], 1);
  }
  __syncthreads();
  sa[t] = lhist[t];
  __syncthreads();
  int* src = sa;
  int* dst = sb;
  for (int off = 1; off < 512; off <<= 1) {
    int val = src[t] + (t >= off ? src[t - off] : 0);
    dst[t] = val;
    __syncthreads();
    int* tmp = src; src = dst; dst = tmp;
  }
  int c = lhist[t];
  int gpos = rbase + src[t] - c;
  if (t < nloc) {
    rp[d0 + t] = gpos;
    dinv[d0 + t] = rsqrtf((float)(c + 1));  // +1 self-loop
  }
  lcur[t] = gpos;
  if (b == nbkt - 1 && t == 0) rp[n] = E;
  __syncthreads();
  for (int idx = t; idx < T; idx += 512) {
    int2 e = part[base + idx];
    if (e.y >= 0) {
      int pos = atomicAdd(&lcur[e.y - d0], 1);
      csr[pos] = e.x;
    }
  }
}

// ============================ W prep: transpose + fp16 (single launch) ============
__global__ void prep_all(const float* __restrict__ W1, const float* __restrict__ W2,
                         const float* __restrict__ W3, f16* __restrict__ Wt1,
                         f16* __restrict__ Wt2, f16* __restrict__ Wt3) {
  int b = blockIdx.x, k = threadIdx.x;  // 128 threads
  if (b < 128) {
    Wt1[(size_t)b * 128 + k] = (f16)W1[(size_t)k * 128 + b];
  } else if (b < 256) {
    int nc = b - 128;
    Wt2[(size_t)nc * 128 + k] = (f16)W2[(size_t)k * 128 + nc];
  } else {
    int nc = b - 256;  // 0..63
    Wt3[(size_t)nc * 128 + k] = (nc < 40) ? (f16)W3[(size_t)k * 40 + nc] : (f16)0.f;
  }
}

// ============================ GEMM (MFMA f16, dinv-folded epilogue) ============
// H'[n][NCP] = dinv_row * act(X)[n][128] @ W[128][NCP]
template <int NCP, bool BN, bool F32IN>
__global__ __launch_bounds__(256) void gemm_mfma(const void* __restrict__ Xv,
                                                 const f16* __restrict__ Wt,
                                                 const float* __restrict__ bn_acc,
                                                 const float* __restrict__ g,
                                                 const float* __restrict__ bt,
                                                 float inv_n,
                                                 const float* __restrict__ dinv,
                                                 f16* __restrict__ H, int n) {
  constexpr int CB = NCP / 16;
  __shared__ f16 Xs[128][136];
  __shared__ f16 Ws[NCP][136];
  __shared__ float bnS[128], bnH[128];
  const int t = threadIdx.x;
  const int m0 = blockIdx.x * 128;

  if (BN) {
    if (t < 128) {
      float mean = bn_acc[t] * inv_n;
      float var = bn_acc[128 + t] * inv_n - mean * mean;
      float sc = g[t] * rsqrtf(var + BN_EPS);
      bnS[t] = sc;
      bnH[t] = fmaf(-mean, sc, bt[t]);
    }
    __syncthreads();
  }

  if constexpr (F32IN) {
    const float* X = (const float*)Xv;
#pragma unroll
    for (int p = 0; p < 16; p++) {
      int idx = p * 256 + t;
      int row = idx >> 5, c = (idx & 31) * 4;
      float4 v = make_float4(0.f, 0.f, 0.f, 0.f);
      if (m0 + row < n) v = *(const float4*)&X[(size_t)(m0 + row) * 128 + c];
      if (BN) {
        v.x = fmaxf(fmaf(v.x, bnS[c + 0], bnH[c + 0]), 0.f);
        v.y = fmaxf(fmaf(v.y, bnS[c + 1], bnH[c + 1]), 0.f);
        v.z = fmaxf(fmaf(v.z, bnS[c + 2], bnH[c + 2]), 0.f);
        v.w = fmaxf(fmaf(v.w, bnS[c + 3], bnH[c + 3]), 0.f);
      }
      f16x4 h = {(f16)v.x, (f16)v.y, (f16)v.z, (f16)v.w};
      *(f16x4*)&Xs[row][c] = h;
    }
  } else {
    const f16* X = (const f16*)Xv;
#pragma unroll
    for (int p = 0; p < 8; p++) {
      int idx = p * 256 + t;
      int row = idx >> 4, c = (idx & 15) * 8;
      f16x8 v = {0, 0, 0, 0, 0, 0, 0, 0};
      if (m0 + row < n) v = *(const f16x8*)&X[(size_t)(m0 + row) * 128 + c];
      if (BN) {
#pragma unroll
        for (int j = 0; j < 8; j++) {
          float f = (float)v[j];
          f = fmaxf(fmaf(f, bnS[c + j], bnH[c + j]), 0.f);
          v[j] = (f16)f;
        }
      }
      *(f16x8*)&Xs[row][c] = v;
    }
  }
#pragma unroll
  for (int idx = t; idx < NCP * 16; idx += 256) {
    int row = idx >> 4, c = (idx & 15) * 8;
    *(f16x8*)&Ws[row][c] = *(const f16x8*)&Wt[(size_t)row * 128 + c];
  }
  __syncthreads();

  const int w = t >> 6, l = t & 63;
  const int lr = l & 15, lq = l >> 4;
  f32x4 acc[2][CB];
#pragma unroll
  for (int i = 0; i < 2; i++)
#pragma unroll
    for (int j = 0; j < CB; j++) acc[i][j] = (f32x4){0.f, 0.f, 0.f, 0.f};

#pragma unroll
  for (int kb = 0; kb < 4; kb++) {
    f16x8 xf0 = *(const f16x8*)&Xs[w * 32 + lr][kb * 32 + lq * 8];
    f16x8 xf1 = *(const f16x8*)&Xs[w * 32 + 16 + lr][kb * 32 + lq * 8];
#pragma unroll
    for (int cb = 0; cb < CB; cb++) {
      f16x8 wf = *(const f16x8*)&Ws[cb * 16 + lr][kb * 32 + lq * 8];
      acc[0][cb] = __builtin_amdgcn_mfma_f32_16x16x32_f16(wf, xf0, acc[0][cb], 0, 0, 0);
      acc[1][cb] = __builtin_amdgcn_mfma_f32_16x16x32_f16(wf, xf1, acc[1][cb], 0, 0, 0);
    }
  }
#pragma unroll
  for (int rg = 0; rg < 2; rg++) {
    int row = m0 + w * 32 + rg * 16 + lr;
    if (row >= n) continue;
    float dv = dinv[row];
#pragma unroll
    for (int cb = 0; cb < CB; cb++) {
      int col = cb * 16 + lq * 4;
      f32x4 a = acc[rg][cb];
      f16x4 h = {(f16)(a[0] * dv), (f16)(a[1] * dv), (f16)(a[2] * dv),
                 (f16)(a[3] * dv)};
      *(f16x4*)&H[(size_t)row * NCP + col] = h;
    }
  }
}

// ============================ aggregation (gather, fp16 rows) ============================
// out[i][:] = dinv[i] * (H'[i][:] + sum_e H'[src[e]][:]) + bias
// QUAD scheme: nodes (4q..4q+3) on 16-lane groups; 8 ch/lane (16B dwordx4
// loads) -> ONE vmem instruction gathers FOUR 256B rows. Unroll x8 -> 32 rows
// in flight per wave batch. Degree padding reads row 0 (L1-hot, free).
__global__ __launch_bounds__(256) void agg128h(const f16* __restrict__ H,
                                               const int* __restrict__ rp,
                                               const int* __restrict__ csr,
                                               const float* __restrict__ dinv,
                                               const float* __restrict__ bias,
                                               f16* __restrict__ out, int n) {
  const int lane = threadIdx.x & 63;
  const int sub = lane >> 4;   // node slot 0..3
  const int cl = lane & 15;    // channel group: ch cl*8 .. +7
  const int gw = (blockIdx.x * 256 + threadIdx.x) >> 6;
  const int nw = (gridDim.x * 256) >> 6;
  const int nquads = (n + 3) >> 2;
  for (int q = gw; q < nquads; q += nw) {
    const int i = q * 4 + sub;
    const bool valid = (i < n);
    const int ic = valid ? i : 0;
    f16x8 hv = *(const f16x8*)&H[(size_t)ic * 128 + cl * 8];
    float a[8];
#pragma unroll
    for (int c = 0; c < 8; c++) a[c] = (float)hv[c];
    int e0 = rp[ic];
    int cnt = valid ? (rp[ic + 1] - e0) : 0;
    int m = max(cnt, __shfl_xor(cnt, 16));
    m = max(m, __shfl_xor(m, 32));
    int j = 0;
    for (; j + 8 <= m; j += 8) {
      int ss[8];
#pragma unroll
      for (int k = 0; k < 8; k++) ss[k] = csr[(j + k < cnt) ? e0 + j + k : 0];
      f16x8 vv[8];
#pragma unroll
      for (int k = 0; k < 8; k++)
        vv[k] = *(const f16x8*)&H[(size_t)ss[k] * 128 + cl * 8];
#pragma unroll
      for (int k = 0; k < 8; k++) {
        float wk = (j + k < cnt) ? 1.f : 0.f;
#pragma unroll
        for (int c = 0; c < 8; c++) a[c] = fmaf((float)vv[k][c], wk, a[c]);
      }
    }
    for (; j < m; j++) {
      int s0 = csr[(j < cnt) ? e0 + j : 0];
      f16x8 v0 = *(const f16x8*)&H[(size_t)s0 * 128 + cl * 8];
      float wk = (j < cnt) ? 1.f : 0.f;
#pragma unroll
      for (int c = 0; c < 8; c++) a[c] = fmaf((float)v0[c], wk, a[c]);
    }
    if (valid) {
      float dv = dinv[ic];
      float4 b0 = *(const float4*)&bias[cl * 8];
      float4 b1 = *(const float4*)&bias[cl * 8 + 4];
      f16x8 h;
      h[0] = (f16)fmaf(a[0], dv, b0.x);
      h[1] = (f16)fmaf(a[1], dv, b0.y);
      h[2] = (f16)fmaf(a[2], dv, b0.z);
      h[3] = (f16)fmaf(a[3], dv, b0.w);
      h[4] = (f16)fmaf(a[4], dv, b1.x);
      h[5] = (f16)fmaf(a[5], dv, b1.y);
      h[6] = (f16)fmaf(a[6], dv, b1.z);
      h[7] = (f16)fmaf(a[7], dv, b1.w);
      *(f16x8*)&out[(size_t)i * 128 + cl * 8] = h;
    }
  }
}

// layer-3: H padded to 64 cols (128B rows); QUAD scheme, 4 ch/lane (8B loads)
// -> one vmem instr gathers four 128B rows. Output: 40 = 10 x float4 stores.
__global__ __launch_bounds__(256) void agg64h(const f16* __restrict__ H,
                                              const int* __restrict__ rp,
                                              const int* __restrict__ csr,
                                              const float* __restrict__ dinv,
                                              const float* __restrict__ bias,
                                              float* __restrict__ out, int n) {
  const int lane = threadIdx.x & 63;
  const int sub = lane >> 4;   // node slot 0..3
  const int cl = lane & 15;    // channel group: ch cl*4 .. +3
  const int gw = (blockIdx.x * 256 + threadIdx.x) >> 6;
  const int nw = (gridDim.x * 256) >> 6;
  const int nquads = (n + 3) >> 2;
  for (int q = gw; q < nquads; q += nw) {
    const int i = q * 4 + sub;
    const bool valid = (i < n);
    const int ic = valid ? i : 0;
    f16x4 hv = *(const f16x4*)&H[(size_t)ic * 64 + cl * 4];
    float a0 = (float)hv[0], a1 = (float)hv[1], a2 = (float)hv[2],
          a3 = (float)hv[3];
    int e0 = rp[ic];
    int cnt = valid ? (rp[ic + 1] - e0) : 0;
    int m = max(cnt, __shfl_xor(cnt, 16));
    m = max(m, __shfl_xor(m, 32));
    int j = 0;
    for (; j + 8 <= m; j += 8) {
      int ss[8];
#pragma unroll
      for (int k = 0; k < 8; k++) ss[k] = csr[(j + k < cnt) ? e0 + j + k : 0];
      f16x4 vv[8];
#pragma unroll
      for (int k = 0; k < 8; k++)
        vv[k] = *(const f16x4*)&H[(size_t)ss[k] * 64 + cl * 4];
#pragma unroll
      for (int k = 0; k < 8; k++) {
        float wk = (j + k < cnt) ? 1.f : 0.f;
        a0 = fmaf((float)vv[k][0], wk, a0);
        a1 = fmaf((float)vv[k][1], wk, a1);
        a2 = fmaf((float)vv[k][2], wk, a2);
        a3 = fmaf((float)vv[k][3], wk, a3);
      }
    }
    for (; j < m; j++) {
      int s0 = csr[(j < cnt) ? e0 + j : 0];
      f16x4 v0 = *(const f16x4*)&H[(size_t)s0 * 64 + cl * 4];
      float wk = (j < cnt) ? 1.f : 0.f;
      a0 = fmaf((float)v0[0], wk, a0);
      a1 = fmaf((float)v0[1], wk, a1);
      a2 = fmaf((float)v0[2], wk, a2);
      a3 = fmaf((float)v0[3], wk, a3);
    }
    if (valid && cl < 10) {
      float dv = dinv[ic];
      float4 bb = *(const float4*)&bias[cl * 4];
      float4 o;
      o.x = fmaf(a0, dv, bb.x);
      o.y = fmaf(a1, dv, bb.y);
      o.z = fmaf(a2, dv, bb.z);
      o.w = fmaf(a3, dv, bb.w);
      *(float4*)&out[(size_t)i * 40 + cl * 4] = o;
    }
  }
}

// ============================ batchnorm stats (fp16 input) ============================
__global__ __launch_bounds__(256) void bn_stats_h(const f16* __restrict__ H, int n,
                                                  float* __restrict__ acc) {
  int t = threadIdx.x;
  int c2 = t & 63;
  int rg = t >> 6;
  float2 s = {0.f, 0.f}, s2 = {0.f, 0.f};
  for (int r = blockIdx.x * 4 + rg; r < n; r += gridDim.x * 4) {
    float2 v = __half22float2(*(const __half2*)&H[(size_t)r * 128 + c2 * 2]);
    s.x += v.x;
    s.y += v.y;
    s2.x = fmaf(v.x, v.x, s2.x);
    s2.y = fmaf(v.y, v.y, s2.y);
  }
  __shared__ float ls[4][128], ls2[4][128];
  ls[rg][c2 * 2] = s.x;
  ls[rg][c2 * 2 + 1] = s.y;
  ls2[rg][c2 * 2] = s2.x;
  ls2[rg][c2 * 2 + 1] = s2.y;
  __syncthreads();
  if (t < 128) {
    float a_ = ls[0][t] + ls[1][t] + ls[2][t] + ls[3][t];
    float b_ = ls2[0][t] + ls2[1][t] + ls2[2][t] + ls2[3][t];
    atomicAdd(&acc[t], a_);
    atomicAdd(&acc[128 + t], b_);
  }
}

// ============================ launch ============================
extern "C" void kernel_launch(void* const* d_in, const int* in_sizes, int n_in,
                              void* d_out, int out_size, void* d_ws, size_t ws_size,
                              hipStream_t stream) {
  const float* x = (const float*)d_in[0];
  const void* eb = d_in[1];
  const float* W1 = (const float*)d_in[2];
  const float* b1 = (const float*)d_in[3];
  const float* g1 = (const float*)d_in[4];
  const float* bt1 = (const float*)d_in[5];
  const float* W2 = (const float*)d_in[6];
  const float* b2 = (const float*)d_in[7];
  const float* g2 = (const float*)d_in[8];
  const float* bt2 = (const float*)d_in[9];
  const float* W3 = (const float*)d_in[10];
  const float* b3 = (const float*)d_in[11];

  const int n = in_sizes[0] / 128;
  const int E = in_sizes[1] / 2;
  const float inv_n = 1.0f / (float)n;

  char* w = (char*)d_ws;
  auto alloc = [&](size_t bytes) {
    void* p = (void*)w;
    w += (bytes + 255) & ~(size_t)255;
    return p;
  };
  const int NBKT = (n + 511) / 512;  // buckets of 512 nodes (<= 256)
  f16* hA = (f16*)alloc((size_t)n * 128 * 2);
  f16* hB = (f16*)alloc((size_t)n * 128 * 2);
  int* csr = (int*)alloc((size_t)E * 4);
  int2* part = (int2*)alloc((size_t)NBKT * BCAP * 8);
  float* dinv = (float*)alloc((size_t)n * 4);
  int* rp = (int*)alloc((size_t)(n + 1) * 4);
  f16* Wt1 = (f16*)alloc(128 * 128 * 2);
  f16* Wt2 = (f16*)alloc(128 * 128 * 2);
  f16* Wt3 = (f16*)alloc(64 * 128 * 2);
  // contiguous zero region:
  int* pcur = (int*)alloc(256 * 4);
  int* realtot = (int*)alloc(256 * 4);
  float* bn_acc1 = (float*)alloc(256 * 4);
  float* bn_acc2 = (float*)alloc(256 * 4);
  size_t zbytes = (char*)bn_acc2 + 256 * 4 - (char*)pcur;
  hipMemsetAsync(pcur, 0, zbytes, stream);

  const int PB = (E + PCHUNK - 1) / PCHUNK;

  prep_all<<<320, 128, 0, stream>>>(W1, W2, W3, Wt1, Wt2, Wt3);

  part_k<<<PB, 256, 0, stream>>>(eb, E, realtot, pcur, part);
  sort_k<<<NBKT, 512, 0, stream>>>(part, pcur, realtot, rp, dinv, csr, n, E, NBKT);

  const int GB = (n + 127) / 128;  // gemm blocks
  const int AGB = 4096;            // agg blocks (grid-stride, 16K waves)

  // layer 1
  gemm_mfma<128, false, true><<<GB, 256, 0, stream>>>(x, Wt1, nullptr, nullptr,
                                                      nullptr, inv_n, dinv, hA, n);
  agg128h<<<AGB, 256, 0, stream>>>(hA, rp, csr, dinv, b1, hB, n);
  bn_stats_h<<<1024, 256, 0, stream>>>(hB, n, bn_acc1);
  // layer 2 (BN scale/shift computed inside GEMM from raw sums)
  gemm_mfma<128, true, false><<<GB, 256, 0, stream>>>(hB, Wt2, bn_acc1, g1, bt1,
                                                      inv_n, dinv, hA, n);
  agg128h<<<AGB, 256, 0, stream>>>(hA, rp, csr, dinv, b2, hB, n);
  bn_stats_h<<<1024, 256, 0, stream>>>(hB, n, bn_acc2);
  // layer 3 (H padded to 64 cols for line-aligned gathers)
  gemm_mfma<64, true, false><<<GB, 256, 0, stream>>>(hB, Wt3, bn_acc2, g2, bt2,
                                                     inv_n, dinv, hA, n);
  agg64h<<<AGB, 256, 0, stream>>>(hA, rp, csr, dinv, b3, (float*)d_out, n);
}

// Round 12
// 422.213 us; speedup vs baseline: 1.6832x; 1.0329x over previous
//
#include <hip/hip_runtime.h>
#include <hip/hip_fp16.h>
#include <cstdint>

#define BN_EPS 1e-5f
#define PCHUNK 4096
#define BCAP 16384    // per-bucket part capacity
#define CSRCAP 16384  // per-bucket csr capacity (padded degree sum ~10K max)

typedef _Float16 f16;
typedef _Float16 f16x8 __attribute__((ext_vector_type(8)));
typedef _Float16 f16x4 __attribute__((ext_vector_type(4)));
typedef float f32x4 __attribute__((ext_vector_type(4)));

// ============================ edge preprocessing ============================

__device__ __forceinline__ void load_edge(const void* eb, int E, bool w64,
                                          int e, int& s, int& d) {
  if (w64) {
    const long long* p = (const long long*)eb;
    s = (int)p[e];
    d = (int)p[E + e];
  } else {
    const int* p = (const int*)eb;
    s = p[e];
    d = p[E + e];
  }
}

// --- partition: block-local bucket grouping -> 64B-aligned contiguous runs ---
// 512 threads/block for store-path latency hiding. Per-block int64/int32 detect.
__global__ __launch_bounds__(512) void part_k(const void* __restrict__ eb, int E,
                                              int* __restrict__ pcur,
                                              int2* __restrict__ part) {
  __shared__ int hist[256], lofs[256], gbase[256], lcur[256];
  __shared__ int sa[256], sb[256];
  __shared__ int2 stage[PCHUNK];  // 32KB
  __shared__ int w64f;
  const int t = threadIdx.x;
  const int e0 = blockIdx.x * PCHUNK;
  const int cnt = min(PCHUNK, E - e0);
  if (t < 256) hist[t] = 0;
  if (t == 0) w64f = 0;
  __syncthreads();
  {
    const unsigned* w = (const unsigned*)eb;
    int nz = 0;
    int cov = min(cnt, 512);
    for (int k = t; k < cov; k += 512) nz |= (w[2 * (size_t)(e0 + k) + 1] != 0u);
    if (nz) atomicOr(&w64f, 1);
  }
  __syncthreads();
  const bool w64 = (w64f == 0);
  int2 ed[8];
#pragma unroll
  for (int k = 0; k < 8; k++) {
    int idx = t + k * 512;
    if (idx < cnt) {
      int s, d;
      load_edge(eb, E, w64, e0 + idx, s, d);
      ed[k].x = s;
      ed[k].y = d;
      atomicAdd(&hist[d >> 9], 1);
    }
  }
  __syncthreads();
  // exclusive scan of hist (256 entries) -> lofs
  if (t < 256) sa[t] = hist[t];
  __syncthreads();
  int* src = sa;
  int* dst = sb;
  for (int off = 1; off < 256; off <<= 1) {
    int val = 0;
    if (t < 256) val = src[t] + (t >= off ? src[t - off] : 0);
    __syncthreads();
    if (t < 256) dst[t] = val;
    __syncthreads();
    int* tmp = src; src = dst; dst = tmp;
  }
  int c = 0;
  if (t < 256) {
    c = hist[t];
    lofs[t] = src[t] - c;
    int cpad = (c + 7) & ~7;  // 64B-aligned reservation
    gbase[t] = (c > 0) ? (t * BCAP + atomicAdd(&pcur[t], cpad)) : 0;
    lcur[t] = src[t] - c;
  }
  __syncthreads();
  // place into staging, grouped by bucket
#pragma unroll
  for (int k = 0; k < 8; k++) {
    int idx = t + k * 512;
    if (idx < cnt) {
      int b = ed[k].y >> 9;
      int p = atomicAdd(&lcur[b], 1);
      stage[p] = ed[k];
    }
  }
  __syncthreads();
  // stream out: each bucket-run lands contiguously at its 64B-aligned base
  for (int idx = t; idx < cnt; idx += 512) {
    int2 e = stage[idx];
    int b = e.y >> 9;
    part[gbase[b] + (idx - lofs[b])] = e;
  }
  // sentinel padding (dst=-1) fills the aligned tail
  if (t < 256 && c > 0) {
    int cpad = (c + 7) & ~7;
    for (int k = c; k < cpad; k++) part[gbase[t] + k] = make_int2(0, -1);
  }
}

// --- per-bucket: local degree histogram -> rpc{start,cntp}, dinv, padded csr ---
// Each node's csr segment 8-aligned & padded with zero-row index n.
__global__ __launch_bounds__(512) void sort_k(const int2* __restrict__ part,
                                              const int* __restrict__ pcur,
                                              int2* __restrict__ rpc,
                                              float* __restrict__ dinv,
                                              int* __restrict__ csr, int n) {
  __shared__ int lhist[512], lcur[512], lstart[512];
  __shared__ int sa[512], sb[512];
  const int b = blockIdx.x;
  const int d0 = b << 9;
  const int t = threadIdx.x;
  const int nloc = min(512, n - d0);
  lhist[t] = 0;
  __syncthreads();
  const int base = b * BCAP;
  const int T = pcur[b];
  for (int idx = t; idx < T; idx += 512) {
    int2 e = part[base + idx];
    if (e.y >= 0) atomicAdd(&lhist[e.y - d0], 1);
  }
  __syncthreads();
  int c = lhist[t];
  int cpad = (c + 7) & ~7;
  sa[t] = cpad;
  __syncthreads();
  int* src = sa;
  int* dst = sb;
  for (int off = 1; off < 512; off <<= 1) {
    int val = src[t] + (t >= off ? src[t - off] : 0);
    __syncthreads();
    dst[t] = val;
    __syncthreads();
    int* tmp = src; src = dst; dst = tmp;
  }
  int start = b * CSRCAP + src[t] - cpad;
  if (t < nloc) {
    rpc[d0 + t] = make_int2(start, cpad);
    dinv[d0 + t] = rsqrtf((float)(c + 1));  // +1 self-loop
  }
  lstart[t] = start;
  lcur[t] = start;
  __syncthreads();
  for (int idx = t; idx < T; idx += 512) {
    int2 e = part[base + idx];
    if (e.y >= 0) {
      int pos = atomicAdd(&lcur[e.y - d0], 1);
      csr[pos] = e.x;
    }
  }
  // pad each segment tail with zero-row index n
  if (t < nloc) {
    for (int k = c; k < cpad; k++) csr[lstart[t] + k] = n;
  }
}

// ============================ W prep: transpose + fp16 (single launch) ============
__global__ void prep_all(const float* __restrict__ W1, const float* __restrict__ W2,
                         const float* __restrict__ W3, f16* __restrict__ Wt1,
                         f16* __restrict__ Wt2, f16* __restrict__ Wt3) {
  int b = blockIdx.x, k = threadIdx.x;  // 128 threads
  if (b < 128) {
    Wt1[(size_t)b * 128 + k] = (f16)W1[(size_t)k * 128 + b];
  } else if (b < 256) {
    int nc = b - 128;
    Wt2[(size_t)nc * 128 + k] = (f16)W2[(size_t)k * 128 + nc];
  } else {
    int nc = b - 256;  // 0..63
    Wt3[(size_t)nc * 128 + k] = (nc < 40) ? (f16)W3[(size_t)k * 40 + nc] : (f16)0.f;
  }
}

// ============================ GEMM (MFMA f16, dinv-folded epilogue) ============
// H'[row] = dinv[row] * act(X)[row] @ W ; row n (zero row) written as zeros.
template <int NCP, bool BN, bool F32IN>
__global__ __launch_bounds__(256) void gemm_mfma(const void* __restrict__ Xv,
                                                 const f16* __restrict__ Wt,
                                                 const float* __restrict__ bn_acc,
                                                 const float* __restrict__ g,
                                                 const float* __restrict__ bt,
                                                 float inv_n,
                                                 const float* __restrict__ dinv,
                                                 f16* __restrict__ H, int n) {
  constexpr int CB = NCP / 16;
  __shared__ f16 Xs[128][136];
  __shared__ f16 Ws[NCP][136];
  __shared__ float bnS[128], bnH[128];
  const int t = threadIdx.x;
  const int m0 = blockIdx.x * 128;

  if (BN) {
    if (t < 128) {
      float mean = bn_acc[t] * inv_n;
      float var = bn_acc[128 + t] * inv_n - mean * mean;
      float sc = g[t] * rsqrtf(var + BN_EPS);
      bnS[t] = sc;
      bnH[t] = fmaf(-mean, sc, bt[t]);
    }
    __syncthreads();
  }

  if constexpr (F32IN) {
    const float* X = (const float*)Xv;
#pragma unroll
    for (int p = 0; p < 16; p++) {
      int idx = p * 256 + t;
      int row = idx >> 5, c = (idx & 31) * 4;
      float4 v = make_float4(0.f, 0.f, 0.f, 0.f);
      if (m0 + row < n) v = *(const float4*)&X[(size_t)(m0 + row) * 128 + c];
      if (BN) {
        v.x = fmaxf(fmaf(v.x, bnS[c + 0], bnH[c + 0]), 0.f);
        v.y = fmaxf(fmaf(v.y, bnS[c + 1], bnH[c + 1]), 0.f);
        v.z = fmaxf(fmaf(v.z, bnS[c + 2], bnH[c + 2]), 0.f);
        v.w = fmaxf(fmaf(v.w, bnS[c + 3], bnH[c + 3]), 0.f);
      }
      f16x4 h = {(f16)v.x, (f16)v.y, (f16)v.z, (f16)v.w};
      *(f16x4*)&Xs[row][c] = h;
    }
  } else {
    const f16* X = (const f16*)Xv;
#pragma unroll
    for (int p = 0; p < 8; p++) {
      int idx = p * 256 + t;
      int row = idx >> 4, c = (idx & 15) * 8;
      f16x8 v = {0, 0, 0, 0, 0, 0, 0, 0};
      if (m0 + row < n) v = *(const f16x8*)&X[(size_t)(m0 + row) * 128 + c];
      if (BN) {
#pragma unroll
        for (int j = 0; j < 8; j++) {
          float f = (float)v[j];
          f = fmaxf(fmaf(f, bnS[c + j], bnH[c + j]), 0.f);
          v[j] = (f16)f;
        }
      }
      *(f16x8*)&Xs[row][c] = v;
    }
  }
#pragma unroll
  for (int idx = t; idx < NCP * 16; idx += 256) {
    int row = idx >> 4, c = (idx & 15) * 8;
    *(f16x8*)&Ws[row][c] = *(const f16x8*)&Wt[(size_t)row * 128 + c];
  }
  __syncthreads();

  const int w = t >> 6, l = t & 63;
  const int lr = l & 15, lq = l >> 4;
  f32x4 acc[2][CB];
#pragma unroll
  for (int i = 0; i < 2; i++)
#pragma unroll
    for (int j = 0; j < CB; j++) acc[i][j] = (f32x4){0.f, 0.f, 0.f, 0.f};

#pragma unroll
  for (int kb = 0; kb < 4; kb++) {
    f16x8 xf0 = *(const f16x8*)&Xs[w * 32 + lr][kb * 32 + lq * 8];
    f16x8 xf1 = *(const f16x8*)&Xs[w * 32 + 16 + lr][kb * 32 + lq * 8];
#pragma unroll
    for (int cb = 0; cb < CB; cb++) {
      f16x8 wf = *(const f16x8*)&Ws[cb * 16 + lr][kb * 32 + lq * 8];
      acc[0][cb] = __builtin_amdgcn_mfma_f32_16x16x32_f16(wf, xf0, acc[0][cb], 0, 0, 0);
      acc[1][cb] = __builtin_amdgcn_mfma_f32_16x16x32_f16(wf, xf1, acc[1][cb], 0, 0, 0);
    }
  }
#pragma unroll
  for (int rg = 0; rg < 2; rg++) {
    int row = m0 + w * 32 + rg * 16 + lr;
    if (row > n) continue;
    float dv = (row < n) ? dinv[row] : 0.f;  // row n -> zeros (padding row)
#pragma unroll
    for (int cb = 0; cb < CB; cb++) {
      int col = cb * 16 + lq * 4;
      f32x4 a = acc[rg][cb];
      f16x4 h = {(f16)(a[0] * dv), (f16)(a[1] * dv), (f16)(a[2] * dv),
                 (f16)(a[3] * dv)};
      *(f16x4*)&H[(size_t)row * NCP + col] = h;
    }
  }
}

// ============================ aggregation (gather, fp16 rows) ============================
// out[i][:] = dinv[i] * (H'[i][:] + sum_e H'[src[e]][:]) + bias
// QUAD: nodes (4q..4q+3) on 16-lane groups, 8 ch/lane (16B gathers) -> one vmem
// instruction fetches FOUR rows. Padded csr (zero-row) -> branchless inner loop,
// f16 pk-add accumulation. One quad per wave, exact grid.
__global__ __launch_bounds__(256) void agg128h(const f16* __restrict__ H,
                                               const int2* __restrict__ rpc,
                                               const int* __restrict__ csr,
                                               const float* __restrict__ dinv,
                                               const float* __restrict__ bias,
                                               f16* __restrict__ out, int n) {
  const int lane = threadIdx.x & 63;
  const int sub = lane >> 4, cl = lane & 15;
  const int q = (blockIdx.x * 256 + threadIdx.x) >> 6;
  const int i = q * 4 + sub;
  const bool valid = (i < n);
  const int ic = valid ? i : 0;
  f16x8 a = *(const f16x8*)&H[(size_t)ic * 128 + cl * 8];
  int2 rc = rpc[ic];
  const int e0 = rc.x, cntp = rc.y;
  for (int j = 0; j < cntp; j += 8) {
    int4 c0 = *(const int4*)&csr[e0 + j];
    int4 c1 = *(const int4*)&csr[e0 + j + 4];
    f16x8 v0 = *(const f16x8*)&H[(size_t)c0.x * 128 + cl * 8];
    f16x8 v1 = *(const f16x8*)&H[(size_t)c0.y * 128 + cl * 8];
    f16x8 v2 = *(const f16x8*)&H[(size_t)c0.z * 128 + cl * 8];
    f16x8 v3 = *(const f16x8*)&H[(size_t)c0.w * 128 + cl * 8];
    f16x8 v4 = *(const f16x8*)&H[(size_t)c1.x * 128 + cl * 8];
    f16x8 v5 = *(const f16x8*)&H[(size_t)c1.y * 128 + cl * 8];
    f16x8 v6 = *(const f16x8*)&H[(size_t)c1.z * 128 + cl * 8];
    f16x8 v7 = *(const f16x8*)&H[(size_t)c1.w * 128 + cl * 8];
    f16x8 t01 = v0 + v1;
    f16x8 t23 = v2 + v3;
    f16x8 t45 = v4 + v5;
    f16x8 t67 = v6 + v7;
    a = a + ((t01 + t23) + (t45 + t67));
  }
  if (valid) {
    float dv = dinv[ic];
    float4 b0 = *(const float4*)&bias[cl * 8];
    float4 b1 = *(const float4*)&bias[cl * 8 + 4];
    f16x8 h;
    h[0] = (f16)fmaf((float)a[0], dv, b0.x);
    h[1] = (f16)fmaf((float)a[1], dv, b0.y);
    h[2] = (f16)fmaf((float)a[2], dv, b0.z);
    h[3] = (f16)fmaf((float)a[3], dv, b0.w);
    h[4] = (f16)fmaf((float)a[4], dv, b1.x);
    h[5] = (f16)fmaf((float)a[5], dv, b1.y);
    h[6] = (f16)fmaf((float)a[6], dv, b1.z);
    h[7] = (f16)fmaf((float)a[7], dv, b1.w);
    *(f16x8*)&out[(size_t)i * 128 + cl * 8] = h;
  }
}

// layer-3: H padded to 64 cols (128B rows); QUAD, 4 ch/lane (8B gathers).
__global__ __launch_bounds__(256) void agg64h(const f16* __restrict__ H,
                                              const int2* __restrict__ rpc,
                                              const int* __restrict__ csr,
                                              const float* __restrict__ dinv,
                                              const float* __restrict__ bias,
                                              float* __restrict__ out, int n) {
  const int lane = threadIdx.x & 63;
  const int sub = lane >> 4, cl = lane & 15;
  const int q = (blockIdx.x * 256 + threadIdx.x) >> 6;
  const int i = q * 4 + sub;
  const bool valid = (i < n);
  const int ic = valid ? i : 0;
  f16x4 a = *(const f16x4*)&H[(size_t)ic * 64 + cl * 4];
  int2 rc = rpc[ic];
  const int e0 = rc.x, cntp = rc.y;
  for (int j = 0; j < cntp; j += 8) {
    int4 c0 = *(const int4*)&csr[e0 + j];
    int4 c1 = *(const int4*)&csr[e0 + j + 4];
    f16x4 v0 = *(const f16x4*)&H[(size_t)c0.x * 64 + cl * 4];
    f16x4 v1 = *(const f16x4*)&H[(size_t)c0.y * 64 + cl * 4];
    f16x4 v2 = *(const f16x4*)&H[(size_t)c0.z * 64 + cl * 4];
    f16x4 v3 = *(const f16x4*)&H[(size_t)c0.w * 64 + cl * 4];
    f16x4 v4 = *(const f16x4*)&H[(size_t)c1.x * 64 + cl * 4];
    f16x4 v5 = *(const f16x4*)&H[(size_t)c1.y * 64 + cl * 4];
    f16x4 v6 = *(const f16x4*)&H[(size_t)c1.z * 64 + cl * 4];
    f16x4 v7 = *(const f16x4*)&H[(size_t)c1.w * 64 + cl * 4];
    f16x4 t01 = v0 + v1;
    f16x4 t23 = v2 + v3;
    f16x4 t45 = v4 + v5;
    f16x4 t67 = v6 + v7;
    a = a + ((t01 + t23) + (t45 + t67));
  }
  if (valid && cl < 10) {
    float dv = dinv[ic];
    float4 bb = *(const float4*)&bias[cl * 4];
    float4 o;
    o.x = fmaf((float)a[0], dv, bb.x);
    o.y = fmaf((float)a[1], dv, bb.y);
    o.z = fmaf((float)a[2], dv, bb.z);
    o.w = fmaf((float)a[3], dv, bb.w);
    *(float4*)&out[(size_t)i * 40 + cl * 4] = o;
  }
}

// ============================ batchnorm stats (fp16 input) ============================
__global__ __launch_bounds__(256) void bn_stats_h(const f16* __restrict__ H, int n,
                                                  float* __restrict__ acc) {
  int t = threadIdx.x;
  int c2 = t & 63;
  int rg = t >> 6;
  float2 s = {0.f, 0.f}, s2 = {0.f, 0.f};
  for (int r = blockIdx.x * 4 + rg; r < n; r += gridDim.x * 4) {
    float2 v = __half22float2(*(const __half2*)&H[(size_t)r * 128 + c2 * 2]);
    s.x += v.x;
    s.y += v.y;
    s2.x = fmaf(v.x, v.x, s2.x);
    s2.y = fmaf(v.y, v.y, s2.y);
  }
  __shared__ float ls[4][128], ls2[4][128];
  ls[rg][c2 * 2] = s.x;
  ls[rg][c2 * 2 + 1] = s.y;
  ls2[rg][c2 * 2] = s2.x;
  ls2[rg][c2 * 2 + 1] = s2.y;
  __syncthreads();
  if (t < 128) {
    float a_ = ls[0][t] + ls[1][t] + ls[2][t] + ls[3][t];
    float b_ = ls2[0][t] + ls2[1][t] + ls2[2][t] + ls2[3][t];
    atomicAdd(&acc[t], a_);
    atomicAdd(&acc[128 + t], b_);
  }
}

// ============================ launch ============================
extern "C" void kernel_launch(void* const* d_in, const int* in_sizes, int n_in,
                              void* d_out, int out_size, void* d_ws, size_t ws_size,
                              hipStream_t stream) {
  const float* x = (const float*)d_in[0];
  const void* eb = d_in[1];
  const float* W1 = (const float*)d_in[2];
  const float* b1 = (const float*)d_in[3];
  const float* g1 = (const float*)d_in[4];
  const float* bt1 = (const float*)d_in[5];
  const float* W2 = (const float*)d_in[6];
  const float* b2 = (const float*)d_in[7];
  const float* g2 = (const float*)d_in[8];
  const float* bt2 = (const float*)d_in[9];
  const float* W3 = (const float*)d_in[10];
  const float* b3 = (const float*)d_in[11];

  const int n = in_sizes[0] / 128;
  const int E = in_sizes[1] / 2;
  const float inv_n = 1.0f / (float)n;

  char* w = (char*)d_ws;
  auto alloc = [&](size_t bytes) {
    void* p = (void*)w;
    w += (bytes + 255) & ~(size_t)255;
    return p;
  };
  const int NBKT = (n + 511) / 512;  // buckets of 512 nodes (<= 256)
  f16* hA = (f16*)alloc((size_t)(n + 1) * 128 * 2);  // +1 zero row
  f16* hB = (f16*)alloc((size_t)(n + 1) * 128 * 2);
  int* csr = (int*)alloc((size_t)NBKT * CSRCAP * 4);
  int2* part = (int2*)alloc((size_t)NBKT * BCAP * 8);
  float* dinv = (float*)alloc((size_t)n * 4);
  int2* rpc = (int2*)alloc((size_t)n * 8);
  f16* Wt1 = (f16*)alloc(128 * 128 * 2);
  f16* Wt2 = (f16*)alloc(128 * 128 * 2);
  f16* Wt3 = (f16*)alloc(64 * 128 * 2);
  // contiguous zero region:
  int* pcur = (int*)alloc(256 * 4);
  float* bn_acc1 = (float*)alloc(256 * 4);
  float* bn_acc2 = (float*)alloc(256 * 4);
  size_t zbytes = (char*)bn_acc2 + 256 * 4 - (char*)pcur;
  hipMemsetAsync(pcur, 0, zbytes, stream);

  const int PB = (E + PCHUNK - 1) / PCHUNK;

  prep_all<<<320, 128, 0, stream>>>(W1, W2, W3, Wt1, Wt2, Wt3);

  part_k<<<PB, 512, 0, stream>>>(eb, E, pcur, part);
  sort_k<<<NBKT, 512, 0, stream>>>(part, pcur, rpc, dinv, csr, n);

  const int GB = (n + 128) / 128;             // covers row n (zero row)
  const int NQ = (n + 3) / 4;                 // quads
  const int AGB = (NQ + 3) / 4;               // one quad per wave, 4 waves/block

  // layer 1
  gemm_mfma<128, false, true><<<GB, 256, 0, stream>>>(x, Wt1, nullptr, nullptr,
                                                      nullptr, inv_n, dinv, hA, n);
  agg128h<<<AGB, 256, 0, stream>>>(hA, rpc, csr, dinv, b1, hB, n);
  bn_stats_h<<<1024, 256, 0, stream>>>(hB, n, bn_acc1);
  // layer 2 (BN scale/shift computed inside GEMM from raw sums)
  gemm_mfma<128, true, false><<<GB, 256, 0, stream>>>(hB, Wt2, bn_acc1, g1, bt1,
                                                      inv_n, dinv, hA, n);
  agg128h<<<AGB, 256, 0, stream>>>(hA, rpc, csr, dinv, b2, hB, n);
  bn_stats_h<<<1024, 256, 0, stream>>>(hB, n, bn_acc2);
  // layer 3 (H padded to 64 cols for line-aligned gathers)
  gemm_mfma<64, true, false><<<GB, 256, 0, stream>>>(hB, Wt3, bn_acc2, g2, bt2,
                                                     inv_n, dinv, hA, n);
  agg64h<<<AGB, 256, 0, stream>>>(hA, rpc, csr, dinv, b3, (float*)d_out, n);
}

// Round 13
// 374.347 us; speedup vs baseline: 1.8984x; 1.1279x over previous
//
#include <hip/hip_runtime.h>
#include <hip/hip_fp16.h>
#include <cstdint>

#define BN_EPS 1e-5f
#define PCHUNK 8192
#define BCAP 16384    // per-bucket part capacity
#define CSRCAP 16384  // per-bucket csr capacity (padded degree sum ~10.3K max)

typedef _Float16 f16;
typedef _Float16 f16x8 __attribute__((ext_vector_type(8)));
typedef _Float16 f16x4 __attribute__((ext_vector_type(4)));
typedef float f32x4 __attribute__((ext_vector_type(4)));

// ============================ edge preprocessing ============================

__device__ __forceinline__ void load_edge(const void* eb, int E, bool w64,
                                          int e, int& s, int& d) {
  if (w64) {
    const long long* p = (const long long*)eb;
    s = (int)p[e];
    d = (int)p[E + e];
  } else {
    const int* p = (const int*)eb;
    s = p[e];
    d = p[E + e];
  }
}

// --- partition: block-local bucket grouping -> 64B-aligned contiguous runs ---
// 8192-edge chunks, 512 threads, 64KB LDS stage. Per-block int64/int32 detect.
__global__ __launch_bounds__(512) void part_k(const void* __restrict__ eb, int E,
                                              int* __restrict__ pcur,
                                              int2* __restrict__ part) {
  __shared__ int hist[256], lofs[256], gbase[256], lcur[256];
  __shared__ int sa[256], sb[256];
  __shared__ int2 stage[PCHUNK];  // 64KB
  __shared__ int w64f;
  const int t = threadIdx.x;
  const int e0 = blockIdx.x * PCHUNK;
  const int cnt = min(PCHUNK, E - e0);
  if (t < 256) hist[t] = 0;
  if (t == 0) w64f = 0;
  __syncthreads();
  {
    const unsigned* w = (const unsigned*)eb;
    int nz = 0;
    int cov = min(cnt, 512);
    for (int k = t; k < cov; k += 512) nz |= (w[2 * (size_t)(e0 + k) + 1] != 0u);
    if (nz) atomicOr(&w64f, 1);
  }
  __syncthreads();
  const bool w64 = (w64f == 0);
  int2 ed[16];
#pragma unroll
  for (int k = 0; k < 16; k++) {
    int idx = t + k * 512;
    if (idx < cnt) {
      int s, d;
      load_edge(eb, E, w64, e0 + idx, s, d);
      ed[k].x = s;
      ed[k].y = d;
      atomicAdd(&hist[d >> 9], 1);
    }
  }
  __syncthreads();
  // exclusive scan of hist (256 entries) -> lofs
  if (t < 256) sa[t] = hist[t];
  __syncthreads();
  int* src = sa;
  int* dst = sb;
  for (int off = 1; off < 256; off <<= 1) {
    int val = 0;
    if (t < 256) val = src[t] + (t >= off ? src[t - off] : 0);
    __syncthreads();
    if (t < 256) dst[t] = val;
    __syncthreads();
    int* tmp = src; src = dst; dst = tmp;
  }
  int c = 0;
  if (t < 256) {
    c = hist[t];
    lofs[t] = src[t] - c;
    int cpad = (c + 7) & ~7;  // 64B-aligned reservation
    gbase[t] = (c > 0) ? (t * BCAP + atomicAdd(&pcur[t], cpad)) : 0;
    lcur[t] = src[t] - c;
  }
  __syncthreads();
  // place into staging, grouped by bucket
#pragma unroll
  for (int k = 0; k < 16; k++) {
    int idx = t + k * 512;
    if (idx < cnt) {
      int b = ed[k].y >> 9;
      int p = atomicAdd(&lcur[b], 1);
      stage[p] = ed[k];
    }
  }
  __syncthreads();
  // stream out: each bucket-run lands contiguously at its 64B-aligned base
  for (int idx = t; idx < cnt; idx += 512) {
    int2 e = stage[idx];
    int b = e.y >> 9;
    part[gbase[b] + (idx - lofs[b])] = e;
  }
  // sentinel padding (dst=-1) fills the aligned tail
  if (t < 256 && c > 0) {
    int cpad = (c + 7) & ~7;
    for (int k = c; k < cpad; k++) part[gbase[t] + k] = make_int2(0, -1);
  }
}

// --- per-bucket: local degree histogram -> rpc{start,cntp}, dinv, padded csr ---
// Each node's csr segment 8-aligned & padded with zero-row index n.
__global__ __launch_bounds__(512) void sort_k(const int2* __restrict__ part,
                                              const int* __restrict__ pcur,
                                              int2* __restrict__ rpc,
                                              float* __restrict__ dinv,
                                              int* __restrict__ csr, int n) {
  __shared__ int lhist[512], lcur[512], lstart[512];
  __shared__ int sa[512], sb[512];
  const int b = blockIdx.x;
  const int d0 = b << 9;
  const int t = threadIdx.x;
  const int nloc = min(512, n - d0);
  lhist[t] = 0;
  __syncthreads();
  const int base = b * BCAP;
  const int T = pcur[b];
  for (int idx = t; idx < T; idx += 512) {
    int2 e = part[base + idx];
    if (e.y >= 0) atomicAdd(&lhist[e.y - d0], 1);
  }
  __syncthreads();
  int c = lhist[t];
  int cpad = (c + 7) & ~7;
  sa[t] = cpad;
  __syncthreads();
  int* src = sa;
  int* dst = sb;
  for (int off = 1; off < 512; off <<= 1) {
    int val = src[t] + (t >= off ? src[t - off] : 0);
    __syncthreads();
    dst[t] = val;
    __syncthreads();
    int* tmp = src; src = dst; dst = tmp;
  }
  int start = b * CSRCAP + src[t] - cpad;
  if (t < nloc) {
    rpc[d0 + t] = make_int2(start, cpad);
    dinv[d0 + t] = rsqrtf((float)(c + 1));  // +1 self-loop
  }
  lstart[t] = start;
  lcur[t] = start;
  __syncthreads();
  for (int idx = t; idx < T; idx += 512) {
    int2 e = part[base + idx];
    if (e.y >= 0) {
      int pos = atomicAdd(&lcur[e.y - d0], 1);
      csr[pos] = e.x;
    }
  }
  // pad each segment tail with zero-row index n
  if (t < nloc) {
    for (int k = c; k < cpad; k++) csr[lstart[t] + k] = n;
  }
}

// ============================ W prep: transpose + fp16 (single launch) ============
__global__ void prep_all(const float* __restrict__ W1, const float* __restrict__ W2,
                         const float* __restrict__ W3, f16* __restrict__ Wt1,
                         f16* __restrict__ Wt2, f16* __restrict__ Wt3) {
  int b = blockIdx.x, k = threadIdx.x;  // 128 threads
  if (b < 128) {
    Wt1[(size_t)b * 128 + k] = (f16)W1[(size_t)k * 128 + b];
  } else if (b < 256) {
    int nc = b - 128;
    Wt2[(size_t)nc * 128 + k] = (f16)W2[(size_t)k * 128 + nc];
  } else {
    int nc = b - 256;  // 0..63
    Wt3[(size_t)nc * 128 + k] = (nc < 40) ? (f16)W3[(size_t)k * 40 + nc] : (f16)0.f;
  }
}

// ============================ GEMM (MFMA f16, dinv-folded epilogue) ============
// H'[row] = dinv[row] * act(X)[row] @ W ; row n (zero row) written as zeros.
// BN scale/shift derived from 4-replica raw sums (sum at r*256+t, sq at +128).
template <int NCP, bool BN, bool F32IN>
__global__ __launch_bounds__(256) void gemm_mfma(const void* __restrict__ Xv,
                                                 const f16* __restrict__ Wt,
                                                 const float* __restrict__ bn_acc,
                                                 const float* __restrict__ g,
                                                 const float* __restrict__ bt,
                                                 float inv_n,
                                                 const float* __restrict__ dinv,
                                                 f16* __restrict__ H, int n) {
  constexpr int CB = NCP / 16;
  __shared__ f16 Xs[128][136];
  __shared__ f16 Ws[NCP][136];
  __shared__ float bnS[128], bnH[128];
  const int t = threadIdx.x;
  const int m0 = blockIdx.x * 128;

  if (BN) {
    if (t < 128) {
      float s0 = bn_acc[t] + bn_acc[256 + t] + bn_acc[512 + t] + bn_acc[768 + t];
      float s1 = bn_acc[128 + t] + bn_acc[384 + t] + bn_acc[640 + t] +
                 bn_acc[896 + t];
      float mean = s0 * inv_n;
      float var = s1 * inv_n - mean * mean;
      float sc = g[t] * rsqrtf(var + BN_EPS);
      bnS[t] = sc;
      bnH[t] = fmaf(-mean, sc, bt[t]);
    }
    __syncthreads();
  }

  if constexpr (F32IN) {
    const float* X = (const float*)Xv;
#pragma unroll
    for (int p = 0; p < 16; p++) {
      int idx = p * 256 + t;
      int row = idx >> 5, c = (idx & 31) * 4;
      float4 v = make_float4(0.f, 0.f, 0.f, 0.f);
      if (m0 + row < n) v = *(const float4*)&X[(size_t)(m0 + row) * 128 + c];
      if (BN) {
        v.x = fmaxf(fmaf(v.x, bnS[c + 0], bnH[c + 0]), 0.f);
        v.y = fmaxf(fmaf(v.y, bnS[c + 1], bnH[c + 1]), 0.f);
        v.z = fmaxf(fmaf(v.z, bnS[c + 2], bnH[c + 2]), 0.f);
        v.w = fmaxf(fmaf(v.w, bnS[c + 3], bnH[c + 3]), 0.f);
      }
      f16x4 h = {(f16)v.x, (f16)v.y, (f16)v.z, (f16)v.w};
      *(f16x4*)&Xs[row][c] = h;
    }
  } else {
    const f16* X = (const f16*)Xv;
#pragma unroll
    for (int p = 0; p < 8; p++) {
      int idx = p * 256 + t;
      int row = idx >> 4, c = (idx & 15) * 8;
      f16x8 v = {0, 0, 0, 0, 0, 0, 0, 0};
      if (m0 + row < n) v = *(const f16x8*)&X[(size_t)(m0 + row) * 128 + c];
      if (BN) {
#pragma unroll
        for (int j = 0; j < 8; j++) {
          float f = (float)v[j];
          f = fmaxf(fmaf(f, bnS[c + j], bnH[c + j]), 0.f);
          v[j] = (f16)f;
        }
      }
      *(f16x8*)&Xs[row][c] = v;
    }
  }
#pragma unroll
  for (int idx = t; idx < NCP * 16; idx += 256) {
    int row = idx >> 4, c = (idx & 15) * 8;
    *(f16x8*)&Ws[row][c] = *(const f16x8*)&Wt[(size_t)row * 128 + c];
  }
  __syncthreads();

  const int w = t >> 6, l = t & 63;
  const int lr = l & 15, lq = l >> 4;
  f32x4 acc[2][CB];
#pragma unroll
  for (int i = 0; i < 2; i++)
#pragma unroll
    for (int j = 0; j < CB; j++) acc[i][j] = (f32x4){0.f, 0.f, 0.f, 0.f};

#pragma unroll
  for (int kb = 0; kb < 4; kb++) {
    f16x8 xf0 = *(const f16x8*)&Xs[w * 32 + lr][kb * 32 + lq * 8];
    f16x8 xf1 = *(const f16x8*)&Xs[w * 32 + 16 + lr][kb * 32 + lq * 8];
#pragma unroll
    for (int cb = 0; cb < CB; cb++) {
      f16x8 wf = *(const f16x8*)&Ws[cb * 16 + lr][kb * 32 + lq * 8];
      acc[0][cb] = __builtin_amdgcn_mfma_f32_16x16x32_f16(wf, xf0, acc[0][cb], 0, 0, 0);
      acc[1][cb] = __builtin_amdgcn_mfma_f32_16x16x32_f16(wf, xf1, acc[1][cb], 0, 0, 0);
    }
  }
#pragma unroll
  for (int rg = 0; rg < 2; rg++) {
    int row = m0 + w * 32 + rg * 16 + lr;
    if (row > n) continue;
    float dv = (row < n) ? dinv[row] : 0.f;  // row n -> zeros (padding row)
#pragma unroll
    for (int cb = 0; cb < CB; cb++) {
      int col = cb * 16 + lq * 4;
      f32x4 a = acc[rg][cb];
      f16x4 h = {(f16)(a[0] * dv), (f16)(a[1] * dv), (f16)(a[2] * dv),
                 (f16)(a[3] * dv)};
      *(f16x4*)&H[(size_t)row * NCP + col] = h;
    }
  }
}

// ============================ aggregation + fused BN stats ============================
// out[i][:] = dinv[i] * (H'[i][:] + sum_e H'[src[e]][:]) + bias
// QUAD: nodes (4q..4q+3) on 16-lane groups, 8 ch/lane (16B gathers). Padded
// csr -> branchless loop, f16 pk-add. Fused BN stats: shfl-reduce over the
// quad, LDS accumulate, 256 global atomics/block into replica blockIdx&3.
__global__ __launch_bounds__(256) void agg128h(const f16* __restrict__ H,
                                               const int2* __restrict__ rpc,
                                               const int* __restrict__ csr,
                                               const float* __restrict__ dinv,
                                               const float* __restrict__ bias,
                                               f16* __restrict__ out,
                                               float* __restrict__ bnacc, int n) {
  __shared__ float lsum[128], lsq[128];
  const int t = threadIdx.x;
  if (t < 128) {
    lsum[t] = 0.f;
    lsq[t] = 0.f;
  }
  __syncthreads();
  const int lane = t & 63;
  const int sub = lane >> 4, cl = lane & 15;
  const int q = (blockIdx.x * 256 + t) >> 6;
  const int i = q * 4 + sub;
  const bool valid = (i < n);
  const int ic = valid ? i : 0;
  f16x8 a = *(const f16x8*)&H[(size_t)ic * 128 + cl * 8];
  int2 rc = rpc[ic];
  const int e0 = rc.x, cntp = rc.y;
  for (int j = 0; j < cntp; j += 8) {
    int4 c0 = *(const int4*)&csr[e0 + j];
    int4 c1 = *(const int4*)&csr[e0 + j + 4];
    f16x8 v0 = *(const f16x8*)&H[(size_t)c0.x * 128 + cl * 8];
    f16x8 v1 = *(const f16x8*)&H[(size_t)c0.y * 128 + cl * 8];
    f16x8 v2 = *(const f16x8*)&H[(size_t)c0.z * 128 + cl * 8];
    f16x8 v3 = *(const f16x8*)&H[(size_t)c0.w * 128 + cl * 8];
    f16x8 v4 = *(const f16x8*)&H[(size_t)c1.x * 128 + cl * 8];
    f16x8 v5 = *(const f16x8*)&H[(size_t)c1.y * 128 + cl * 8];
    f16x8 v6 = *(const f16x8*)&H[(size_t)c1.z * 128 + cl * 8];
    f16x8 v7 = *(const f16x8*)&H[(size_t)c1.w * 128 + cl * 8];
    f16x8 t01 = v0 + v1;
    f16x8 t23 = v2 + v3;
    f16x8 t45 = v4 + v5;
    f16x8 t67 = v6 + v7;
    a = a + ((t01 + t23) + (t45 + t67));
  }
  float dv = dinv[ic];
  float4 b0 = *(const float4*)&bias[cl * 8];
  float4 b1 = *(const float4*)&bias[cl * 8 + 4];
  float ov[8];
  ov[0] = fmaf((float)a[0], dv, b0.x);
  ov[1] = fmaf((float)a[1], dv, b0.y);
  ov[2] = fmaf((float)a[2], dv, b0.z);
  ov[3] = fmaf((float)a[3], dv, b0.w);
  ov[4] = fmaf((float)a[4], dv, b1.x);
  ov[5] = fmaf((float)a[5], dv, b1.y);
  ov[6] = fmaf((float)a[6], dv, b1.z);
  ov[7] = fmaf((float)a[7], dv, b1.w);
  if (valid) {
    f16x8 h;
#pragma unroll
    for (int c = 0; c < 8; c++) h[c] = (f16)ov[c];
    *(f16x8*)&out[(size_t)i * 128 + cl * 8] = h;
  }
  // ---- fused BN stats ----
  float hs[8], qs[8];
#pragma unroll
  for (int c = 0; c < 8; c++) {
    float v = valid ? ov[c] : 0.f;
    hs[c] = v;
    qs[c] = v * v;
  }
#pragma unroll
  for (int c = 0; c < 8; c++) {
    hs[c] += __shfl_xor(hs[c], 16);
    hs[c] += __shfl_xor(hs[c], 32);
    qs[c] += __shfl_xor(qs[c], 16);
    qs[c] += __shfl_xor(qs[c], 32);
  }
  if (sub == 0) {
#pragma unroll
    for (int c = 0; c < 8; c++) {
      atomicAdd(&lsum[cl * 8 + c], hs[c]);
      atomicAdd(&lsq[cl * 8 + c], qs[c]);
    }
  }
  __syncthreads();
  if (t < 128) {
    float* dstp = bnacc + (blockIdx.x & 3) * 256;
    atomicAdd(&dstp[t], lsum[t]);
    atomicAdd(&dstp[128 + t], lsq[t]);
  }
}

// layer-3: H padded to 64 cols (128B rows); QUAD, 4 ch/lane (8B gathers).
__global__ __launch_bounds__(256) void agg64h(const f16* __restrict__ H,
                                              const int2* __restrict__ rpc,
                                              const int* __restrict__ csr,
                                              const float* __restrict__ dinv,
                                              const float* __restrict__ bias,
                                              float* __restrict__ out, int n) {
  const int lane = threadIdx.x & 63;
  const int sub = lane >> 4, cl = lane & 15;
  const int q = (blockIdx.x * 256 + threadIdx.x) >> 6;
  const int i = q * 4 + sub;
  const bool valid = (i < n);
  const int ic = valid ? i : 0;
  f16x4 a = *(const f16x4*)&H[(size_t)ic * 64 + cl * 4];
  int2 rc = rpc[ic];
  const int e0 = rc.x, cntp = rc.y;
  for (int j = 0; j < cntp; j += 8) {
    int4 c0 = *(const int4*)&csr[e0 + j];
    int4 c1 = *(const int4*)&csr[e0 + j + 4];
    f16x4 v0 = *(const f16x4*)&H[(size_t)c0.x * 64 + cl * 4];
    f16x4 v1 = *(const f16x4*)&H[(size_t)c0.y * 64 + cl * 4];
    f16x4 v2 = *(const f16x4*)&H[(size_t)c0.z * 64 + cl * 4];
    f16x4 v3 = *(const f16x4*)&H[(size_t)c0.w * 64 + cl * 4];
    f16x4 v4 = *(const f16x4*)&H[(size_t)c1.x * 64 + cl * 4];
    f16x4 v5 = *(const f16x4*)&H[(size_t)c1.y * 64 + cl * 4];
    f16x4 v6 = *(const f16x4*)&H[(size_t)c1.z * 64 + cl * 4];
    f16x4 v7 = *(const f16x4*)&H[(size_t)c1.w * 64 + cl * 4];
    f16x4 t01 = v0 + v1;
    f16x4 t23 = v2 + v3;
    f16x4 t45 = v4 + v5;
    f16x4 t67 = v6 + v7;
    a = a + ((t01 + t23) + (t45 + t67));
  }
  if (valid && cl < 10) {
    float dv = dinv[ic];
    float4 bb = *(const float4*)&bias[cl * 4];
    float4 o;
    o.x = fmaf((float)a[0], dv, bb.x);
    o.y = fmaf((float)a[1], dv, bb.y);
    o.z = fmaf((float)a[2], dv, bb.z);
    o.w = fmaf((float)a[3], dv, bb.w);
    *(float4*)&out[(size_t)i * 40 + cl * 4] = o;
  }
}

// ============================ launch ============================
extern "C" void kernel_launch(void* const* d_in, const int* in_sizes, int n_in,
                              void* d_out, int out_size, void* d_ws, size_t ws_size,
                              hipStream_t stream) {
  const float* x = (const float*)d_in[0];
  const void* eb = d_in[1];
  const float* W1 = (const float*)d_in[2];
  const float* b1 = (const float*)d_in[3];
  const float* g1 = (const float*)d_in[4];
  const float* bt1 = (const float*)d_in[5];
  const float* W2 = (const float*)d_in[6];
  const float* b2 = (const float*)d_in[7];
  const float* g2 = (const float*)d_in[8];
  const float* bt2 = (const float*)d_in[9];
  const float* W3 = (const float*)d_in[10];
  const float* b3 = (const float*)d_in[11];

  const int n = in_sizes[0] / 128;
  const int E = in_sizes[1] / 2;
  const float inv_n = 1.0f / (float)n;

  char* w = (char*)d_ws;
  auto alloc = [&](size_t bytes) {
    void* p = (void*)w;
    w += (bytes + 255) & ~(size_t)255;
    return p;
  };
  const int NBKT = (n + 511) / 512;  // buckets of 512 nodes (<= 256)
  f16* hA = (f16*)alloc((size_t)(n + 1) * 128 * 2);  // +1 zero row
  f16* hB = (f16*)alloc((size_t)(n + 1) * 128 * 2);
  int* csr = (int*)alloc((size_t)NBKT * CSRCAP * 4);
  int2* part = (int2*)alloc((size_t)NBKT * BCAP * 8);
  float* dinv = (float*)alloc((size_t)n * 4);
  int2* rpc = (int2*)alloc((size_t)n * 8);
  f16* Wt1 = (f16*)alloc(128 * 128 * 2);
  f16* Wt2 = (f16*)alloc(128 * 128 * 2);
  f16* Wt3 = (f16*)alloc(64 * 128 * 2);
  // contiguous zero region:
  int* pcur = (int*)alloc(256 * 4);
  float* bn_acc1 = (float*)alloc(1024 * 4);  // 4 replicas x (128 sum + 128 sq)
  float* bn_acc2 = (float*)alloc(1024 * 4);
  size_t zbytes = (char*)bn_acc2 + 1024 * 4 - (char*)pcur;
  hipMemsetAsync(pcur, 0, zbytes, stream);

  const int PB = (E + PCHUNK - 1) / PCHUNK;

  prep_all<<<320, 128, 0, stream>>>(W1, W2, W3, Wt1, Wt2, Wt3);

  part_k<<<PB, 512, 0, stream>>>(eb, E, pcur, part);
  sort_k<<<NBKT, 512, 0, stream>>>(part, pcur, rpc, dinv, csr, n);

  const int GB = (n + 128) / 128;  // covers row n (zero row)
  const int NQ = (n + 3) / 4;      // quads
  const int AGB = (NQ + 3) / 4;    // one quad per wave, 4 waves/block

  // layer 1
  gemm_mfma<128, false, true><<<GB, 256, 0, stream>>>(x, Wt1, nullptr, nullptr,
                                                      nullptr, inv_n, dinv, hA, n);
  agg128h<<<AGB, 256, 0, stream>>>(hA, rpc, csr, dinv, b1, hB, bn_acc1, n);
  // layer 2 (BN scale/shift from fused 4-replica raw sums)
  gemm_mfma<128, true, false><<<GB, 256, 0, stream>>>(hB, Wt2, bn_acc1, g1, bt1,
                                                      inv_n, dinv, hA, n);
  agg128h<<<AGB, 256, 0, stream>>>(hA, rpc, csr, dinv, b2, hB, bn_acc2, n);
  // layer 3 (H padded to 64 cols for line-aligned gathers)
  gemm_mfma<64, true, false><<<GB, 256, 0, stream>>>(hB, Wt3, bn_acc2, g2, bt2,
                                                     inv_n, dinv, hA, n);
  agg64h<<<AGB, 256, 0, stream>>>(hA, rpc, csr, dinv, b3, (float*)d_out, n);
}